// Round 3
// baseline (4706.257 us; speedup 1.0000x reference)
//
#include <hip/hip_runtime.h>
#include <math.h>

#define BN_SCALE 0.999995000037499687f   // 1/sqrt(1+1e-5)
#define NPTS 1024
#define NB   2048    // 32*64 clouds

// exact-rounding sum of 3 squares, matching XLA/NumPy's ((x*x + y*y) + z*z) without fma contraction
__device__ __forceinline__ float sq3(float x, float y, float z) {
  return __fadd_rn(__fadd_rn(__fmul_rn(x, x), __fmul_rn(y, y)), __fmul_rn(z, z));
}

// ---------------------------------------------------------------------------
// FPS over 1024 points -> 32 centers per cloud. Bit-exact mirror of reference.
// ---------------------------------------------------------------------------
__global__ __launch_bounds__(256) void k_fps1(const float* __restrict__ x,
                                              float* __restrict__ nxyz1) {
  int b = blockIdx.x;
  const float* cloud = x + (size_t)b * NPTS * 6;
  __shared__ float px[NPTS], py[NPTS], pz[NPTS], dist[NPTS];
  __shared__ float wv_s[4];
  __shared__ int   wi_s[4];
  __shared__ int   last_s;
  int t = threadIdx.x;
  for (int i = t; i < NPTS; i += 256) {
    px[i] = cloud[i * 6 + 0];
    py[i] = cloud[i * 6 + 1];
    pz[i] = cloud[i * 6 + 2];
    dist[i] = 1e10f;
  }
  __syncthreads();
  if (t == 0) {
    nxyz1[(size_t)b * 96 + 0] = px[0];
    nxyz1[(size_t)b * 96 + 1] = py[0];
    nxyz1[(size_t)b * 96 + 2] = pz[0];
  }
  int last = 0;
  for (int s = 1; s < 32; ++s) {
    float lx = px[last], ly = py[last], lz = pz[last];
    float bv = -1.0f; int bi = NPTS;
    for (int i = t; i < NPTS; i += 256) {
      float dx = __fsub_rn(px[i], lx);
      float dy = __fsub_rn(py[i], ly);
      float dz = __fsub_rn(pz[i], lz);
      float d  = sq3(dx, dy, dz);
      float nd = fminf(dist[i], d);
      dist[i] = nd;
      if (nd > bv || (nd == bv && i < bi)) { bv = nd; bi = i; }
    }
    // wave64 reduce (first-occurrence argmax: prefer larger val, then smaller idx)
    for (int off = 32; off; off >>= 1) {
      float ov = __shfl_down(bv, off);
      int   oi = __shfl_down(bi, off);
      if (ov > bv || (ov == bv && oi < bi)) { bv = ov; bi = oi; }
    }
    if ((t & 63) == 0) { wv_s[t >> 6] = bv; wi_s[t >> 6] = bi; }
    __syncthreads();                       // sync A
    if (t == 0) {
      for (int w = 1; w < 4; ++w)
        if (wv_s[w] > bv || (wv_s[w] == bv && wi_s[w] < bi)) { bv = wv_s[w]; bi = wi_s[w]; }
      last_s = bi;
      nxyz1[(size_t)b * 96 + s * 3 + 0] = px[bi];
      nxyz1[(size_t)b * 96 + s * 3 + 1] = py[bi];
      nxyz1[(size_t)b * 96 + s * 3 + 2] = pz[bi];
    }
    __syncthreads();                       // sync B
    last = last_s;
  }
}

// ---------------------------------------------------------------------------
// Ball query SA1: 65536 centers, scan 1024 points in index order, first 32 hits.
// d2 mirrors the reference's expanded form |c|^2 + |p|^2 - 2*c.p (rn ops, no fma).
// ---------------------------------------------------------------------------
__global__ __launch_bounds__(256) void k_bq1(const float* __restrict__ x,
                                             const float* __restrict__ nxyz1,
                                             int* __restrict__ idx1) {
  int c = blockIdx.x * 256 + threadIdx.x;
  if (c >= NB * 32) return;
  int b = c >> 5;
  const float* cloud = x + (size_t)b * NPTS * 6;
  float cx = nxyz1[c * 3 + 0], cy = nxyz1[c * 3 + 1], cz = nxyz1[c * 3 + 2];
  float sqc = sq3(cx, cy, cz);
  const float r2 = (float)(0.2 * 0.2);
  int hits = 0, fh = NPTS - 1;
  int* outp = idx1 + (size_t)c * 32;
  for (int i = 0; i < NPTS; ++i) {
    float ppx = cloud[i * 6 + 0], ppy = cloud[i * 6 + 1], ppz = cloud[i * 6 + 2];
    float sqp = sq3(ppx, ppy, ppz);
    float dt  = __fadd_rn(__fadd_rn(__fmul_rn(cx, ppx), __fmul_rn(cy, ppy)), __fmul_rn(cz, ppz));
    float d2  = __fsub_rn(__fadd_rn(sqc, sqp), __fmul_rn(2.0f, dt));
    if (d2 < r2) {
      if (hits == 0) fh = i;
      outp[hits] = i;
      if (++hits == 32) break;
    }
  }
  for (int j = hits; j < 32; ++j) outp[j] = fh;
}

// ---------------------------------------------------------------------------
// SA1 grouping + MLP(6->64->64->128) + max over 32 samples. One block per center.
// ---------------------------------------------------------------------------
__global__ __launch_bounds__(256) void k_sa1(const float* __restrict__ x,
                                             const float* __restrict__ nxyz1,
                                             const int* __restrict__ idx1,
                                             const float* __restrict__ w0, const float* __restrict__ b0,
                                             const float* __restrict__ w1, const float* __restrict__ b1,
                                             const float* __restrict__ w2, const float* __restrict__ b2,
                                             float* __restrict__ f1) {
  int c = blockIdx.x;           // 0..65535
  int b = c >> 5;
  int t = threadIdx.x;
  __shared__ float h0[32][6];
  __shared__ float h1[32][64];
  __shared__ float h2[32][64];
  __shared__ float pm[2][128];
  const float* cloud = x + (size_t)b * NPTS * 6;
  const int* idx = idx1 + (size_t)c * 32;
  if (t < 192) {
    int samp = t / 6, d = t - samp * 6;
    int pt = idx[samp];
    float v = cloud[pt * 6 + d];
    if (d < 3) v -= nxyz1[c * 3 + d];
    h0[samp][d] = v;
  }
  __syncthreads();
  // L1: 32x64, dot6. thread -> (oc = t&63, 8 samples)
  {
    int oc = t & 63, sg = t >> 6;
    float acc[8];
    float bb = b0[oc];
    #pragma unroll
    for (int k = 0; k < 8; ++k) acc[k] = bb;
    for (int d = 0; d < 6; ++d) {
      float wv = w0[d * 64 + oc];
      #pragma unroll
      for (int k = 0; k < 8; ++k) acc[k] += h0[sg * 8 + k][d] * wv;
    }
    #pragma unroll
    for (int k = 0; k < 8; ++k) h1[sg * 8 + k][oc] = fmaxf(acc[k] * BN_SCALE, 0.f);
  }
  __syncthreads();
  // L2: 32x64, dot64
  {
    int oc = t & 63, sg = t >> 6;
    float acc[8];
    float bb = b1[oc];
    #pragma unroll
    for (int k = 0; k < 8; ++k) acc[k] = bb;
    for (int d4 = 0; d4 < 16; ++d4) {
      int d = d4 * 4;
      float wa = w1[(d + 0) * 64 + oc];
      float wb = w1[(d + 1) * 64 + oc];
      float wc = w1[(d + 2) * 64 + oc];
      float wd = w1[(d + 3) * 64 + oc];
      #pragma unroll
      for (int k = 0; k < 8; ++k) {
        float4 h4 = *reinterpret_cast<const float4*>(&h1[sg * 8 + k][d]);
        acc[k] += h4.x * wa + h4.y * wb + h4.z * wc + h4.w * wd;
      }
    }
    #pragma unroll
    for (int k = 0; k < 8; ++k) h2[sg * 8 + k][oc] = fmaxf(acc[k] * BN_SCALE, 0.f);
  }
  __syncthreads();
  // L3: 32x128, dot64, folded max over samples
  {
    int oc = t & 127, part = t >> 7;
    float acc[16];
    float bb = b2[oc];
    #pragma unroll
    for (int k = 0; k < 16; ++k) acc[k] = bb;
    for (int d4 = 0; d4 < 16; ++d4) {
      int d = d4 * 4;
      float wa = w2[(d + 0) * 128 + oc];
      float wb = w2[(d + 1) * 128 + oc];
      float wc = w2[(d + 2) * 128 + oc];
      float wd = w2[(d + 3) * 128 + oc];
      #pragma unroll
      for (int k = 0; k < 16; ++k) {
        float4 h4 = *reinterpret_cast<const float4*>(&h2[part * 16 + k][d]);
        acc[k] += h4.x * wa + h4.y * wb + h4.z * wc + h4.w * wd;
      }
    }
    float m = 0.f;
    #pragma unroll
    for (int k = 0; k < 16; ++k) m = fmaxf(m, fmaxf(acc[k] * BN_SCALE, 0.f));
    pm[part][oc] = m;
  }
  __syncthreads();
  if (t < 128) f1[(size_t)c * 128 + t] = fmaxf(pm[0][t], pm[1][t]);
}

// ---------------------------------------------------------------------------
// FPS over 32 centers -> 16. One wave per cloud.
// ---------------------------------------------------------------------------
__global__ __launch_bounds__(64) void k_fps2(const float* __restrict__ nxyz1,
                                             float* __restrict__ nxyz2) {
  int b = blockIdx.x;
  int t = threadIdx.x;  // 0..63
  const float* pts = nxyz1 + (size_t)b * 96;
  float ppx = 0.f, ppy = 0.f, ppz = 0.f, dist = -1.f;
  if (t < 32) { ppx = pts[t * 3]; ppy = pts[t * 3 + 1]; ppz = pts[t * 3 + 2]; dist = 1e10f; }
  if (t == 0) {
    nxyz2[(size_t)b * 48 + 0] = ppx;
    nxyz2[(size_t)b * 48 + 1] = ppy;
    nxyz2[(size_t)b * 48 + 2] = ppz;
  }
  int last = 0;
  for (int s = 1; s < 16; ++s) {
    float lx = __shfl(ppx, last), ly = __shfl(ppy, last), lz = __shfl(ppz, last);
    if (t < 32) {
      float dx = __fsub_rn(ppx, lx);
      float dy = __fsub_rn(ppy, ly);
      float dz = __fsub_rn(ppz, lz);
      dist = fminf(dist, sq3(dx, dy, dz));
    }
    float bv = dist; int bi = (t < 32) ? t : 1000;
    for (int off = 32; off; off >>= 1) {
      float ov = __shfl_xor(bv, off);
      int   oi = __shfl_xor(bi, off);
      if (ov > bv || (ov == bv && oi < bi)) { bv = ov; bi = oi; }
    }
    last = bi;   // all lanes agree
    float bx = __shfl(ppx, last), by = __shfl(ppy, last), bz = __shfl(ppz, last);
    if (t == 0) {
      nxyz2[(size_t)b * 48 + s * 3 + 0] = bx;
      nxyz2[(size_t)b * 48 + s * 3 + 1] = by;
      nxyz2[(size_t)b * 48 + s * 3 + 2] = bz;
    }
  }
}

// ---------------------------------------------------------------------------
// Ball query SA2: 32768 centers, 32 candidate points, radius 0.4.
// ---------------------------------------------------------------------------
__global__ __launch_bounds__(256) void k_bq2(const float* __restrict__ nxyz1,
                                             const float* __restrict__ nxyz2,
                                             int* __restrict__ idx2) {
  int c = blockIdx.x * 256 + threadIdx.x;
  if (c >= NB * 16) return;
  int b = c >> 4;
  const float* pts = nxyz1 + (size_t)b * 96;
  float cx = nxyz2[c * 3 + 0], cy = nxyz2[c * 3 + 1], cz = nxyz2[c * 3 + 2];
  float sqc = sq3(cx, cy, cz);
  const float r2 = (float)(0.4 * 0.4);
  int hits = 0, fh = 31;
  int* outp = idx2 + (size_t)c * 32;
  for (int i = 0; i < 32; ++i) {
    float ppx = pts[i * 3], ppy = pts[i * 3 + 1], ppz = pts[i * 3 + 2];
    float sqp = sq3(ppx, ppy, ppz);
    float dt  = __fadd_rn(__fadd_rn(__fmul_rn(cx, ppx), __fmul_rn(cy, ppy)), __fmul_rn(cz, ppz));
    float d2  = __fsub_rn(__fadd_rn(sqc, sqp), __fmul_rn(2.0f, dt));
    if (d2 < r2) { if (hits == 0) fh = i; outp[hits++] = i; }
  }
  for (int j = hits; j < 32; ++j) outp[j] = fh;
}

// ---------------------------------------------------------------------------
// SA2 grouping + MLP(131->128->128->256) + max over 32. One block per center.
// ---------------------------------------------------------------------------
__global__ __launch_bounds__(256) void k_sa2(const float* __restrict__ nxyz1,
                                             const float* __restrict__ nxyz2,
                                             const int* __restrict__ idx2,
                                             const float* __restrict__ f1,
                                             const float* __restrict__ w0, const float* __restrict__ b0,
                                             const float* __restrict__ w1, const float* __restrict__ b1,
                                             const float* __restrict__ w2, const float* __restrict__ b2,
                                             float* __restrict__ f2) {
  int c = blockIdx.x;  // 0..32767
  int b = c >> 4;
  int t = threadIdx.x;
  __shared__ float ha[32][132];  // h0 (131 cols); later reused for L2 output (128 cols)
  __shared__ float hb[32][128];  // L1 output
  const int* idx = idx2 + (size_t)c * 32;
  float cx = nxyz2[c * 3 + 0], cy = nxyz2[c * 3 + 1], cz = nxyz2[c * 3 + 2];
  for (int j = t; j < 32 * 131; j += 256) {
    int samp = j / 131, d = j - samp * 131;
    int pt = idx[samp];
    float v;
    if (d < 3) {
      v = nxyz1[((size_t)b * 32 + pt) * 3 + d] - (d == 0 ? cx : (d == 1 ? cy : cz));
    } else {
      v = f1[((size_t)b * 32 + pt) * 128 + (d - 3)];
    }
    ha[samp][d] = v;
  }
  __syncthreads();
  // L1: 32x128, dot131 -> hb
  {
    int oc = t & 127, sb = t >> 7;
    float acc[16];
    float bb = b0[oc];
    #pragma unroll
    for (int k = 0; k < 16; ++k) acc[k] = bb;
    for (int d4 = 0; d4 < 32; ++d4) {
      int d = d4 * 4;
      float wa = w0[(d + 0) * 128 + oc];
      float wb = w0[(d + 1) * 128 + oc];
      float wc = w0[(d + 2) * 128 + oc];
      float wd = w0[(d + 3) * 128 + oc];
      #pragma unroll
      for (int k = 0; k < 16; ++k) {
        float4 h4 = *reinterpret_cast<const float4*>(&ha[sb * 16 + k][d]);
        acc[k] += h4.x * wa + h4.y * wb + h4.z * wc + h4.w * wd;
      }
    }
    for (int d = 128; d < 131; ++d) {
      float wv = w0[d * 128 + oc];
      #pragma unroll
      for (int k = 0; k < 16; ++k) acc[k] += ha[sb * 16 + k][d] * wv;
    }
    #pragma unroll
    for (int k = 0; k < 16; ++k) hb[sb * 16 + k][oc] = fmaxf(acc[k] * BN_SCALE, 0.f);
  }
  __syncthreads();
  // L2: 32x128, dot128 -> ha (cols 0..127)
  {
    int oc = t & 127, sb = t >> 7;
    float acc[16];
    float bb = b1[oc];
    #pragma unroll
    for (int k = 0; k < 16; ++k) acc[k] = bb;
    for (int d4 = 0; d4 < 32; ++d4) {
      int d = d4 * 4;
      float wa = w1[(d + 0) * 128 + oc];
      float wb = w1[(d + 1) * 128 + oc];
      float wc = w1[(d + 2) * 128 + oc];
      float wd = w1[(d + 3) * 128 + oc];
      #pragma unroll
      for (int k = 0; k < 16; ++k) {
        float4 h4 = *reinterpret_cast<const float4*>(&hb[sb * 16 + k][d]);
        acc[k] += h4.x * wa + h4.y * wb + h4.z * wc + h4.w * wd;
      }
    }
    __syncthreads();
    #pragma unroll
    for (int k = 0; k < 16; ++k) ha[sb * 16 + k][oc] = fmaxf(acc[k] * BN_SCALE, 0.f);
  }
  __syncthreads();
  // L3: 32x256, dot128, folded max over 32 samples. oc = t.
  {
    float acc[32];
    float bb = b2[t];
    #pragma unroll
    for (int s = 0; s < 32; ++s) acc[s] = bb;
    for (int d4 = 0; d4 < 32; ++d4) {
      int d = d4 * 4;
      float wa = w2[(d + 0) * 256 + t];
      float wb = w2[(d + 1) * 256 + t];
      float wc = w2[(d + 2) * 256 + t];
      float wd = w2[(d + 3) * 256 + t];
      #pragma unroll
      for (int s = 0; s < 32; ++s) {
        float4 h4 = *reinterpret_cast<const float4*>(&ha[s][d]);
        acc[s] += h4.x * wa + h4.y * wb + h4.z * wc + h4.w * wd;
      }
    }
    float m = 0.f;
    #pragma unroll
    for (int s = 0; s < 32; ++s) m = fmaxf(m, fmaxf(acc[s] * BN_SCALE, 0.f));
    f2[(size_t)c * 256 + t] = m;
  }
}

// ---------------------------------------------------------------------------
// MLP3 (259->256->512->768) over 16 rows + max + FC(768->768). One block per cloud.
// LDS overlaid phases, peak 48KB.
// ---------------------------------------------------------------------------
__global__ __launch_bounds__(256) void k_mlp3(const float* __restrict__ nxyz2,
                                              const float* __restrict__ f2,
                                              const float* __restrict__ w0, const float* __restrict__ b0,
                                              const float* __restrict__ w1, const float* __restrict__ b1,
                                              const float* __restrict__ w2, const float* __restrict__ b2,
                                              const float* __restrict__ fcw, const float* __restrict__ fcb,
                                              float* __restrict__ outp) {
  int b = blockIdx.x;
  int t = threadIdx.x;
  __shared__ float smem[12288];            // 48KB
  float* h1 = smem;                        // [16][256] at 0      (16KB)
  float* h0 = smem + 4096;                 // [16][260] at 16KB   (16.25KB)  dead after L1
  float* h2 = smem + 4096;                 // [16][512] at 16KB   (32KB)     overlays h0
  float* g  = smem;                        // [768]     at 0      overlays h1 after L2 done
  // load h0 (pitch 260)
  for (int j = t; j < 16 * 259; j += 256) {
    int s = j / 259, d = j - s * 259;
    float v = (d < 3) ? nxyz2[(size_t)b * 48 + s * 3 + d]
                      : f2[((size_t)b * 16 + s) * 256 + (d - 3)];
    h0[s * 260 + d] = v;
  }
  __syncthreads();
  // L1: 16x256, dot259. oc = t.
  {
    float acc[16];
    float bb = b0[t];
    #pragma unroll
    for (int s = 0; s < 16; ++s) acc[s] = bb;
    for (int d4 = 0; d4 < 64; ++d4) {
      int d = d4 * 4;
      float wa = w0[(d + 0) * 256 + t];
      float wb = w0[(d + 1) * 256 + t];
      float wc = w0[(d + 2) * 256 + t];
      float wd = w0[(d + 3) * 256 + t];
      #pragma unroll
      for (int s = 0; s < 16; ++s) {
        float4 h4 = *reinterpret_cast<const float4*>(&h0[s * 260 + d]);
        acc[s] += h4.x * wa + h4.y * wb + h4.z * wc + h4.w * wd;
      }
    }
    for (int d = 256; d < 259; ++d) {
      float wv = w0[d * 256 + t];
      #pragma unroll
      for (int s = 0; s < 16; ++s) acc[s] += h0[s * 260 + d] * wv;
    }
    #pragma unroll
    for (int s = 0; s < 16; ++s) h1[s * 256 + t] = fmaxf(acc[s] * BN_SCALE, 0.f);
  }
  __syncthreads();
  // L2: 16x512, dot256 -> h2 (overlays dead h0). ocs t and t+256.
  {
    float acc0[16], acc1[16];
    float ba = b1[t], bb2 = b1[t + 256];
    #pragma unroll
    for (int s = 0; s < 16; ++s) { acc0[s] = ba; acc1[s] = bb2; }
    for (int d4 = 0; d4 < 64; ++d4) {
      int d = d4 * 4;
      float wa0 = w1[(d + 0) * 512 + t],       wa1 = w1[(d + 0) * 512 + t + 256];
      float wb0 = w1[(d + 1) * 512 + t],       wb1 = w1[(d + 1) * 512 + t + 256];
      float wc0 = w1[(d + 2) * 512 + t],       wc1 = w1[(d + 2) * 512 + t + 256];
      float wd0 = w1[(d + 3) * 512 + t],       wd1 = w1[(d + 3) * 512 + t + 256];
      #pragma unroll
      for (int s = 0; s < 16; ++s) {
        float4 h4 = *reinterpret_cast<const float4*>(&h1[s * 256 + d]);
        acc0[s] += h4.x * wa0 + h4.y * wb0 + h4.z * wc0 + h4.w * wd0;
        acc1[s] += h4.x * wa1 + h4.y * wb1 + h4.z * wc1 + h4.w * wd1;
      }
    }
    __syncthreads();   // all reads of h0 region done before overlaying with h2
    #pragma unroll
    for (int s = 0; s < 16; ++s) {
      h2[s * 512 + t]       = fmaxf(acc0[s] * BN_SCALE, 0.f);
      h2[s * 512 + t + 256] = fmaxf(acc1[s] * BN_SCALE, 0.f);
    }
  }
  __syncthreads();
  // L3: 16x768, dot512, folded max -> g (overlays dead h1). ocs t, t+256, t+512.
  {
    float acc0[16], acc1[16], acc2[16];
    float ba = b2[t], bb2 = b2[t + 256], bc = b2[t + 512];
    #pragma unroll
    for (int s = 0; s < 16; ++s) { acc0[s] = ba; acc1[s] = bb2; acc2[s] = bc; }
    for (int d = 0; d < 512; ++d) {
      float w_0 = w2[(size_t)d * 768 + t];
      float w_1 = w2[(size_t)d * 768 + t + 256];
      float w_2 = w2[(size_t)d * 768 + t + 512];
      #pragma unroll
      for (int s = 0; s < 16; ++s) {
        float hv = h2[s * 512 + d];
        acc0[s] += hv * w_0;
        acc1[s] += hv * w_1;
        acc2[s] += hv * w_2;
      }
    }
    float m0 = 0.f, m1 = 0.f, m2 = 0.f;
    #pragma unroll
    for (int s = 0; s < 16; ++s) {
      m0 = fmaxf(m0, fmaxf(acc0[s] * BN_SCALE, 0.f));
      m1 = fmaxf(m1, fmaxf(acc1[s] * BN_SCALE, 0.f));
      m2 = fmaxf(m2, fmaxf(acc2[s] * BN_SCALE, 0.f));
    }
    __syncthreads();  // h1 region dead; safe to overlay g
    g[t] = m0; g[t + 256] = m1; g[t + 512] = m2;
  }
  __syncthreads();
  // FC: 768 -> 768
  {
    float a0 = fcb[t], a1 = fcb[t + 256], a2 = fcb[t + 512];
    for (int d = 0; d < 768; ++d) {
      float gv = g[d];
      a0 += gv * fcw[(size_t)d * 768 + t];
      a1 += gv * fcw[(size_t)d * 768 + t + 256];
      a2 += gv * fcw[(size_t)d * 768 + t + 512];
    }
    outp[(size_t)b * 768 + t]       = a0;
    outp[(size_t)b * 768 + t + 256] = a1;
    outp[(size_t)b * 768 + t + 512] = a2;
  }
}

// ---------------------------------------------------------------------------
extern "C" void kernel_launch(void* const* d_in, const int* in_sizes, int n_in,
                              void* d_out, int out_size, void* d_ws, size_t ws_size,
                              hipStream_t stream) {
  const float* x    = (const float*)d_in[0];
  const float* w1_0 = (const float*)d_in[1];  const float* b1_0 = (const float*)d_in[2];
  const float* w1_1 = (const float*)d_in[3];  const float* b1_1 = (const float*)d_in[4];
  const float* w1_2 = (const float*)d_in[5];  const float* b1_2 = (const float*)d_in[6];
  const float* w2_0 = (const float*)d_in[7];  const float* b2_0 = (const float*)d_in[8];
  const float* w2_1 = (const float*)d_in[9];  const float* b2_1 = (const float*)d_in[10];
  const float* w2_2 = (const float*)d_in[11]; const float* b2_2 = (const float*)d_in[12];
  const float* w3_0 = (const float*)d_in[13]; const float* b3_0 = (const float*)d_in[14];
  const float* w3_1 = (const float*)d_in[15]; const float* b3_1 = (const float*)d_in[16];
  const float* w3_2 = (const float*)d_in[17]; const float* b3_2 = (const float*)d_in[18];
  const float* fc_w = (const float*)d_in[19]; const float* fc_b = (const float*)d_in[20];
  float* outp = (float*)d_out;

  // Workspace layout (floats):
  //   nxyz1: NB*96        = 196,608
  //   nxyz2: NB*48        =  98,304
  //   f1:    NB*32*128    = 8,388,608
  //   f2:    NB*16*256    = 8,388,608
  //   idx1:  NB*32*32 int = 2,097,152
  //   idx2:  NB*16*32 int = 1,048,576
  // total ≈ 80.9 MB. Guard against a smaller ws to avoid OOB GPU faults.
  const size_t need_bytes =
      ((size_t)NB * 96 + (size_t)NB * 48 + (size_t)NB * 32 * 128 +
       (size_t)NB * 16 * 256) * sizeof(float) +
      ((size_t)NB * 32 * 32 + (size_t)NB * 16 * 32) * sizeof(int);
  if (ws_size < need_bytes) {
    // Not enough scratch: skip launches; harness will report a clean absmax
    // failure instead of a GPU memory fault.
    return;
  }

  float* nxyz1 = (float*)d_ws;                       // 2048*32*3
  float* nxyz2 = nxyz1 + (size_t)NB * 96;            // 2048*16*3
  float* f1    = nxyz2 + (size_t)NB * 48;            // 2048*32*128
  float* f2    = f1    + (size_t)NB * 32 * 128;      // 2048*16*256
  int*   idx1  = (int*)(f2 + (size_t)NB * 16 * 256); // 2048*32*32
  int*   idx2  = idx1 + (size_t)NB * 32 * 32;        // 2048*16*32

  k_fps1<<<NB, 256, 0, stream>>>(x, nxyz1);
  k_bq1 <<<(NB * 32) / 256, 256, 0, stream>>>(x, nxyz1, idx1);
  k_sa1 <<<NB * 32, 256, 0, stream>>>(x, nxyz1, idx1, w1_0, b1_0, w1_1, b1_1, w1_2, b1_2, f1);
  k_fps2<<<NB, 64, 0, stream>>>(nxyz1, nxyz2);
  k_bq2 <<<(NB * 16) / 256, 256, 0, stream>>>(nxyz1, nxyz2, idx2);
  k_sa2 <<<NB * 16, 256, 0, stream>>>(nxyz1, nxyz2, idx2, f1,
                                      w2_0, b2_0, w2_1, b2_1, w2_2, b2_2, f2);
  k_mlp3<<<NB, 256, 0, stream>>>(nxyz2, f2, w3_0, b3_0, w3_1, b3_1, w3_2, b3_2,
                                 fc_w, fc_b, outp);
}

// Round 4
// 3794.607 us; speedup vs baseline: 1.2402x; 1.2402x over previous
//
#include <hip/hip_runtime.h>
#include <math.h>

#define BN_SCALE 0.999995000037499687f   // 1/sqrt(1+1e-5)
#define NPTS 1024
#define NB   2048    // 32*64 clouds

// exact-rounding sum of 3 squares, matching XLA/NumPy's ((x*x + y*y) + z*z) without fma contraction
__device__ __forceinline__ float sq3(float x, float y, float z) {
  return __fadd_rn(__fadd_rn(__fmul_rn(x, x), __fmul_rn(y, y)), __fmul_rn(z, z));
}

// ---------------------------------------------------------------------------
// FPS over 1024 points -> 32 centers per cloud. Bit-exact mirror of reference.
// ---------------------------------------------------------------------------
__global__ __launch_bounds__(256) void k_fps1(const float* __restrict__ x,
                                              float* __restrict__ nxyz1) {
  int b = blockIdx.x;
  const float* cloud = x + (size_t)b * NPTS * 6;
  __shared__ float px[NPTS], py[NPTS], pz[NPTS], dist[NPTS];
  __shared__ float wv_s[4];
  __shared__ int   wi_s[4];
  __shared__ int   last_s;
  int t = threadIdx.x;
  for (int i = t; i < NPTS; i += 256) {
    px[i] = cloud[i * 6 + 0];
    py[i] = cloud[i * 6 + 1];
    pz[i] = cloud[i * 6 + 2];
    dist[i] = 1e10f;
  }
  __syncthreads();
  if (t == 0) {
    nxyz1[(size_t)b * 96 + 0] = px[0];
    nxyz1[(size_t)b * 96 + 1] = py[0];
    nxyz1[(size_t)b * 96 + 2] = pz[0];
  }
  int last = 0;
  for (int s = 1; s < 32; ++s) {
    float lx = px[last], ly = py[last], lz = pz[last];
    float bv = -1.0f; int bi = NPTS;
    for (int i = t; i < NPTS; i += 256) {
      float dx = __fsub_rn(px[i], lx);
      float dy = __fsub_rn(py[i], ly);
      float dz = __fsub_rn(pz[i], lz);
      float d  = sq3(dx, dy, dz);
      float nd = fminf(dist[i], d);
      dist[i] = nd;
      if (nd > bv || (nd == bv && i < bi)) { bv = nd; bi = i; }
    }
    for (int off = 32; off; off >>= 1) {
      float ov = __shfl_down(bv, off);
      int   oi = __shfl_down(bi, off);
      if (ov > bv || (ov == bv && oi < bi)) { bv = ov; bi = oi; }
    }
    if ((t & 63) == 0) { wv_s[t >> 6] = bv; wi_s[t >> 6] = bi; }
    __syncthreads();
    if (t == 0) {
      for (int w = 1; w < 4; ++w)
        if (wv_s[w] > bv || (wv_s[w] == bv && wi_s[w] < bi)) { bv = wv_s[w]; bi = wi_s[w]; }
      last_s = bi;
      nxyz1[(size_t)b * 96 + s * 3 + 0] = px[bi];
      nxyz1[(size_t)b * 96 + s * 3 + 1] = py[bi];
      nxyz1[(size_t)b * 96 + s * 3 + 2] = pz[bi];
    }
    __syncthreads();
    last = last_s;
  }
}

// ---------------------------------------------------------------------------
// Ball query SA1 (unchanged; bit-exact d2 formula).
// ---------------------------------------------------------------------------
__global__ __launch_bounds__(256) void k_bq1(const float* __restrict__ x,
                                             const float* __restrict__ nxyz1,
                                             int* __restrict__ idx1) {
  int c = blockIdx.x * 256 + threadIdx.x;
  if (c >= NB * 32) return;
  int b = c >> 5;
  const float* cloud = x + (size_t)b * NPTS * 6;
  float cx = nxyz1[c * 3 + 0], cy = nxyz1[c * 3 + 1], cz = nxyz1[c * 3 + 2];
  float sqc = sq3(cx, cy, cz);
  const float r2 = (float)(0.2 * 0.2);
  int hits = 0, fh = NPTS - 1;
  int* outp = idx1 + (size_t)c * 32;
  for (int i = 0; i < NPTS; ++i) {
    float ppx = cloud[i * 6 + 0], ppy = cloud[i * 6 + 1], ppz = cloud[i * 6 + 2];
    float sqp = sq3(ppx, ppy, ppz);
    float dt  = __fadd_rn(__fadd_rn(__fmul_rn(cx, ppx), __fmul_rn(cy, ppy)), __fmul_rn(cz, ppz));
    float d2  = __fsub_rn(__fadd_rn(sqc, sqp), __fmul_rn(2.0f, dt));
    if (d2 < r2) {
      if (hits == 0) fh = i;
      outp[hits] = i;
      if (++hits == 32) break;
    }
  }
  for (int j = hits; j < 32; ++j) outp[j] = fh;
}

// ---------------------------------------------------------------------------
// SA1 grouping + MLP(6->64->64->128) + max. 2-oc register blocking in L2/L3,
// fmaf chains everywhere.
// ---------------------------------------------------------------------------
__global__ __launch_bounds__(256) void k_sa1(const float* __restrict__ x,
                                             const float* __restrict__ nxyz1,
                                             const int* __restrict__ idx1,
                                             const float* __restrict__ w0, const float* __restrict__ b0,
                                             const float* __restrict__ w1, const float* __restrict__ b1,
                                             const float* __restrict__ w2, const float* __restrict__ b2,
                                             float* __restrict__ f1) {
  int c = blockIdx.x;           // 0..65535
  int b = c >> 5;
  int t = threadIdx.x;
  __shared__ float h0[32][6];
  __shared__ float h1[32][64];
  __shared__ float h2[32][64];
  __shared__ float pm[4][128];
  const float* cloud = x + (size_t)b * NPTS * 6;
  const int* idx = idx1 + (size_t)c * 32;
  if (t < 192) {
    int samp = t / 6, d = t - samp * 6;
    int pt = idx[samp];
    float v = cloud[pt * 6 + d];
    if (d < 3) v -= nxyz1[c * 3 + d];
    h0[samp][d] = v;
  }
  __syncthreads();
  // L1: 32x64, dot6. (1 oc, 8 samples)
  {
    int oc = t & 63, sg = t >> 6;
    float acc[8];
    float bb = b0[oc];
    #pragma unroll
    for (int k = 0; k < 8; ++k) acc[k] = bb;
    for (int d = 0; d < 6; ++d) {
      float wv = w0[d * 64 + oc];
      #pragma unroll
      for (int k = 0; k < 8; ++k) acc[k] = fmaf(h0[sg * 8 + k][d], wv, acc[k]);
    }
    #pragma unroll
    for (int k = 0; k < 8; ++k) h1[sg * 8 + k][oc] = fmaxf(acc[k] * BN_SCALE, 0.f);
  }
  __syncthreads();
  // L2: 32x64, dot64. (2 oc, 4 samples): op = t&31 -> {op, op+32}; sg = t>>5
  {
    int op = t & 31, sg = t >> 5;
    float acc0[4], acc1[4];
    float bb0 = b1[op], bb1 = b1[op + 32];
    #pragma unroll
    for (int k = 0; k < 4; ++k) { acc0[k] = bb0; acc1[k] = bb1; }
    for (int d4 = 0; d4 < 16; ++d4) {
      int d = d4 * 4;
      float wa0 = w1[(d + 0) * 64 + op], wa1 = w1[(d + 0) * 64 + op + 32];
      float wb0 = w1[(d + 1) * 64 + op], wb1 = w1[(d + 1) * 64 + op + 32];
      float wc0 = w1[(d + 2) * 64 + op], wc1 = w1[(d + 2) * 64 + op + 32];
      float wd0 = w1[(d + 3) * 64 + op], wd1 = w1[(d + 3) * 64 + op + 32];
      #pragma unroll
      for (int k = 0; k < 4; ++k) {
        float4 h4 = *reinterpret_cast<const float4*>(&h1[sg * 4 + k][d]);
        acc0[k] = fmaf(h4.x, wa0, acc0[k]); acc0[k] = fmaf(h4.y, wb0, acc0[k]);
        acc0[k] = fmaf(h4.z, wc0, acc0[k]); acc0[k] = fmaf(h4.w, wd0, acc0[k]);
        acc1[k] = fmaf(h4.x, wa1, acc1[k]); acc1[k] = fmaf(h4.y, wb1, acc1[k]);
        acc1[k] = fmaf(h4.z, wc1, acc1[k]); acc1[k] = fmaf(h4.w, wd1, acc1[k]);
      }
    }
    #pragma unroll
    for (int k = 0; k < 4; ++k) {
      h2[sg * 4 + k][op]      = fmaxf(acc0[k] * BN_SCALE, 0.f);
      h2[sg * 4 + k][op + 32] = fmaxf(acc1[k] * BN_SCALE, 0.f);
    }
  }
  __syncthreads();
  // L3: 32x128, dot64, folded max. (2 oc, 8 samples): op = t&63 -> {op, op+64}; sg = t>>6
  {
    int op = t & 63, sg = t >> 6;
    float acc0[8], acc1[8];
    float bb0 = b2[op], bb1 = b2[op + 64];
    #pragma unroll
    for (int k = 0; k < 8; ++k) { acc0[k] = bb0; acc1[k] = bb1; }
    for (int d4 = 0; d4 < 16; ++d4) {
      int d = d4 * 4;
      float wa0 = w2[(d + 0) * 128 + op], wa1 = w2[(d + 0) * 128 + op + 64];
      float wb0 = w2[(d + 1) * 128 + op], wb1 = w2[(d + 1) * 128 + op + 64];
      float wc0 = w2[(d + 2) * 128 + op], wc1 = w2[(d + 2) * 128 + op + 64];
      float wd0 = w2[(d + 3) * 128 + op], wd1 = w2[(d + 3) * 128 + op + 64];
      #pragma unroll
      for (int k = 0; k < 8; ++k) {
        float4 h4 = *reinterpret_cast<const float4*>(&h2[sg * 8 + k][d]);
        acc0[k] = fmaf(h4.x, wa0, acc0[k]); acc0[k] = fmaf(h4.y, wb0, acc0[k]);
        acc0[k] = fmaf(h4.z, wc0, acc0[k]); acc0[k] = fmaf(h4.w, wd0, acc0[k]);
        acc1[k] = fmaf(h4.x, wa1, acc1[k]); acc1[k] = fmaf(h4.y, wb1, acc1[k]);
        acc1[k] = fmaf(h4.z, wc1, acc1[k]); acc1[k] = fmaf(h4.w, wd1, acc1[k]);
      }
    }
    float m0 = 0.f, m1 = 0.f;
    #pragma unroll
    for (int k = 0; k < 8; ++k) {
      m0 = fmaxf(m0, fmaxf(acc0[k] * BN_SCALE, 0.f));
      m1 = fmaxf(m1, fmaxf(acc1[k] * BN_SCALE, 0.f));
    }
    pm[sg][op] = m0; pm[sg][op + 64] = m1;
  }
  __syncthreads();
  if (t < 128) {
    float m = fmaxf(fmaxf(pm[0][t], pm[1][t]), fmaxf(pm[2][t], pm[3][t]));
    f1[(size_t)c * 128 + t] = m;
  }
}

// ---------------------------------------------------------------------------
// FPS over 32 centers -> 16. One wave per cloud. (unchanged)
// ---------------------------------------------------------------------------
__global__ __launch_bounds__(64) void k_fps2(const float* __restrict__ nxyz1,
                                             float* __restrict__ nxyz2) {
  int b = blockIdx.x;
  int t = threadIdx.x;
  const float* pts = nxyz1 + (size_t)b * 96;
  float ppx = 0.f, ppy = 0.f, ppz = 0.f, dist = -1.f;
  if (t < 32) { ppx = pts[t * 3]; ppy = pts[t * 3 + 1]; ppz = pts[t * 3 + 2]; dist = 1e10f; }
  if (t == 0) {
    nxyz2[(size_t)b * 48 + 0] = ppx;
    nxyz2[(size_t)b * 48 + 1] = ppy;
    nxyz2[(size_t)b * 48 + 2] = ppz;
  }
  int last = 0;
  for (int s = 1; s < 16; ++s) {
    float lx = __shfl(ppx, last), ly = __shfl(ppy, last), lz = __shfl(ppz, last);
    if (t < 32) {
      float dx = __fsub_rn(ppx, lx);
      float dy = __fsub_rn(ppy, ly);
      float dz = __fsub_rn(ppz, lz);
      dist = fminf(dist, sq3(dx, dy, dz));
    }
    float bv = dist; int bi = (t < 32) ? t : 1000;
    for (int off = 32; off; off >>= 1) {
      float ov = __shfl_xor(bv, off);
      int   oi = __shfl_xor(bi, off);
      if (ov > bv || (ov == bv && oi < bi)) { bv = ov; bi = oi; }
    }
    last = bi;
    float bx = __shfl(ppx, last), by = __shfl(ppy, last), bz = __shfl(ppz, last);
    if (t == 0) {
      nxyz2[(size_t)b * 48 + s * 3 + 0] = bx;
      nxyz2[(size_t)b * 48 + s * 3 + 1] = by;
      nxyz2[(size_t)b * 48 + s * 3 + 2] = bz;
    }
  }
}

// ---------------------------------------------------------------------------
// Ball query SA2 (unchanged).
// ---------------------------------------------------------------------------
__global__ __launch_bounds__(256) void k_bq2(const float* __restrict__ nxyz1,
                                             const float* __restrict__ nxyz2,
                                             int* __restrict__ idx2) {
  int c = blockIdx.x * 256 + threadIdx.x;
  if (c >= NB * 16) return;
  int b = c >> 4;
  const float* pts = nxyz1 + (size_t)b * 96;
  float cx = nxyz2[c * 3 + 0], cy = nxyz2[c * 3 + 1], cz = nxyz2[c * 3 + 2];
  float sqc = sq3(cx, cy, cz);
  const float r2 = (float)(0.4 * 0.4);
  int hits = 0, fh = 31;
  int* outp = idx2 + (size_t)c * 32;
  for (int i = 0; i < 32; ++i) {
    float ppx = pts[i * 3], ppy = pts[i * 3 + 1], ppz = pts[i * 3 + 2];
    float sqp = sq3(ppx, ppy, ppz);
    float dt  = __fadd_rn(__fadd_rn(__fmul_rn(cx, ppx), __fmul_rn(cy, ppy)), __fmul_rn(cz, ppz));
    float d2  = __fsub_rn(__fadd_rn(sqc, sqp), __fmul_rn(2.0f, dt));
    if (d2 < r2) { if (hits == 0) fh = i; outp[hits++] = i; }
  }
  for (int j = hits; j < 32; ++j) outp[j] = fh;
}

// ---------------------------------------------------------------------------
// SA2 grouping + MLP(131->128->128->256) + max. 2-oc register blocking,
// fmaf chains. DS reads/block: 524K -> 262K.
// ---------------------------------------------------------------------------
__global__ __launch_bounds__(256) void k_sa2(const float* __restrict__ nxyz1,
                                             const float* __restrict__ nxyz2,
                                             const int* __restrict__ idx2,
                                             const float* __restrict__ f1,
                                             const float* __restrict__ w0, const float* __restrict__ b0,
                                             const float* __restrict__ w1, const float* __restrict__ b1,
                                             const float* __restrict__ w2, const float* __restrict__ b2,
                                             float* __restrict__ f2) {
  int c = blockIdx.x;  // 0..32767
  int b = c >> 4;
  int t = threadIdx.x;
  __shared__ float ha[32][132];  // h0 (131 cols); later reused for L2 output (128 cols)
  __shared__ float hb[32][128];  // L1 output
  __shared__ float pm[2][256];
  const int* idx = idx2 + (size_t)c * 32;
  float cx = nxyz2[c * 3 + 0], cy = nxyz2[c * 3 + 1], cz = nxyz2[c * 3 + 2];
  for (int j = t; j < 32 * 131; j += 256) {
    int samp = j / 131, d = j - samp * 131;
    int pt = idx[samp];
    float v;
    if (d < 3) {
      v = nxyz1[((size_t)b * 32 + pt) * 3 + d] - (d == 0 ? cx : (d == 1 ? cy : cz));
    } else {
      v = f1[((size_t)b * 32 + pt) * 128 + (d - 3)];
    }
    ha[samp][d] = v;
  }
  __syncthreads();
  // L1: 32x128, dot131 -> hb. (2 oc, 8 samples): op=t&63 -> {op, op+64}; sg=t>>6
  {
    int op = t & 63, sg = t >> 6;
    float acc0[8], acc1[8];
    float bb0 = b0[op], bb1 = b0[op + 64];
    #pragma unroll
    for (int k = 0; k < 8; ++k) { acc0[k] = bb0; acc1[k] = bb1; }
    for (int d4 = 0; d4 < 32; ++d4) {
      int d = d4 * 4;
      float wa0 = w0[(d + 0) * 128 + op], wa1 = w0[(d + 0) * 128 + op + 64];
      float wb0 = w0[(d + 1) * 128 + op], wb1 = w0[(d + 1) * 128 + op + 64];
      float wc0 = w0[(d + 2) * 128 + op], wc1 = w0[(d + 2) * 128 + op + 64];
      float wd0 = w0[(d + 3) * 128 + op], wd1 = w0[(d + 3) * 128 + op + 64];
      #pragma unroll
      for (int k = 0; k < 8; ++k) {
        float4 h4 = *reinterpret_cast<const float4*>(&ha[sg * 8 + k][d]);
        acc0[k] = fmaf(h4.x, wa0, acc0[k]); acc0[k] = fmaf(h4.y, wb0, acc0[k]);
        acc0[k] = fmaf(h4.z, wc0, acc0[k]); acc0[k] = fmaf(h4.w, wd0, acc0[k]);
        acc1[k] = fmaf(h4.x, wa1, acc1[k]); acc1[k] = fmaf(h4.y, wb1, acc1[k]);
        acc1[k] = fmaf(h4.z, wc1, acc1[k]); acc1[k] = fmaf(h4.w, wd1, acc1[k]);
      }
    }
    for (int d = 128; d < 131; ++d) {
      float w_0 = w0[d * 128 + op], w_1 = w0[d * 128 + op + 64];
      #pragma unroll
      for (int k = 0; k < 8; ++k) {
        float hv = ha[sg * 8 + k][d];
        acc0[k] = fmaf(hv, w_0, acc0[k]);
        acc1[k] = fmaf(hv, w_1, acc1[k]);
      }
    }
    #pragma unroll
    for (int k = 0; k < 8; ++k) {
      hb[sg * 8 + k][op]      = fmaxf(acc0[k] * BN_SCALE, 0.f);
      hb[sg * 8 + k][op + 64] = fmaxf(acc1[k] * BN_SCALE, 0.f);
    }
  }
  __syncthreads();
  // L2: 32x128, dot128 -> ha[..][0..127]. (2 oc, 8 samples). ha-readers (L1) all done.
  {
    int op = t & 63, sg = t >> 6;
    float acc0[8], acc1[8];
    float bb0 = b1[op], bb1 = b1[op + 64];
    #pragma unroll
    for (int k = 0; k < 8; ++k) { acc0[k] = bb0; acc1[k] = bb1; }
    for (int d4 = 0; d4 < 32; ++d4) {
      int d = d4 * 4;
      float wa0 = w1[(d + 0) * 128 + op], wa1 = w1[(d + 0) * 128 + op + 64];
      float wb0 = w1[(d + 1) * 128 + op], wb1 = w1[(d + 1) * 128 + op + 64];
      float wc0 = w1[(d + 2) * 128 + op], wc1 = w1[(d + 2) * 128 + op + 64];
      float wd0 = w1[(d + 3) * 128 + op], wd1 = w1[(d + 3) * 128 + op + 64];
      #pragma unroll
      for (int k = 0; k < 8; ++k) {
        float4 h4 = *reinterpret_cast<const float4*>(&hb[sg * 8 + k][d]);
        acc0[k] = fmaf(h4.x, wa0, acc0[k]); acc0[k] = fmaf(h4.y, wb0, acc0[k]);
        acc0[k] = fmaf(h4.z, wc0, acc0[k]); acc0[k] = fmaf(h4.w, wd0, acc0[k]);
        acc1[k] = fmaf(h4.x, wa1, acc1[k]); acc1[k] = fmaf(h4.y, wb1, acc1[k]);
        acc1[k] = fmaf(h4.z, wc1, acc1[k]); acc1[k] = fmaf(h4.w, wd1, acc1[k]);
      }
    }
    #pragma unroll
    for (int k = 0; k < 8; ++k) {
      ha[sg * 8 + k][op]      = fmaxf(acc0[k] * BN_SCALE, 0.f);
      ha[sg * 8 + k][op + 64] = fmaxf(acc1[k] * BN_SCALE, 0.f);
    }
  }
  __syncthreads();
  // L3: 32x256, dot128, folded max. (2 oc, 16 samples): op=t&127 -> {op, op+128}; sb=t>>7
  {
    int op = t & 127, sb = t >> 7;
    float acc0[16], acc1[16];
    float bb0 = b2[op], bb1 = b2[op + 128];
    #pragma unroll
    for (int s = 0; s < 16; ++s) { acc0[s] = bb0; acc1[s] = bb1; }
    for (int d4 = 0; d4 < 32; ++d4) {
      int d = d4 * 4;
      float wa0 = w2[(d + 0) * 256 + op], wa1 = w2[(d + 0) * 256 + op + 128];
      float wb0 = w2[(d + 1) * 256 + op], wb1 = w2[(d + 1) * 256 + op + 128];
      float wc0 = w2[(d + 2) * 256 + op], wc1 = w2[(d + 2) * 256 + op + 128];
      float wd0 = w2[(d + 3) * 256 + op], wd1 = w2[(d + 3) * 256 + op + 128];
      #pragma unroll
      for (int s = 0; s < 16; ++s) {
        float4 h4 = *reinterpret_cast<const float4*>(&ha[sb * 16 + s][d]);
        acc0[s] = fmaf(h4.x, wa0, acc0[s]); acc0[s] = fmaf(h4.y, wb0, acc0[s]);
        acc0[s] = fmaf(h4.z, wc0, acc0[s]); acc0[s] = fmaf(h4.w, wd0, acc0[s]);
        acc1[s] = fmaf(h4.x, wa1, acc1[s]); acc1[s] = fmaf(h4.y, wb1, acc1[s]);
        acc1[s] = fmaf(h4.z, wc1, acc1[s]); acc1[s] = fmaf(h4.w, wd1, acc1[s]);
      }
    }
    float m0 = 0.f, m1 = 0.f;
    #pragma unroll
    for (int s = 0; s < 16; ++s) {
      m0 = fmaxf(m0, fmaxf(acc0[s] * BN_SCALE, 0.f));
      m1 = fmaxf(m1, fmaxf(acc1[s] * BN_SCALE, 0.f));
    }
    pm[sb][op] = m0; pm[sb][op + 128] = m1;
  }
  __syncthreads();
  f2[(size_t)c * 256 + t] = fmaxf(pm[0][t], pm[1][t]);
}

// ---------------------------------------------------------------------------
// MLP3 (259->256->512->768) over 16 rows + max + FC(768->768). One block per cloud.
// L3/FC inner reads vectorized to float4; fmaf chains.
// ---------------------------------------------------------------------------
__global__ __launch_bounds__(256) void k_mlp3(const float* __restrict__ nxyz2,
                                              const float* __restrict__ f2,
                                              const float* __restrict__ w0, const float* __restrict__ b0,
                                              const float* __restrict__ w1, const float* __restrict__ b1,
                                              const float* __restrict__ w2, const float* __restrict__ b2,
                                              const float* __restrict__ fcw, const float* __restrict__ fcb,
                                              float* __restrict__ outp) {
  int b = blockIdx.x;
  int t = threadIdx.x;
  __shared__ float smem[12288];            // 48KB
  float* h1 = smem;                        // [16][256] at 0
  float* h0 = smem + 4096;                 // [16][260] at 16KB (dead after L1)
  float* h2 = smem + 4096;                 // [16][512] overlays h0
  float* g  = smem;                        // [768] overlays h1 after L2 done
  for (int j = t; j < 16 * 259; j += 256) {
    int s = j / 259, d = j - s * 259;
    float v = (d < 3) ? nxyz2[(size_t)b * 48 + s * 3 + d]
                      : f2[((size_t)b * 16 + s) * 256 + (d - 3)];
    h0[s * 260 + d] = v;
  }
  __syncthreads();
  // L1: 16x256, dot259. oc = t.
  {
    float acc[16];
    float bb = b0[t];
    #pragma unroll
    for (int s = 0; s < 16; ++s) acc[s] = bb;
    for (int d4 = 0; d4 < 64; ++d4) {
      int d = d4 * 4;
      float wa = w0[(d + 0) * 256 + t];
      float wb = w0[(d + 1) * 256 + t];
      float wc = w0[(d + 2) * 256 + t];
      float wd = w0[(d + 3) * 256 + t];
      #pragma unroll
      for (int s = 0; s < 16; ++s) {
        float4 h4 = *reinterpret_cast<const float4*>(&h0[s * 260 + d]);
        acc[s] = fmaf(h4.x, wa, acc[s]); acc[s] = fmaf(h4.y, wb, acc[s]);
        acc[s] = fmaf(h4.z, wc, acc[s]); acc[s] = fmaf(h4.w, wd, acc[s]);
      }
    }
    for (int d = 256; d < 259; ++d) {
      float wv = w0[d * 256 + t];
      #pragma unroll
      for (int s = 0; s < 16; ++s) acc[s] = fmaf(h0[s * 260 + d], wv, acc[s]);
    }
    #pragma unroll
    for (int s = 0; s < 16; ++s) h1[s * 256 + t] = fmaxf(acc[s] * BN_SCALE, 0.f);
  }
  __syncthreads();
  // L2: 16x512, dot256 -> h2. ocs t and t+256.
  {
    float acc0[16], acc1[16];
    float ba = b1[t], bb2 = b1[t + 256];
    #pragma unroll
    for (int s = 0; s < 16; ++s) { acc0[s] = ba; acc1[s] = bb2; }
    for (int d4 = 0; d4 < 64; ++d4) {
      int d = d4 * 4;
      float wa0 = w1[(d + 0) * 512 + t],       wa1 = w1[(d + 0) * 512 + t + 256];
      float wb0 = w1[(d + 1) * 512 + t],       wb1 = w1[(d + 1) * 512 + t + 256];
      float wc0 = w1[(d + 2) * 512 + t],       wc1 = w1[(d + 2) * 512 + t + 256];
      float wd0 = w1[(d + 3) * 512 + t],       wd1 = w1[(d + 3) * 512 + t + 256];
      #pragma unroll
      for (int s = 0; s < 16; ++s) {
        float4 h4 = *reinterpret_cast<const float4*>(&h1[s * 256 + d]);
        acc0[s] = fmaf(h4.x, wa0, acc0[s]); acc0[s] = fmaf(h4.y, wb0, acc0[s]);
        acc0[s] = fmaf(h4.z, wc0, acc0[s]); acc0[s] = fmaf(h4.w, wd0, acc0[s]);
        acc1[s] = fmaf(h4.x, wa1, acc1[s]); acc1[s] = fmaf(h4.y, wb1, acc1[s]);
        acc1[s] = fmaf(h4.z, wc1, acc1[s]); acc1[s] = fmaf(h4.w, wd1, acc1[s]);
      }
    }
    __syncthreads();   // all reads of h0 region done before overlaying with h2
    #pragma unroll
    for (int s = 0; s < 16; ++s) {
      h2[s * 512 + t]       = fmaxf(acc0[s] * BN_SCALE, 0.f);
      h2[s * 512 + t + 256] = fmaxf(acc1[s] * BN_SCALE, 0.f);
    }
  }
  __syncthreads();
  // L3: 16x768, dot512, folded max -> g. ocs t, t+256, t+512. float4 h2 reads.
  {
    float acc0[16], acc1[16], acc2[16];
    float ba = b2[t], bb2 = b2[t + 256], bc = b2[t + 512];
    #pragma unroll
    for (int s = 0; s < 16; ++s) { acc0[s] = ba; acc1[s] = bb2; acc2[s] = bc; }
    for (int d4 = 0; d4 < 128; ++d4) {
      int d = d4 * 4;
      float wA0 = w2[(size_t)(d + 0) * 768 + t], wA1 = w2[(size_t)(d + 0) * 768 + t + 256], wA2 = w2[(size_t)(d + 0) * 768 + t + 512];
      float wB0 = w2[(size_t)(d + 1) * 768 + t], wB1 = w2[(size_t)(d + 1) * 768 + t + 256], wB2 = w2[(size_t)(d + 1) * 768 + t + 512];
      float wC0 = w2[(size_t)(d + 2) * 768 + t], wC1 = w2[(size_t)(d + 2) * 768 + t + 256], wC2 = w2[(size_t)(d + 2) * 768 + t + 512];
      float wD0 = w2[(size_t)(d + 3) * 768 + t], wD1 = w2[(size_t)(d + 3) * 768 + t + 256], wD2 = w2[(size_t)(d + 3) * 768 + t + 512];
      #pragma unroll
      for (int s = 0; s < 16; ++s) {
        float4 h4 = *reinterpret_cast<const float4*>(&h2[s * 512 + d]);
        acc0[s] = fmaf(h4.x, wA0, acc0[s]); acc0[s] = fmaf(h4.y, wB0, acc0[s]);
        acc0[s] = fmaf(h4.z, wC0, acc0[s]); acc0[s] = fmaf(h4.w, wD0, acc0[s]);
        acc1[s] = fmaf(h4.x, wA1, acc1[s]); acc1[s] = fmaf(h4.y, wB1, acc1[s]);
        acc1[s] = fmaf(h4.z, wC1, acc1[s]); acc1[s] = fmaf(h4.w, wD1, acc1[s]);
        acc2[s] = fmaf(h4.x, wA2, acc2[s]); acc2[s] = fmaf(h4.y, wB2, acc2[s]);
        acc2[s] = fmaf(h4.z, wC2, acc2[s]); acc2[s] = fmaf(h4.w, wD2, acc2[s]);
      }
    }
    float m0 = 0.f, m1 = 0.f, m2 = 0.f;
    #pragma unroll
    for (int s = 0; s < 16; ++s) {
      m0 = fmaxf(m0, fmaxf(acc0[s] * BN_SCALE, 0.f));
      m1 = fmaxf(m1, fmaxf(acc1[s] * BN_SCALE, 0.f));
      m2 = fmaxf(m2, fmaxf(acc2[s] * BN_SCALE, 0.f));
    }
    __syncthreads();  // h1 region dead; safe to overlay g
    g[t] = m0; g[t + 256] = m1; g[t + 512] = m2;
  }
  __syncthreads();
  // FC: 768 -> 768, float4 g reads.
  {
    float a0 = fcb[t], a1 = fcb[t + 256], a2 = fcb[t + 512];
    for (int d4 = 0; d4 < 192; ++d4) {
      int d = d4 * 4;
      float4 g4 = *reinterpret_cast<const float4*>(&g[d]);
      float wA0 = fcw[(size_t)(d + 0) * 768 + t], wA1 = fcw[(size_t)(d + 0) * 768 + t + 256], wA2 = fcw[(size_t)(d + 0) * 768 + t + 512];
      float wB0 = fcw[(size_t)(d + 1) * 768 + t], wB1 = fcw[(size_t)(d + 1) * 768 + t + 256], wB2 = fcw[(size_t)(d + 1) * 768 + t + 512];
      float wC0 = fcw[(size_t)(d + 2) * 768 + t], wC1 = fcw[(size_t)(d + 2) * 768 + t + 256], wC2 = fcw[(size_t)(d + 2) * 768 + t + 512];
      float wD0 = fcw[(size_t)(d + 3) * 768 + t], wD1 = fcw[(size_t)(d + 3) * 768 + t + 256], wD2 = fcw[(size_t)(d + 3) * 768 + t + 512];
      a0 = fmaf(g4.x, wA0, a0); a0 = fmaf(g4.y, wB0, a0); a0 = fmaf(g4.z, wC0, a0); a0 = fmaf(g4.w, wD0, a0);
      a1 = fmaf(g4.x, wA1, a1); a1 = fmaf(g4.y, wB1, a1); a1 = fmaf(g4.z, wC1, a1); a1 = fmaf(g4.w, wD1, a1);
      a2 = fmaf(g4.x, wA2, a2); a2 = fmaf(g4.y, wB2, a2); a2 = fmaf(g4.z, wC2, a2); a2 = fmaf(g4.w, wD2, a2);
    }
    outp[(size_t)b * 768 + t]       = a0;
    outp[(size_t)b * 768 + t + 256] = a1;
    outp[(size_t)b * 768 + t + 512] = a2;
  }
}

// ---------------------------------------------------------------------------
extern "C" void kernel_launch(void* const* d_in, const int* in_sizes, int n_in,
                              void* d_out, int out_size, void* d_ws, size_t ws_size,
                              hipStream_t stream) {
  const float* x    = (const float*)d_in[0];
  const float* w1_0 = (const float*)d_in[1];  const float* b1_0 = (const float*)d_in[2];
  const float* w1_1 = (const float*)d_in[3];  const float* b1_1 = (const float*)d_in[4];
  const float* w1_2 = (const float*)d_in[5];  const float* b1_2 = (const float*)d_in[6];
  const float* w2_0 = (const float*)d_in[7];  const float* b2_0 = (const float*)d_in[8];
  const float* w2_1 = (const float*)d_in[9];  const float* b2_1 = (const float*)d_in[10];
  const float* w2_2 = (const float*)d_in[11]; const float* b2_2 = (const float*)d_in[12];
  const float* w3_0 = (const float*)d_in[13]; const float* b3_0 = (const float*)d_in[14];
  const float* w3_1 = (const float*)d_in[15]; const float* b3_1 = (const float*)d_in[16];
  const float* w3_2 = (const float*)d_in[17]; const float* b3_2 = (const float*)d_in[18];
  const float* fc_w = (const float*)d_in[19]; const float* fc_b = (const float*)d_in[20];
  float* outp = (float*)d_out;

  const size_t need_bytes =
      ((size_t)NB * 96 + (size_t)NB * 48 + (size_t)NB * 32 * 128 +
       (size_t)NB * 16 * 256) * sizeof(float) +
      ((size_t)NB * 32 * 32 + (size_t)NB * 16 * 32) * sizeof(int);
  if (ws_size < need_bytes) return;

  float* nxyz1 = (float*)d_ws;
  float* nxyz2 = nxyz1 + (size_t)NB * 96;
  float* f1    = nxyz2 + (size_t)NB * 48;
  float* f2    = f1    + (size_t)NB * 32 * 128;
  int*   idx1  = (int*)(f2 + (size_t)NB * 16 * 256);
  int*   idx2  = idx1 + (size_t)NB * 32 * 32;

  k_fps1<<<NB, 256, 0, stream>>>(x, nxyz1);
  k_bq1 <<<(NB * 32) / 256, 256, 0, stream>>>(x, nxyz1, idx1);
  k_sa1 <<<NB * 32, 256, 0, stream>>>(x, nxyz1, idx1, w1_0, b1_0, w1_1, b1_1, w1_2, b1_2, f1);
  k_fps2<<<NB, 64, 0, stream>>>(nxyz1, nxyz2);
  k_bq2 <<<(NB * 16) / 256, 256, 0, stream>>>(nxyz1, nxyz2, idx2);
  k_sa2 <<<NB * 16, 256, 0, stream>>>(nxyz1, nxyz2, idx2, f1,
                                      w2_0, b2_0, w2_1, b2_1, w2_2, b2_2, f2);
  k_mlp3<<<NB, 256, 0, stream>>>(nxyz2, f2, w3_0, b3_0, w3_1, b3_1, w3_2, b3_2,
                                 fc_w, fc_b, outp);
}

// Round 5
// 2443.362 us; speedup vs baseline: 1.9261x; 1.5530x over previous
//
#include <hip/hip_runtime.h>
#include <math.h>

#define BN_SCALE 0.999995000037499687f   // 1/sqrt(1+1e-5)
#define NPTS 1024
#define NB   2048    // 32*64 clouds

typedef __attribute__((ext_vector_type(8))) short bh8;
typedef __attribute__((ext_vector_type(4))) float f32x4;

// exact-rounding sum of 3 squares, matching XLA/NumPy's ((x*x + y*y) + z*z) without fma contraction
__device__ __forceinline__ float sq3(float x, float y, float z) {
  return __fadd_rn(__fadd_rn(__fmul_rn(x, x), __fmul_rn(y, y)), __fmul_rn(z, z));
}

// RNE f32 -> bf16 bits
__device__ __forceinline__ short bf16hi(float v) {
  unsigned u = __float_as_uint(v);
  unsigned r = (u + 0x7FFFu + ((u >> 16) & 1u)) >> 16;
  return (short)r;
}
__device__ __forceinline__ float bf16tof(short s) {
  unsigned u = ((unsigned)(unsigned short)s) << 16;
  return __uint_as_float(u);
}
__device__ __forceinline__ void bf16split(float v, short& hi, short& lo) {
  hi = bf16hi(v);
  lo = bf16hi(v - bf16tof(hi));
}

// ---------------------------------------------------------------------------
// FPS over 1024 points -> 32 centers per cloud. Bit-exact mirror of reference.
// ---------------------------------------------------------------------------
__global__ __launch_bounds__(256) void k_fps1(const float* __restrict__ x,
                                              float* __restrict__ nxyz1) {
  int b = blockIdx.x;
  const float* cloud = x + (size_t)b * NPTS * 6;
  __shared__ float px[NPTS], py[NPTS], pz[NPTS], dist[NPTS];
  __shared__ float wv_s[4];
  __shared__ int   wi_s[4];
  __shared__ int   last_s;
  int t = threadIdx.x;
  for (int i = t; i < NPTS; i += 256) {
    px[i] = cloud[i * 6 + 0];
    py[i] = cloud[i * 6 + 1];
    pz[i] = cloud[i * 6 + 2];
    dist[i] = 1e10f;
  }
  __syncthreads();
  if (t == 0) {
    nxyz1[(size_t)b * 96 + 0] = px[0];
    nxyz1[(size_t)b * 96 + 1] = py[0];
    nxyz1[(size_t)b * 96 + 2] = pz[0];
  }
  int last = 0;
  for (int s = 1; s < 32; ++s) {
    float lx = px[last], ly = py[last], lz = pz[last];
    float bv = -1.0f; int bi = NPTS;
    for (int i = t; i < NPTS; i += 256) {
      float dx = __fsub_rn(px[i], lx);
      float dy = __fsub_rn(py[i], ly);
      float dz = __fsub_rn(pz[i], lz);
      float d  = sq3(dx, dy, dz);
      float nd = fminf(dist[i], d);
      dist[i] = nd;
      if (nd > bv || (nd == bv && i < bi)) { bv = nd; bi = i; }
    }
    for (int off = 32; off; off >>= 1) {
      float ov = __shfl_down(bv, off);
      int   oi = __shfl_down(bi, off);
      if (ov > bv || (ov == bv && oi < bi)) { bv = ov; bi = oi; }
    }
    if ((t & 63) == 0) { wv_s[t >> 6] = bv; wi_s[t >> 6] = bi; }
    __syncthreads();
    if (t == 0) {
      for (int w = 1; w < 4; ++w)
        if (wv_s[w] > bv || (wv_s[w] == bv && wi_s[w] < bi)) { bv = wv_s[w]; bi = wi_s[w]; }
      last_s = bi;
      nxyz1[(size_t)b * 96 + s * 3 + 0] = px[bi];
      nxyz1[(size_t)b * 96 + s * 3 + 1] = py[bi];
      nxyz1[(size_t)b * 96 + s * 3 + 2] = pz[bi];
    }
    __syncthreads();
    last = last_s;
  }
}

// ---------------------------------------------------------------------------
// Ball query SA1 (bit-exact d2 formula).
// ---------------------------------------------------------------------------
__global__ __launch_bounds__(256) void k_bq1(const float* __restrict__ x,
                                             const float* __restrict__ nxyz1,
                                             int* __restrict__ idx1) {
  int c = blockIdx.x * 256 + threadIdx.x;
  if (c >= NB * 32) return;
  int b = c >> 5;
  const float* cloud = x + (size_t)b * NPTS * 6;
  float cx = nxyz1[c * 3 + 0], cy = nxyz1[c * 3 + 1], cz = nxyz1[c * 3 + 2];
  float sqc = sq3(cx, cy, cz);
  const float r2 = (float)(0.2 * 0.2);
  int hits = 0, fh = NPTS - 1;
  int* outp = idx1 + (size_t)c * 32;
  for (int i = 0; i < NPTS; ++i) {
    float ppx = cloud[i * 6 + 0], ppy = cloud[i * 6 + 1], ppz = cloud[i * 6 + 2];
    float sqp = sq3(ppx, ppy, ppz);
    float dt  = __fadd_rn(__fadd_rn(__fmul_rn(cx, ppx), __fmul_rn(cy, ppy)), __fmul_rn(cz, ppz));
    float d2  = __fsub_rn(__fadd_rn(sqc, sqp), __fmul_rn(2.0f, dt));
    if (d2 < r2) {
      if (hits == 0) fh = i;
      outp[hits] = i;
      if (++hits == 32) break;
    }
  }
  for (int j = hits; j < 32; ++j) outp[j] = fh;
}

// ---------------------------------------------------------------------------
// SA1 grouping + MLP(6->64->64->128) + max. (unchanged from round 4)
// ---------------------------------------------------------------------------
__global__ __launch_bounds__(256) void k_sa1(const float* __restrict__ x,
                                             const float* __restrict__ nxyz1,
                                             const int* __restrict__ idx1,
                                             const float* __restrict__ w0, const float* __restrict__ b0,
                                             const float* __restrict__ w1, const float* __restrict__ b1,
                                             const float* __restrict__ w2, const float* __restrict__ b2,
                                             float* __restrict__ f1) {
  int c = blockIdx.x;           // 0..65535
  int b = c >> 5;
  int t = threadIdx.x;
  __shared__ float h0[32][6];
  __shared__ float h1[32][64];
  __shared__ float h2[32][64];
  __shared__ float pm[4][128];
  const float* cloud = x + (size_t)b * NPTS * 6;
  const int* idx = idx1 + (size_t)c * 32;
  if (t < 192) {
    int samp = t / 6, d = t - samp * 6;
    int pt = idx[samp];
    float v = cloud[pt * 6 + d];
    if (d < 3) v -= nxyz1[c * 3 + d];
    h0[samp][d] = v;
  }
  __syncthreads();
  {
    int oc = t & 63, sg = t >> 6;
    float acc[8];
    float bb = b0[oc];
    #pragma unroll
    for (int k = 0; k < 8; ++k) acc[k] = bb;
    for (int d = 0; d < 6; ++d) {
      float wv = w0[d * 64 + oc];
      #pragma unroll
      for (int k = 0; k < 8; ++k) acc[k] = fmaf(h0[sg * 8 + k][d], wv, acc[k]);
    }
    #pragma unroll
    for (int k = 0; k < 8; ++k) h1[sg * 8 + k][oc] = fmaxf(acc[k] * BN_SCALE, 0.f);
  }
  __syncthreads();
  {
    int op = t & 31, sg = t >> 5;
    float acc0[4], acc1[4];
    float bb0 = b1[op], bb1 = b1[op + 32];
    #pragma unroll
    for (int k = 0; k < 4; ++k) { acc0[k] = bb0; acc1[k] = bb1; }
    for (int d4 = 0; d4 < 16; ++d4) {
      int d = d4 * 4;
      float wa0 = w1[(d + 0) * 64 + op], wa1 = w1[(d + 0) * 64 + op + 32];
      float wb0 = w1[(d + 1) * 64 + op], wb1 = w1[(d + 1) * 64 + op + 32];
      float wc0 = w1[(d + 2) * 64 + op], wc1 = w1[(d + 2) * 64 + op + 32];
      float wd0 = w1[(d + 3) * 64 + op], wd1 = w1[(d + 3) * 64 + op + 32];
      #pragma unroll
      for (int k = 0; k < 4; ++k) {
        float4 h4 = *reinterpret_cast<const float4*>(&h1[sg * 4 + k][d]);
        acc0[k] = fmaf(h4.x, wa0, acc0[k]); acc0[k] = fmaf(h4.y, wb0, acc0[k]);
        acc0[k] = fmaf(h4.z, wc0, acc0[k]); acc0[k] = fmaf(h4.w, wd0, acc0[k]);
        acc1[k] = fmaf(h4.x, wa1, acc1[k]); acc1[k] = fmaf(h4.y, wb1, acc1[k]);
        acc1[k] = fmaf(h4.z, wc1, acc1[k]); acc1[k] = fmaf(h4.w, wd1, acc1[k]);
      }
    }
    #pragma unroll
    for (int k = 0; k < 4; ++k) {
      h2[sg * 4 + k][op]      = fmaxf(acc0[k] * BN_SCALE, 0.f);
      h2[sg * 4 + k][op + 32] = fmaxf(acc1[k] * BN_SCALE, 0.f);
    }
  }
  __syncthreads();
  {
    int op = t & 63, sg = t >> 6;
    float acc0[8], acc1[8];
    float bb0 = b2[op], bb1 = b2[op + 64];
    #pragma unroll
    for (int k = 0; k < 8; ++k) { acc0[k] = bb0; acc1[k] = bb1; }
    for (int d4 = 0; d4 < 16; ++d4) {
      int d = d4 * 4;
      float wa0 = w2[(d + 0) * 128 + op], wa1 = w2[(d + 0) * 128 + op + 64];
      float wb0 = w2[(d + 1) * 128 + op], wb1 = w2[(d + 1) * 128 + op + 64];
      float wc0 = w2[(d + 2) * 128 + op], wc1 = w2[(d + 2) * 128 + op + 64];
      float wd0 = w2[(d + 3) * 128 + op], wd1 = w2[(d + 3) * 128 + op + 64];
      #pragma unroll
      for (int k = 0; k < 8; ++k) {
        float4 h4 = *reinterpret_cast<const float4*>(&h2[sg * 8 + k][d]);
        acc0[k] = fmaf(h4.x, wa0, acc0[k]); acc0[k] = fmaf(h4.y, wb0, acc0[k]);
        acc0[k] = fmaf(h4.z, wc0, acc0[k]); acc0[k] = fmaf(h4.w, wd0, acc0[k]);
        acc1[k] = fmaf(h4.x, wa1, acc1[k]); acc1[k] = fmaf(h4.y, wb1, acc1[k]);
        acc1[k] = fmaf(h4.z, wc1, acc1[k]); acc1[k] = fmaf(h4.w, wd1, acc1[k]);
      }
    }
    float m0 = 0.f, m1 = 0.f;
    #pragma unroll
    for (int k = 0; k < 8; ++k) {
      m0 = fmaxf(m0, fmaxf(acc0[k] * BN_SCALE, 0.f));
      m1 = fmaxf(m1, fmaxf(acc1[k] * BN_SCALE, 0.f));
    }
    pm[sg][op] = m0; pm[sg][op + 64] = m1;
  }
  __syncthreads();
  if (t < 128) {
    float m = fmaxf(fmaxf(pm[0][t], pm[1][t]), fmaxf(pm[2][t], pm[3][t]));
    f1[(size_t)c * 128 + t] = m;
  }
}

// ---------------------------------------------------------------------------
// FPS over 32 centers -> 16. One wave per cloud. (unchanged)
// ---------------------------------------------------------------------------
__global__ __launch_bounds__(64) void k_fps2(const float* __restrict__ nxyz1,
                                             float* __restrict__ nxyz2) {
  int b = blockIdx.x;
  int t = threadIdx.x;
  const float* pts = nxyz1 + (size_t)b * 96;
  float ppx = 0.f, ppy = 0.f, ppz = 0.f, dist = -1.f;
  if (t < 32) { ppx = pts[t * 3]; ppy = pts[t * 3 + 1]; ppz = pts[t * 3 + 2]; dist = 1e10f; }
  if (t == 0) {
    nxyz2[(size_t)b * 48 + 0] = ppx;
    nxyz2[(size_t)b * 48 + 1] = ppy;
    nxyz2[(size_t)b * 48 + 2] = ppz;
  }
  int last = 0;
  for (int s = 1; s < 16; ++s) {
    float lx = __shfl(ppx, last), ly = __shfl(ppy, last), lz = __shfl(ppz, last);
    if (t < 32) {
      float dx = __fsub_rn(ppx, lx);
      float dy = __fsub_rn(ppy, ly);
      float dz = __fsub_rn(ppz, lz);
      dist = fminf(dist, sq3(dx, dy, dz));
    }
    float bv = dist; int bi = (t < 32) ? t : 1000;
    for (int off = 32; off; off >>= 1) {
      float ov = __shfl_xor(bv, off);
      int   oi = __shfl_xor(bi, off);
      if (ov > bv || (ov == bv && oi < bi)) { bv = ov; bi = oi; }
    }
    last = bi;
    float bx = __shfl(ppx, last), by = __shfl(ppy, last), bz = __shfl(ppz, last);
    if (t == 0) {
      nxyz2[(size_t)b * 48 + s * 3 + 0] = bx;
      nxyz2[(size_t)b * 48 + s * 3 + 1] = by;
      nxyz2[(size_t)b * 48 + s * 3 + 2] = bz;
    }
  }
}

// ---------------------------------------------------------------------------
// Ball query SA2 (unchanged).
// ---------------------------------------------------------------------------
__global__ __launch_bounds__(256) void k_bq2(const float* __restrict__ nxyz1,
                                             const float* __restrict__ nxyz2,
                                             int* __restrict__ idx2) {
  int c = blockIdx.x * 256 + threadIdx.x;
  if (c >= NB * 16) return;
  int b = c >> 4;
  const float* pts = nxyz1 + (size_t)b * 96;
  float cx = nxyz2[c * 3 + 0], cy = nxyz2[c * 3 + 1], cz = nxyz2[c * 3 + 2];
  float sqc = sq3(cx, cy, cz);
  const float r2 = (float)(0.4 * 0.4);
  int hits = 0, fh = 31;
  int* outp = idx2 + (size_t)c * 32;
  for (int i = 0; i < 32; ++i) {
    float ppx = pts[i * 3], ppy = pts[i * 3 + 1], ppz = pts[i * 3 + 2];
    float sqp = sq3(ppx, ppy, ppz);
    float dt  = __fadd_rn(__fadd_rn(__fmul_rn(cx, ppx), __fmul_rn(cy, ppy)), __fmul_rn(cz, ppz));
    float d2  = __fsub_rn(__fadd_rn(sqc, sqp), __fmul_rn(2.0f, dt));
    if (d2 < r2) { if (hits == 0) fh = i; outp[hits++] = i; }
  }
  for (int j = hits; j < 32; ++j) outp[j] = fh;
}

// ---------------------------------------------------------------------------
// Weight prep for SA2 MFMA: w2_* (fp32, [K][N]) -> fragment-major hi/lo bf16.
// Layout: [nt][kt][{hi,lo}][lane 0..63][elem 0..7], elem e of lane l covers
//   k = kt*32 + (l>>4)*8 + e, col = nt*16 + (l&15); zero-padded for k >= Kreal.
// ---------------------------------------------------------------------------
__global__ __launch_bounds__(256) void k_prep(const float* __restrict__ w0,
                                              const float* __restrict__ w1,
                                              const float* __restrict__ w2,
                                              short* __restrict__ wt0,
                                              short* __restrict__ wt1,
                                              short* __restrict__ wt2) {
  int p = blockIdx.x * 256 + threadIdx.x;
  const int S1 = 8 * 5 * 512, S2 = 8 * 4 * 512, S3 = 16 * 4 * 512;
  const float* src; short* dst; int KT, Kreal, N; int q;
  if (p < S1)           { q = p;           src = w0; dst = wt0; KT = 5; Kreal = 131; N = 128; }
  else if (p < S1 + S2) { q = p - S1;      src = w1; dst = wt1; KT = 4; Kreal = 128; N = 128; }
  else if (p < S1 + S2 + S3) { q = p - S1 - S2; src = w2; dst = wt2; KT = 4; Kreal = 128; N = 256; }
  else return;
  int nt = q / (KT * 512);
  int r  = q - nt * (KT * 512);
  int kt = r >> 9;
  int e  = r & 511;
  int l = e >> 3, i = e & 7;
  int k = kt * 32 + ((l >> 4) << 3) + i;
  int col = nt * 16 + (l & 15);
  float v = (k < Kreal) ? src[(size_t)k * N + col] : 0.f;
  short hi, lo;
  bf16split(v, hi, lo);
  size_t base = ((size_t)(nt * KT + kt) * 2) * 512 + e;
  dst[base] = hi;
  dst[base + 512] = lo;
}

// ---------------------------------------------------------------------------
// SA2 MFMA GEMM helper: per-wave tile set = NTL ntiles x 4 mtiles, K = KT*32.
// A from LDS (hi/lo, pitch PA shorts), B from prepped global frags.
// 3-term split: hi*Whi + hi*Wlo + lo*Whi.
// ---------------------------------------------------------------------------
template<int NTL, int KT, int PA>
__device__ __forceinline__ void mfma_gemm(const short* Ahi, const short* Alo,
                                          const short* __restrict__ wt,
                                          int w, int l, int lrow, int lk,
                                          f32x4 acc[][4]) {
  for (int kt = 0; kt < KT; ++kt) {
    bh8 ahi[4], alo[4];
    #pragma unroll
    for (int mt = 0; mt < 4; ++mt) {
      int aoff = (mt * 16 + lrow) * PA + kt * 32 + lk;
      ahi[mt] = *(const bh8*)(Ahi + aoff);
      alo[mt] = *(const bh8*)(Alo + aoff);
    }
    #pragma unroll
    for (int ntl = 0; ntl < NTL; ++ntl) {
      int nt = w * NTL + ntl;
      bh8 bhi = *(const bh8*)(wt + (size_t)((nt * KT + kt) * 2 + 0) * 512 + l * 8);
      bh8 blo = *(const bh8*)(wt + (size_t)((nt * KT + kt) * 2 + 1) * 512 + l * 8);
      #pragma unroll
      for (int mt = 0; mt < 4; ++mt) {
        acc[ntl][mt] = __builtin_amdgcn_mfma_f32_16x16x32_bf16(ahi[mt], bhi, acc[ntl][mt], 0, 0, 0);
        acc[ntl][mt] = __builtin_amdgcn_mfma_f32_16x16x32_bf16(ahi[mt], blo, acc[ntl][mt], 0, 0, 0);
        acc[ntl][mt] = __builtin_amdgcn_mfma_f32_16x16x32_bf16(alo[mt], bhi, acc[ntl][mt], 0, 0, 0);
      }
    }
  }
}

// Epilogue for GEMM1/2: bias+BN+relu, split to hi/lo, store to LDS [64][136].
template<int NTL>
__device__ __forceinline__ void epi_mid(f32x4 acc[][4], const float* __restrict__ bias,
                                        short* Dhi, short* Dlo,
                                        int w, int lrow, int lhi4) {
  #pragma unroll
  for (int ntl = 0; ntl < NTL; ++ntl) {
    int col = (w * NTL + ntl) * 16 + lrow;
    float bv = bias[col];
    #pragma unroll
    for (int mt = 0; mt < 4; ++mt) {
      #pragma unroll
      for (int r = 0; r < 4; ++r) {
        int row = mt * 16 + lhi4 + r;
        float o = fmaxf((acc[ntl][mt][r] + bv) * BN_SCALE, 0.f);
        short hi, lo;
        bf16split(o, hi, lo);
        Dhi[row * 136 + col] = hi;
        Dlo[row * 136 + col] = lo;
      }
    }
  }
}

// ---------------------------------------------------------------------------
// SA2: 2 centers per block (M=64). MLP(131->128->128->256) via split-bf16 MFMA,
// folded per-center column max -> f2.
// ---------------------------------------------------------------------------
__global__ __launch_bounds__(256, 2) void k_sa2(const float* __restrict__ nxyz1,
                                                const float* __restrict__ nxyz2,
                                                const int* __restrict__ idx2,
                                                const float* __restrict__ f1,
                                                const short* __restrict__ wt0,
                                                const short* __restrict__ wt1,
                                                const short* __restrict__ wt2,
                                                const float* __restrict__ b0g,
                                                const float* __restrict__ b1g,
                                                const float* __restrict__ b2g,
                                                float* __restrict__ f2) {
  int c2 = blockIdx.x;   // 0..16383, covers centers 2*c2, 2*c2+1
  int t  = threadIdx.x;
  __shared__ __align__(16) short lds[38912];
  __shared__ int pts[64];
  short* h0hi = lds;             // [64][168]
  short* h0lo = lds + 10752;
  short* h1hi = lds + 21504;     // [64][136]
  short* h1lo = lds + 30208;
  short* h2hi = lds;             // [64][136] overlays h0hi
  short* h2lo = lds + 10752;     // overlays h0lo

  // (a) point indices + zero K-pad (cols 131..159)
  if (t < 64) {
    int g = t >> 5, samp = t & 31;
    pts[t] = idx2[(size_t)(c2 * 2 + g) * 32 + samp];
  }
  for (int j = t; j < 64 * 29; j += 256) {
    int s = j / 29, d = 131 + (j - s * 29);
    h0hi[s * 168 + d] = 0;
    h0lo[s * 168 + d] = 0;
  }
  __syncthreads();

  // (b) gather h0 = [gx(3) | f1(128)] as hi/lo bf16
  for (int j = t; j < 192; j += 256) {
    int s = j / 3, d = j - (j / 3) * 3;
    int g = s >> 5; int c = c2 * 2 + g; int b = c >> 4;
    int pt = pts[s];
    float v = nxyz1[((size_t)b * 32 + pt) * 3 + d] - nxyz2[(size_t)c * 3 + d];
    short hi, lo; bf16split(v, hi, lo);
    h0hi[s * 168 + d] = hi; h0lo[s * 168 + d] = lo;
  }
  for (int j = t; j < 2048; j += 256) {
    int s = j >> 5, d4 = j & 31;
    int g = s >> 5; int c = c2 * 2 + g; int b = c >> 4;
    int pt = pts[s];
    const float4 v4 = *reinterpret_cast<const float4*>(&f1[((size_t)b * 32 + pt) * 128 + d4 * 4]);
    int base = s * 168 + 3 + d4 * 4;
    short hi, lo;
    bf16split(v4.x, hi, lo); h0hi[base + 0] = hi; h0lo[base + 0] = lo;
    bf16split(v4.y, hi, lo); h0hi[base + 1] = hi; h0lo[base + 1] = lo;
    bf16split(v4.z, hi, lo); h0hi[base + 2] = hi; h0lo[base + 2] = lo;
    bf16split(v4.w, hi, lo); h0hi[base + 3] = hi; h0lo[base + 3] = lo;
  }
  __syncthreads();

  int l = t & 63, w = t >> 6;
  int lrow = l & 15;
  int lk   = (l >> 4) << 3;
  int lhi4 = (l >> 4) << 2;
  f32x4 zz = {0.f, 0.f, 0.f, 0.f};

  // GEMM1: [64][160] x [160][128] -> h1
  {
    f32x4 acc[2][4];
    #pragma unroll
    for (int i = 0; i < 2; ++i)
      #pragma unroll
      for (int j = 0; j < 4; ++j) acc[i][j] = zz;
    mfma_gemm<2, 5, 168>(h0hi, h0lo, wt0, w, l, lrow, lk, acc);
    epi_mid<2>(acc, b0g, h1hi, h1lo, w, lrow, lhi4);
  }
  __syncthreads();

  // GEMM2: [64][128] x [128][128] -> h2 (overlays h0)
  {
    f32x4 acc[2][4];
    #pragma unroll
    for (int i = 0; i < 2; ++i)
      #pragma unroll
      for (int j = 0; j < 4; ++j) acc[i][j] = zz;
    mfma_gemm<2, 4, 136>(h1hi, h1lo, wt1, w, l, lrow, lk, acc);
    epi_mid<2>(acc, b1g, h2hi, h2lo, w, lrow, lhi4);
  }
  __syncthreads();

  // GEMM3: [64][128] x [128][256] + per-center column max -> f2
  {
    f32x4 acc[4][4];
    #pragma unroll
    for (int i = 0; i < 4; ++i)
      #pragma unroll
      for (int j = 0; j < 4; ++j) acc[i][j] = zz;
    mfma_gemm<4, 4, 136>(h2hi, h2lo, wt2, w, l, lrow, lk, acc);
    #pragma unroll
    for (int ntl = 0; ntl < 4; ++ntl) {
      int col = (w * 4 + ntl) * 16 + lrow;
      float bv = b2g[col];
      float m0 = 0.f, m1 = 0.f;
      #pragma unroll
      for (int mt = 0; mt < 4; ++mt) {
        float mm = 0.f;
        #pragma unroll
        for (int r = 0; r < 4; ++r)
          mm = fmaxf(mm, fmaxf((acc[ntl][mt][r] + bv) * BN_SCALE, 0.f));
        if (mt < 2) m0 = fmaxf(m0, mm); else m1 = fmaxf(m1, mm);
      }
      m0 = fmaxf(m0, __shfl_xor(m0, 16)); m0 = fmaxf(m0, __shfl_xor(m0, 32));
      m1 = fmaxf(m1, __shfl_xor(m1, 16)); m1 = fmaxf(m1, __shfl_xor(m1, 32));
      if (l < 16) {
        f2[(size_t)(c2 * 2 + 0) * 256 + col] = m0;
        f2[(size_t)(c2 * 2 + 1) * 256 + col] = m1;
      }
    }
  }
}

// ---------------------------------------------------------------------------
// MLP3 (259->256->512->768) over 16 rows + max + FC(768->768). (unchanged)
// ---------------------------------------------------------------------------
__global__ __launch_bounds__(256) void k_mlp3(const float* __restrict__ nxyz2,
                                              const float* __restrict__ f2,
                                              const float* __restrict__ w0, const float* __restrict__ b0,
                                              const float* __restrict__ w1, const float* __restrict__ b1,
                                              const float* __restrict__ w2, const float* __restrict__ b2,
                                              const float* __restrict__ fcw, const float* __restrict__ fcb,
                                              float* __restrict__ outp) {
  int b = blockIdx.x;
  int t = threadIdx.x;
  __shared__ float smem[12288];            // 48KB
  float* h1 = smem;                        // [16][256] at 0
  float* h0 = smem + 4096;                 // [16][260] at 16KB (dead after L1)
  float* h2 = smem + 4096;                 // [16][512] overlays h0
  float* g  = smem;                        // [768] overlays h1 after L2 done
  for (int j = t; j < 16 * 259; j += 256) {
    int s = j / 259, d = j - s * 259;
    float v = (d < 3) ? nxyz2[(size_t)b * 48 + s * 3 + d]
                      : f2[((size_t)b * 16 + s) * 256 + (d - 3)];
    h0[s * 260 + d] = v;
  }
  __syncthreads();
  {
    float acc[16];
    float bb = b0[t];
    #pragma unroll
    for (int s = 0; s < 16; ++s) acc[s] = bb;
    for (int d4 = 0; d4 < 64; ++d4) {
      int d = d4 * 4;
      float wa = w0[(d + 0) * 256 + t];
      float wb = w0[(d + 1) * 256 + t];
      float wc = w0[(d + 2) * 256 + t];
      float wd = w0[(d + 3) * 256 + t];
      #pragma unroll
      for (int s = 0; s < 16; ++s) {
        float4 h4 = *reinterpret_cast<const float4*>(&h0[s * 260 + d]);
        acc[s] = fmaf(h4.x, wa, acc[s]); acc[s] = fmaf(h4.y, wb, acc[s]);
        acc[s] = fmaf(h4.z, wc, acc[s]); acc[s] = fmaf(h4.w, wd, acc[s]);
      }
    }
    for (int d = 256; d < 259; ++d) {
      float wv = w0[d * 256 + t];
      #pragma unroll
      for (int s = 0; s < 16; ++s) acc[s] = fmaf(h0[s * 260 + d], wv, acc[s]);
    }
    #pragma unroll
    for (int s = 0; s < 16; ++s) h1[s * 256 + t] = fmaxf(acc[s] * BN_SCALE, 0.f);
  }
  __syncthreads();
  {
    float acc0[16], acc1[16];
    float ba = b1[t], bb2 = b1[t + 256];
    #pragma unroll
    for (int s = 0; s < 16; ++s) { acc0[s] = ba; acc1[s] = bb2; }
    for (int d4 = 0; d4 < 64; ++d4) {
      int d = d4 * 4;
      float wa0 = w1[(d + 0) * 512 + t],       wa1 = w1[(d + 0) * 512 + t + 256];
      float wb0 = w1[(d + 1) * 512 + t],       wb1 = w1[(d + 1) * 512 + t + 256];
      float wc0 = w1[(d + 2) * 512 + t],       wc1 = w1[(d + 2) * 512 + t + 256];
      float wd0 = w1[(d + 3) * 512 + t],       wd1 = w1[(d + 3) * 512 + t + 256];
      #pragma unroll
      for (int s = 0; s < 16; ++s) {
        float4 h4 = *reinterpret_cast<const float4*>(&h1[s * 256 + d]);
        acc0[s] = fmaf(h4.x, wa0, acc0[s]); acc0[s] = fmaf(h4.y, wb0, acc0[s]);
        acc0[s] = fmaf(h4.z, wc0, acc0[s]); acc0[s] = fmaf(h4.w, wd0, acc0[s]);
        acc1[s] = fmaf(h4.x, wa1, acc1[s]); acc1[s] = fmaf(h4.y, wb1, acc1[s]);
        acc1[s] = fmaf(h4.z, wc1, acc1[s]); acc1[s] = fmaf(h4.w, wd1, acc1[s]);
      }
    }
    __syncthreads();
    #pragma unroll
    for (int s = 0; s < 16; ++s) {
      h2[s * 512 + t]       = fmaxf(acc0[s] * BN_SCALE, 0.f);
      h2[s * 512 + t + 256] = fmaxf(acc1[s] * BN_SCALE, 0.f);
    }
  }
  __syncthreads();
  {
    float acc0[16], acc1[16], acc2[16];
    float ba = b2[t], bb2 = b2[t + 256], bc = b2[t + 512];
    #pragma unroll
    for (int s = 0; s < 16; ++s) { acc0[s] = ba; acc1[s] = bb2; acc2[s] = bc; }
    for (int d4 = 0; d4 < 128; ++d4) {
      int d = d4 * 4;
      float wA0 = w2[(size_t)(d + 0) * 768 + t], wA1 = w2[(size_t)(d + 0) * 768 + t + 256], wA2 = w2[(size_t)(d + 0) * 768 + t + 512];
      float wB0 = w2[(size_t)(d + 1) * 768 + t], wB1 = w2[(size_t)(d + 1) * 768 + t + 256], wB2 = w2[(size_t)(d + 1) * 768 + t + 512];
      float wC0 = w2[(size_t)(d + 2) * 768 + t], wC1 = w2[(size_t)(d + 2) * 768 + t + 256], wC2 = w2[(size_t)(d + 2) * 768 + t + 512];
      float wD0 = w2[(size_t)(d + 3) * 768 + t], wD1 = w2[(size_t)(d + 3) * 768 + t + 256], wD2 = w2[(size_t)(d + 3) * 768 + t + 512];
      #pragma unroll
      for (int s = 0; s < 16; ++s) {
        float4 h4 = *reinterpret_cast<const float4*>(&h2[s * 512 + d]);
        acc0[s] = fmaf(h4.x, wA0, acc0[s]); acc0[s] = fmaf(h4.y, wB0, acc0[s]);
        acc0[s] = fmaf(h4.z, wC0, acc0[s]); acc0[s] = fmaf(h4.w, wD0, acc0[s]);
        acc1[s] = fmaf(h4.x, wA1, acc1[s]); acc1[s] = fmaf(h4.y, wB1, acc1[s]);
        acc1[s] = fmaf(h4.z, wC1, acc1[s]); acc1[s] = fmaf(h4.w, wD1, acc1[s]);
        acc2[s] = fmaf(h4.x, wA2, acc2[s]); acc2[s] = fmaf(h4.y, wB2, acc2[s]);
        acc2[s] = fmaf(h4.z, wC2, acc2[s]); acc2[s] = fmaf(h4.w, wD2, acc2[s]);
      }
    }
    float m0 = 0.f, m1 = 0.f, m2 = 0.f;
    #pragma unroll
    for (int s = 0; s < 16; ++s) {
      m0 = fmaxf(m0, fmaxf(acc0[s] * BN_SCALE, 0.f));
      m1 = fmaxf(m1, fmaxf(acc1[s] * BN_SCALE, 0.f));
      m2 = fmaxf(m2, fmaxf(acc2[s] * BN_SCALE, 0.f));
    }
    __syncthreads();
    g[t] = m0; g[t + 256] = m1; g[t + 512] = m2;
  }
  __syncthreads();
  {
    float a0 = fcb[t], a1 = fcb[t + 256], a2 = fcb[t + 512];
    for (int d4 = 0; d4 < 192; ++d4) {
      int d = d4 * 4;
      float4 g4 = *reinterpret_cast<const float4*>(&g[d]);
      float wA0 = fcw[(size_t)(d + 0) * 768 + t], wA1 = fcw[(size_t)(d + 0) * 768 + t + 256], wA2 = fcw[(size_t)(d + 0) * 768 + t + 512];
      float wB0 = fcw[(size_t)(d + 1) * 768 + t], wB1 = fcw[(size_t)(d + 1) * 768 + t + 256], wB2 = fcw[(size_t)(d + 1) * 768 + t + 512];
      float wC0 = fcw[(size_t)(d + 2) * 768 + t], wC1 = fcw[(size_t)(d + 2) * 768 + t + 256], wC2 = fcw[(size_t)(d + 2) * 768 + t + 512];
      float wD0 = fcw[(size_t)(d + 3) * 768 + t], wD1 = fcw[(size_t)(d + 3) * 768 + t + 256], wD2 = fcw[(size_t)(d + 3) * 768 + t + 512];
      a0 = fmaf(g4.x, wA0, a0); a0 = fmaf(g4.y, wB0, a0); a0 = fmaf(g4.z, wC0, a0); a0 = fmaf(g4.w, wD0, a0);
      a1 = fmaf(g4.x, wA1, a1); a1 = fmaf(g4.y, wB1, a1); a1 = fmaf(g4.z, wC1, a1); a1 = fmaf(g4.w, wD1, a1);
      a2 = fmaf(g4.x, wA2, a2); a2 = fmaf(g4.y, wB2, a2); a2 = fmaf(g4.z, wC2, a2); a2 = fmaf(g4.w, wD2, a2);
    }
    outp[(size_t)b * 768 + t]       = a0;
    outp[(size_t)b * 768 + t + 256] = a1;
    outp[(size_t)b * 768 + t + 512] = a2;
  }
}

// ---------------------------------------------------------------------------
extern "C" void kernel_launch(void* const* d_in, const int* in_sizes, int n_in,
                              void* d_out, int out_size, void* d_ws, size_t ws_size,
                              hipStream_t stream) {
  const float* x    = (const float*)d_in[0];
  const float* w1_0 = (const float*)d_in[1];  const float* b1_0 = (const float*)d_in[2];
  const float* w1_1 = (const float*)d_in[3];  const float* b1_1 = (const float*)d_in[4];
  const float* w1_2 = (const float*)d_in[5];  const float* b1_2 = (const float*)d_in[6];
  const float* w2_0 = (const float*)d_in[7];  const float* b2_0 = (const float*)d_in[8];
  const float* w2_1 = (const float*)d_in[9];  const float* b2_1 = (const float*)d_in[10];
  const float* w2_2 = (const float*)d_in[11]; const float* b2_2 = (const float*)d_in[12];
  const float* w3_0 = (const float*)d_in[13]; const float* b3_0 = (const float*)d_in[14];
  const float* w3_1 = (const float*)d_in[15]; const float* b3_1 = (const float*)d_in[16];
  const float* w3_2 = (const float*)d_in[17]; const float* b3_2 = (const float*)d_in[18];
  const float* fc_w = (const float*)d_in[19]; const float* fc_b = (const float*)d_in[20];
  float* outp = (float*)d_out;

  // Workspace: floats (nxyz1,nxyz2,f1,f2) + ints (idx1,idx2) + bf16 frag weights
  const size_t n_float = (size_t)NB * 96 + (size_t)NB * 48 +
                         (size_t)NB * 32 * 128 + (size_t)NB * 16 * 256;
  const size_t n_int   = (size_t)NB * 32 * 32 + (size_t)NB * 16 * 32;
  const size_t n_short = 40960 + 32768 + 65536;
  const size_t need_bytes = n_float * 4 + n_int * 4 + n_short * 2;
  if (ws_size < need_bytes) return;

  float* nxyz1 = (float*)d_ws;
  float* nxyz2 = nxyz1 + (size_t)NB * 96;
  float* f1    = nxyz2 + (size_t)NB * 48;
  float* f2    = f1    + (size_t)NB * 32 * 128;
  int*   idx1  = (int*)(f2 + (size_t)NB * 16 * 256);
  int*   idx2  = idx1 + (size_t)NB * 32 * 32;
  short* wt0   = (short*)(idx2 + (size_t)NB * 16 * 32);
  short* wt1   = wt0 + 40960;
  short* wt2   = wt1 + 32768;

  k_prep<<<272, 256, 0, stream>>>(w2_0, w2_1, w2_2, wt0, wt1, wt2);
  k_fps1<<<NB, 256, 0, stream>>>(x, nxyz1);
  k_bq1 <<<(NB * 32) / 256, 256, 0, stream>>>(x, nxyz1, idx1);
  k_sa1 <<<NB * 32, 256, 0, stream>>>(x, nxyz1, idx1, w1_0, b1_0, w1_1, b1_1, w1_2, b1_2, f1);
  k_fps2<<<NB, 64, 0, stream>>>(nxyz1, nxyz2);
  k_bq2 <<<(NB * 16) / 256, 256, 0, stream>>>(nxyz1, nxyz2, idx2);
  k_sa2 <<<NB * 8, 256, 0, stream>>>(nxyz1, nxyz2, idx2, f1, wt0, wt1, wt2,
                                     b2_0, b2_1, b2_2, f2);
  k_mlp3<<<NB, 256, 0, stream>>>(nxyz2, f2, w3_0, b3_0, w3_1, b3_1, w3_2, b3_2,
                                 fc_w, fc_b, outp);
}

// Round 6
// 1877.494 us; speedup vs baseline: 2.5067x; 1.3014x over previous
//
#include <hip/hip_runtime.h>
#include <math.h>

#define BN_SCALE 0.999995000037499687f   // 1/sqrt(1+1e-5)
#define NPTS 1024
#define NB   2048    // 32*64 clouds

typedef __attribute__((ext_vector_type(8))) short bh8;
typedef __attribute__((ext_vector_type(4))) float f32x4;

// exact-rounding sum of 3 squares, matching XLA/NumPy's ((x*x + y*y) + z*z) without fma contraction
__device__ __forceinline__ float sq3(float x, float y, float z) {
  return __fadd_rn(__fadd_rn(__fmul_rn(x, x), __fmul_rn(y, y)), __fmul_rn(z, z));
}

// RNE f32 -> bf16 bits
__device__ __forceinline__ short bf16hi(float v) {
  unsigned u = __float_as_uint(v);
  unsigned r = (u + 0x7FFFu + ((u >> 16) & 1u)) >> 16;
  return (short)r;
}
__device__ __forceinline__ float bf16tof(short s) {
  unsigned u = ((unsigned)(unsigned short)s) << 16;
  return __uint_as_float(u);
}
__device__ __forceinline__ void bf16split(float v, short& hi, short& lo) {
  hi = bf16hi(v);
  lo = bf16hi(v - bf16tof(hi));
}

// ---------------------------------------------------------------------------
// FPS over 1024 points -> 32 centers per cloud. Bit-exact mirror of reference.
// ---------------------------------------------------------------------------
__global__ __launch_bounds__(256) void k_fps1(const float* __restrict__ x,
                                              float* __restrict__ nxyz1) {
  int b = blockIdx.x;
  const float* cloud = x + (size_t)b * NPTS * 6;
  __shared__ float px[NPTS], py[NPTS], pz[NPTS], dist[NPTS];
  __shared__ float wv_s[4];
  __shared__ int   wi_s[4];
  __shared__ int   last_s;
  int t = threadIdx.x;
  for (int i = t; i < NPTS; i += 256) {
    px[i] = cloud[i * 6 + 0];
    py[i] = cloud[i * 6 + 1];
    pz[i] = cloud[i * 6 + 2];
    dist[i] = 1e10f;
  }
  __syncthreads();
  if (t == 0) {
    nxyz1[(size_t)b * 96 + 0] = px[0];
    nxyz1[(size_t)b * 96 + 1] = py[0];
    nxyz1[(size_t)b * 96 + 2] = pz[0];
  }
  int last = 0;
  for (int s = 1; s < 32; ++s) {
    float lx = px[last], ly = py[last], lz = pz[last];
    float bv = -1.0f; int bi = NPTS;
    for (int i = t; i < NPTS; i += 256) {
      float dx = __fsub_rn(px[i], lx);
      float dy = __fsub_rn(py[i], ly);
      float dz = __fsub_rn(pz[i], lz);
      float d  = sq3(dx, dy, dz);
      float nd = fminf(dist[i], d);
      dist[i] = nd;
      if (nd > bv || (nd == bv && i < bi)) { bv = nd; bi = i; }
    }
    for (int off = 32; off; off >>= 1) {
      float ov = __shfl_down(bv, off);
      int   oi = __shfl_down(bi, off);
      if (ov > bv || (ov == bv && oi < bi)) { bv = ov; bi = oi; }
    }
    if ((t & 63) == 0) { wv_s[t >> 6] = bv; wi_s[t >> 6] = bi; }
    __syncthreads();
    if (t == 0) {
      for (int w = 1; w < 4; ++w)
        if (wv_s[w] > bv || (wv_s[w] == bv && wi_s[w] < bi)) { bv = wv_s[w]; bi = wi_s[w]; }
      last_s = bi;
      nxyz1[(size_t)b * 96 + s * 3 + 0] = px[bi];
      nxyz1[(size_t)b * 96 + s * 3 + 1] = py[bi];
      nxyz1[(size_t)b * 96 + s * 3 + 2] = pz[bi];
    }
    __syncthreads();
    last = last_s;
  }
}

// ---------------------------------------------------------------------------
// Ball query SA1 (bit-exact d2 formula).
// ---------------------------------------------------------------------------
__global__ __launch_bounds__(256) void k_bq1(const float* __restrict__ x,
                                             const float* __restrict__ nxyz1,
                                             int* __restrict__ idx1) {
  int c = blockIdx.x * 256 + threadIdx.x;
  if (c >= NB * 32) return;
  int b = c >> 5;
  const float* cloud = x + (size_t)b * NPTS * 6;
  float cx = nxyz1[c * 3 + 0], cy = nxyz1[c * 3 + 1], cz = nxyz1[c * 3 + 2];
  float sqc = sq3(cx, cy, cz);
  const float r2 = (float)(0.2 * 0.2);
  int hits = 0, fh = NPTS - 1;
  int* outp = idx1 + (size_t)c * 32;
  for (int i = 0; i < NPTS; ++i) {
    float ppx = cloud[i * 6 + 0], ppy = cloud[i * 6 + 1], ppz = cloud[i * 6 + 2];
    float sqp = sq3(ppx, ppy, ppz);
    float dt  = __fadd_rn(__fadd_rn(__fmul_rn(cx, ppx), __fmul_rn(cy, ppy)), __fmul_rn(cz, ppz));
    float d2  = __fsub_rn(__fadd_rn(sqc, sqp), __fmul_rn(2.0f, dt));
    if (d2 < r2) {
      if (hits == 0) fh = i;
      outp[hits] = i;
      if (++hits == 32) break;
    }
  }
  for (int j = hits; j < 32; ++j) outp[j] = fh;
}

// ---------------------------------------------------------------------------
// Generic weight prep: src fp32 [K][N] -> fragment-major hi/lo bf16.
// Layout: [nt][kt][{hi,lo}][lane 0..63][elem 0..7], elem e of lane l covers
//   k = kt*32 + (l>>4)*8 + e, col = nt*16 + (l&15); zero-padded for k >= Kreal.
// ---------------------------------------------------------------------------
__device__ __forceinline__ void prep_one(const float* __restrict__ src,
                                         short* __restrict__ dst,
                                         int q, int KT, int Kreal, int N) {
  int nt = q / (KT * 512);
  int r  = q - nt * (KT * 512);
  int kt = r >> 9;
  int e  = r & 511;
  int l = e >> 3, i = e & 7;
  int k = kt * 32 + ((l >> 4) << 3) + i;
  int col = nt * 16 + (l & 15);
  float v = (k < Kreal) ? src[(size_t)k * N + col] : 0.f;
  short hi, lo;
  bf16split(v, hi, lo);
  size_t base = ((size_t)(nt * KT + kt) * 2) * 512 + e;
  dst[base] = hi;
  dst[base + 512] = lo;
}

// SA2 weights: w2_0 [131][128] KT=5, w2_1 [128][128] KT=4, w2_2 [128][256] KT=4
__global__ __launch_bounds__(256) void k_prep(const float* __restrict__ w0,
                                              const float* __restrict__ w1,
                                              const float* __restrict__ w2,
                                              short* __restrict__ wt0,
                                              short* __restrict__ wt1,
                                              short* __restrict__ wt2) {
  int p = blockIdx.x * 256 + threadIdx.x;
  const int S1 = 8 * 5 * 512, S2 = 8 * 4 * 512, S3 = 16 * 4 * 512;
  if (p < S1)                 prep_one(w0, wt0, p,           5, 131, 128);
  else if (p < S1 + S2)       prep_one(w1, wt1, p - S1,      4, 128, 128);
  else if (p < S1 + S2 + S3)  prep_one(w2, wt2, p - S1 - S2, 4, 128, 256);
}

// SA1 weights: w1_0 [6][64] KT=1, w1_1 [64][64] KT=2, w1_2 [64][128] KT=2
__global__ __launch_bounds__(256) void k_prep1(const float* __restrict__ w0,
                                               const float* __restrict__ w1,
                                               const float* __restrict__ w2,
                                               short* __restrict__ wt0,
                                               short* __restrict__ wt1,
                                               short* __restrict__ wt2) {
  int p = blockIdx.x * 256 + threadIdx.x;
  const int S1 = 4 * 1 * 512, S2 = 4 * 2 * 512, S3 = 8 * 2 * 512;
  if (p < S1)                 prep_one(w0, wt0, p,           1, 6,  64);
  else if (p < S1 + S2)       prep_one(w1, wt1, p - S1,      2, 64, 64);
  else if (p < S1 + S2 + S3)  prep_one(w2, wt2, p - S1 - S2, 2, 64, 128);
}

// ---------------------------------------------------------------------------
// MFMA GEMM helper: per-wave tile set = NTL ntiles x 4 mtiles, K = KT*32.
// A from LDS (hi/lo, pitch PA shorts), B from prepped global frags.
// 3-term split: hi*Whi + hi*Wlo + lo*Whi.
// ---------------------------------------------------------------------------
template<int NTL, int KT, int PA>
__device__ __forceinline__ void mfma_gemm(const short* Ahi, const short* Alo,
                                          const short* __restrict__ wt,
                                          int w, int l, int lrow, int lk,
                                          f32x4 acc[][4]) {
  for (int kt = 0; kt < KT; ++kt) {
    bh8 ahi[4], alo[4];
    #pragma unroll
    for (int mt = 0; mt < 4; ++mt) {
      int aoff = (mt * 16 + lrow) * PA + kt * 32 + lk;
      ahi[mt] = *(const bh8*)(Ahi + aoff);
      alo[mt] = *(const bh8*)(Alo + aoff);
    }
    #pragma unroll
    for (int ntl = 0; ntl < NTL; ++ntl) {
      int nt = w * NTL + ntl;
      bh8 bhi = *(const bh8*)(wt + (size_t)((nt * KT + kt) * 2 + 0) * 512 + l * 8);
      bh8 blo = *(const bh8*)(wt + (size_t)((nt * KT + kt) * 2 + 1) * 512 + l * 8);
      #pragma unroll
      for (int mt = 0; mt < 4; ++mt) {
        acc[ntl][mt] = __builtin_amdgcn_mfma_f32_16x16x32_bf16(ahi[mt], bhi, acc[ntl][mt], 0, 0, 0);
        acc[ntl][mt] = __builtin_amdgcn_mfma_f32_16x16x32_bf16(ahi[mt], blo, acc[ntl][mt], 0, 0, 0);
        acc[ntl][mt] = __builtin_amdgcn_mfma_f32_16x16x32_bf16(alo[mt], bhi, acc[ntl][mt], 0, 0, 0);
      }
    }
  }
}

// Epilogue for mid layers: bias+BN+relu, split hi/lo, store to LDS (pitch PD).
template<int NTL, int PD>
__device__ __forceinline__ void epi_mid(f32x4 acc[][4], const float* __restrict__ bias,
                                        short* Dhi, short* Dlo,
                                        int w, int lrow, int lhi4) {
  #pragma unroll
  for (int ntl = 0; ntl < NTL; ++ntl) {
    int col = (w * NTL + ntl) * 16 + lrow;
    float bv = bias[col];
    #pragma unroll
    for (int mt = 0; mt < 4; ++mt) {
      #pragma unroll
      for (int r = 0; r < 4; ++r) {
        int row = mt * 16 + lhi4 + r;
        float o = fmaxf((acc[ntl][mt][r] + bv) * BN_SCALE, 0.f);
        short hi, lo;
        bf16split(o, hi, lo);
        Dhi[row * PD + col] = hi;
        Dlo[row * PD + col] = lo;
      }
    }
  }
}

// Final epilogue: bias+BN+relu, per-center (rows 0..31 / 32..63) column max -> out.
template<int NTL>
__device__ __forceinline__ void epi_max(f32x4 acc[][4], const float* __restrict__ bias,
                                        float* __restrict__ outA, float* __restrict__ outB,
                                        int w, int l, int lrow) {
  #pragma unroll
  for (int ntl = 0; ntl < NTL; ++ntl) {
    int col = (w * NTL + ntl) * 16 + lrow;
    float bv = bias[col];
    float m0 = 0.f, m1 = 0.f;
    #pragma unroll
    for (int mt = 0; mt < 4; ++mt) {
      float mm = 0.f;
      #pragma unroll
      for (int r = 0; r < 4; ++r)
        mm = fmaxf(mm, fmaxf((acc[ntl][mt][r] + bv) * BN_SCALE, 0.f));
      if (mt < 2) m0 = fmaxf(m0, mm); else m1 = fmaxf(m1, mm);
    }
    m0 = fmaxf(m0, __shfl_xor(m0, 16)); m0 = fmaxf(m0, __shfl_xor(m0, 32));
    m1 = fmaxf(m1, __shfl_xor(m1, 16)); m1 = fmaxf(m1, __shfl_xor(m1, 32));
    if (l < 16) {
      outA[col] = m0;
      outB[col] = m1;
    }
  }
}

// ---------------------------------------------------------------------------
// SA1: 2 centers per block (M=64). MLP(6->64->64->128) via split-bf16 MFMA,
// folded per-center column max -> f1.
// ---------------------------------------------------------------------------
__global__ __launch_bounds__(256) void k_sa1(const float* __restrict__ x,
                                             const float* __restrict__ nxyz1,
                                             const int* __restrict__ idx1,
                                             const short* __restrict__ wt0,
                                             const short* __restrict__ wt1,
                                             const short* __restrict__ wt2,
                                             const float* __restrict__ b0g,
                                             const float* __restrict__ b1g,
                                             const float* __restrict__ b2g,
                                             float* __restrict__ f1) {
  int c2 = blockIdx.x;   // 0..32767, covers centers 2*c2, 2*c2+1
  int t  = threadIdx.x;
  __shared__ __align__(16) short lds[18432];   // 4 x 4608-short buffers
  __shared__ int pts[64];
  short* h0hi = lds;             // [64][40] (K=32 padded), within 4608
  short* h0lo = lds + 4608;
  short* h1hi = lds + 9216;      // [64][72] (K=64)
  short* h1lo = lds + 13824;
  short* h2hi = lds;             // [64][72] overlays h0hi
  short* h2lo = lds + 4608;      // overlays h0lo

  // (a) point indices
  if (t < 64) {
    int g = t >> 5, samp = t & 31;
    pts[t] = idx1[(size_t)(c2 * 2 + g) * 32 + samp];
  }
  // zero K-pad: cols 6..39 of h0 (pitch 40)
  for (int j = t; j < 64 * 34; j += 256) {
    int s = j / 34, d = 6 + (j - s * 34);
    h0hi[s * 40 + d] = 0;
    h0lo[s * 40 + d] = 0;
  }
  __syncthreads();

  // (b) gather h0 = [gx(3) | feats(3)] hi/lo
  for (int j = t; j < 384; j += 256) {
    int s = j / 6, d = j - (j / 6) * 6;
    int g = s >> 5; int c = c2 * 2 + g; int b = c >> 5;
    int pt = pts[s];
    float v = x[((size_t)b * NPTS + pt) * 6 + d];
    if (d < 3) v -= nxyz1[(size_t)c * 3 + d];
    short hi, lo; bf16split(v, hi, lo);
    h0hi[s * 40 + d] = hi; h0lo[s * 40 + d] = lo;
  }
  __syncthreads();

  int l = t & 63, w = t >> 6;
  int lrow = l & 15;
  int lk   = (l >> 4) << 3;
  int lhi4 = (l >> 4) << 2;
  f32x4 zz = {0.f, 0.f, 0.f, 0.f};

  // GEMM1: [64][32] x [32][64] -> h1
  {
    f32x4 acc[1][4];
    #pragma unroll
    for (int j = 0; j < 4; ++j) acc[0][j] = zz;
    mfma_gemm<1, 1, 40>(h0hi, h0lo, wt0, w, l, lrow, lk, acc);
    epi_mid<1, 72>(acc, b0g, h1hi, h1lo, w, lrow, lhi4);
  }
  __syncthreads();

  // GEMM2: [64][64] x [64][64] -> h2 (overlays h0)
  {
    f32x4 acc[1][4];
    #pragma unroll
    for (int j = 0; j < 4; ++j) acc[0][j] = zz;
    mfma_gemm<1, 2, 72>(h1hi, h1lo, wt1, w, l, lrow, lk, acc);
    epi_mid<1, 72>(acc, b1g, h2hi, h2lo, w, lrow, lhi4);
  }
  __syncthreads();

  // GEMM3: [64][64] x [64][128] + per-center column max -> f1
  {
    f32x4 acc[2][4];
    #pragma unroll
    for (int i = 0; i < 2; ++i)
      #pragma unroll
      for (int j = 0; j < 4; ++j) acc[i][j] = zz;
    mfma_gemm<2, 2, 72>(h2hi, h2lo, wt2, w, l, lrow, lk, acc);
    epi_max<2>(acc, b2g,
               f1 + (size_t)(c2 * 2 + 0) * 128,
               f1 + (size_t)(c2 * 2 + 1) * 128,
               w, l, lrow);
  }
}

// ---------------------------------------------------------------------------
// FPS over 32 centers -> 16. One wave per cloud. (unchanged)
// ---------------------------------------------------------------------------
__global__ __launch_bounds__(64) void k_fps2(const float* __restrict__ nxyz1,
                                             float* __restrict__ nxyz2) {
  int b = blockIdx.x;
  int t = threadIdx.x;
  const float* pts = nxyz1 + (size_t)b * 96;
  float ppx = 0.f, ppy = 0.f, ppz = 0.f, dist = -1.f;
  if (t < 32) { ppx = pts[t * 3]; ppy = pts[t * 3 + 1]; ppz = pts[t * 3 + 2]; dist = 1e10f; }
  if (t == 0) {
    nxyz2[(size_t)b * 48 + 0] = ppx;
    nxyz2[(size_t)b * 48 + 1] = ppy;
    nxyz2[(size_t)b * 48 + 2] = ppz;
  }
  int last = 0;
  for (int s = 1; s < 16; ++s) {
    float lx = __shfl(ppx, last), ly = __shfl(ppy, last), lz = __shfl(ppz, last);
    if (t < 32) {
      float dx = __fsub_rn(ppx, lx);
      float dy = __fsub_rn(ppy, ly);
      float dz = __fsub_rn(ppz, lz);
      dist = fminf(dist, sq3(dx, dy, dz));
    }
    float bv = dist; int bi = (t < 32) ? t : 1000;
    for (int off = 32; off; off >>= 1) {
      float ov = __shfl_xor(bv, off);
      int   oi = __shfl_xor(bi, off);
      if (ov > bv || (ov == bv && oi < bi)) { bv = ov; bi = oi; }
    }
    last = bi;
    float bx = __shfl(ppx, last), by = __shfl(ppy, last), bz = __shfl(ppz, last);
    if (t == 0) {
      nxyz2[(size_t)b * 48 + s * 3 + 0] = bx;
      nxyz2[(size_t)b * 48 + s * 3 + 1] = by;
      nxyz2[(size_t)b * 48 + s * 3 + 2] = bz;
    }
  }
}

// ---------------------------------------------------------------------------
// Ball query SA2 (unchanged).
// ---------------------------------------------------------------------------
__global__ __launch_bounds__(256) void k_bq2(const float* __restrict__ nxyz1,
                                             const float* __restrict__ nxyz2,
                                             int* __restrict__ idx2) {
  int c = blockIdx.x * 256 + threadIdx.x;
  if (c >= NB * 16) return;
  int b = c >> 4;
  const float* pts = nxyz1 + (size_t)b * 96;
  float cx = nxyz2[c * 3 + 0], cy = nxyz2[c * 3 + 1], cz = nxyz2[c * 3 + 2];
  float sqc = sq3(cx, cy, cz);
  const float r2 = (float)(0.4 * 0.4);
  int hits = 0, fh = 31;
  int* outp = idx2 + (size_t)c * 32;
  for (int i = 0; i < 32; ++i) {
    float ppx = pts[i * 3], ppy = pts[i * 3 + 1], ppz = pts[i * 3 + 2];
    float sqp = sq3(ppx, ppy, ppz);
    float dt  = __fadd_rn(__fadd_rn(__fmul_rn(cx, ppx), __fmul_rn(cy, ppy)), __fmul_rn(cz, ppz));
    float d2  = __fsub_rn(__fadd_rn(sqc, sqp), __fmul_rn(2.0f, dt));
    if (d2 < r2) { if (hits == 0) fh = i; outp[hits++] = i; }
  }
  for (int j = hits; j < 32; ++j) outp[j] = fh;
}

// ---------------------------------------------------------------------------
// SA2: 2 centers per block (M=64). MLP(131->128->128->256) via split-bf16 MFMA,
// folded per-center column max -> f2. (unchanged from round 5 except epi templates)
// ---------------------------------------------------------------------------
__global__ __launch_bounds__(256, 2) void k_sa2(const float* __restrict__ nxyz1,
                                                const float* __restrict__ nxyz2,
                                                const int* __restrict__ idx2,
                                                const float* __restrict__ f1,
                                                const short* __restrict__ wt0,
                                                const short* __restrict__ wt1,
                                                const short* __restrict__ wt2,
                                                const float* __restrict__ b0g,
                                                const float* __restrict__ b1g,
                                                const float* __restrict__ b2g,
                                                float* __restrict__ f2) {
  int c2 = blockIdx.x;   // 0..16383, covers centers 2*c2, 2*c2+1
  int t  = threadIdx.x;
  __shared__ __align__(16) short lds[38912];
  __shared__ int pts[64];
  short* h0hi = lds;             // [64][168]
  short* h0lo = lds + 10752;
  short* h1hi = lds + 21504;     // [64][136]
  short* h1lo = lds + 30208;
  short* h2hi = lds;             // [64][136] overlays h0hi
  short* h2lo = lds + 10752;     // overlays h0lo

  if (t < 64) {
    int g = t >> 5, samp = t & 31;
    pts[t] = idx2[(size_t)(c2 * 2 + g) * 32 + samp];
  }
  for (int j = t; j < 64 * 29; j += 256) {
    int s = j / 29, d = 131 + (j - s * 29);
    h0hi[s * 168 + d] = 0;
    h0lo[s * 168 + d] = 0;
  }
  __syncthreads();

  for (int j = t; j < 192; j += 256) {
    int s = j / 3, d = j - (j / 3) * 3;
    int g = s >> 5; int c = c2 * 2 + g; int b = c >> 4;
    int pt = pts[s];
    float v = nxyz1[((size_t)b * 32 + pt) * 3 + d] - nxyz2[(size_t)c * 3 + d];
    short hi, lo; bf16split(v, hi, lo);
    h0hi[s * 168 + d] = hi; h0lo[s * 168 + d] = lo;
  }
  for (int j = t; j < 2048; j += 256) {
    int s = j >> 5, d4 = j & 31;
    int g = s >> 5; int c = c2 * 2 + g; int b = c >> 4;
    int pt = pts[s];
    const float4 v4 = *reinterpret_cast<const float4*>(&f1[((size_t)b * 32 + pt) * 128 + d4 * 4]);
    int base = s * 168 + 3 + d4 * 4;
    short hi, lo;
    bf16split(v4.x, hi, lo); h0hi[base + 0] = hi; h0lo[base + 0] = lo;
    bf16split(v4.y, hi, lo); h0hi[base + 1] = hi; h0lo[base + 1] = lo;
    bf16split(v4.z, hi, lo); h0hi[base + 2] = hi; h0lo[base + 2] = lo;
    bf16split(v4.w, hi, lo); h0hi[base + 3] = hi; h0lo[base + 3] = lo;
  }
  __syncthreads();

  int l = t & 63, w = t >> 6;
  int lrow = l & 15;
  int lk   = (l >> 4) << 3;
  int lhi4 = (l >> 4) << 2;
  f32x4 zz = {0.f, 0.f, 0.f, 0.f};

  // GEMM1: [64][160] x [160][128] -> h1
  {
    f32x4 acc[2][4];
    #pragma unroll
    for (int i = 0; i < 2; ++i)
      #pragma unroll
      for (int j = 0; j < 4; ++j) acc[i][j] = zz;
    mfma_gemm<2, 5, 168>(h0hi, h0lo, wt0, w, l, lrow, lk, acc);
    epi_mid<2, 136>(acc, b0g, h1hi, h1lo, w, lrow, lhi4);
  }
  __syncthreads();

  // GEMM2: [64][128] x [128][128] -> h2 (overlays h0)
  {
    f32x4 acc[2][4];
    #pragma unroll
    for (int i = 0; i < 2; ++i)
      #pragma unroll
      for (int j = 0; j < 4; ++j) acc[i][j] = zz;
    mfma_gemm<2, 4, 136>(h1hi, h1lo, wt1, w, l, lrow, lk, acc);
    epi_mid<2, 136>(acc, b1g, h2hi, h2lo, w, lrow, lhi4);
  }
  __syncthreads();

  // GEMM3: [64][128] x [128][256] + per-center column max -> f2
  {
    f32x4 acc[4][4];
    #pragma unroll
    for (int i = 0; i < 4; ++i)
      #pragma unroll
      for (int j = 0; j < 4; ++j) acc[i][j] = zz;
    mfma_gemm<4, 4, 136>(h2hi, h2lo, wt2, w, l, lrow, lk, acc);
    epi_max<4>(acc, b2g,
               f2 + (size_t)(c2 * 2 + 0) * 256,
               f2 + (size_t)(c2 * 2 + 1) * 256,
               w, l, lrow);
  }
}

// ---------------------------------------------------------------------------
// MLP3 (259->256->512->768) over 16 rows + max + FC(768->768). (unchanged)
// ---------------------------------------------------------------------------
__global__ __launch_bounds__(256) void k_mlp3(const float* __restrict__ nxyz2,
                                              const float* __restrict__ f2,
                                              const float* __restrict__ w0, const float* __restrict__ b0,
                                              const float* __restrict__ w1, const float* __restrict__ b1,
                                              const float* __restrict__ w2, const float* __restrict__ b2,
                                              const float* __restrict__ fcw, const float* __restrict__ fcb,
                                              float* __restrict__ outp) {
  int b = blockIdx.x;
  int t = threadIdx.x;
  __shared__ float smem[12288];            // 48KB
  float* h1 = smem;                        // [16][256] at 0
  float* h0 = smem + 4096;                 // [16][260] at 16KB (dead after L1)
  float* h2 = smem + 4096;                 // [16][512] overlays h0
  float* g  = smem;                        // [768] overlays h1 after L2 done
  for (int j = t; j < 16 * 259; j += 256) {
    int s = j / 259, d = j - s * 259;
    float v = (d < 3) ? nxyz2[(size_t)b * 48 + s * 3 + d]
                      : f2[((size_t)b * 16 + s) * 256 + (d - 3)];
    h0[s * 260 + d] = v;
  }
  __syncthreads();
  {
    float acc[16];
    float bb = b0[t];
    #pragma unroll
    for (int s = 0; s < 16; ++s) acc[s] = bb;
    for (int d4 = 0; d4 < 64; ++d4) {
      int d = d4 * 4;
      float wa = w0[(d + 0) * 256 + t];
      float wb = w0[(d + 1) * 256 + t];
      float wc = w0[(d + 2) * 256 + t];
      float wd = w0[(d + 3) * 256 + t];
      #pragma unroll
      for (int s = 0; s < 16; ++s) {
        float4 h4 = *reinterpret_cast<const float4*>(&h0[s * 260 + d]);
        acc[s] = fmaf(h4.x, wa, acc[s]); acc[s] = fmaf(h4.y, wb, acc[s]);
        acc[s] = fmaf(h4.z, wc, acc[s]); acc[s] = fmaf(h4.w, wd, acc[s]);
      }
    }
    for (int d = 256; d < 259; ++d) {
      float wv = w0[d * 256 + t];
      #pragma unroll
      for (int s = 0; s < 16; ++s) acc[s] = fmaf(h0[s * 260 + d], wv, acc[s]);
    }
    #pragma unroll
    for (int s = 0; s < 16; ++s) h1[s * 256 + t] = fmaxf(acc[s] * BN_SCALE, 0.f);
  }
  __syncthreads();
  {
    float acc0[16], acc1[16];
    float ba = b1[t], bb2 = b1[t + 256];
    #pragma unroll
    for (int s = 0; s < 16; ++s) { acc0[s] = ba; acc1[s] = bb2; }
    for (int d4 = 0; d4 < 64; ++d4) {
      int d = d4 * 4;
      float wa0 = w1[(d + 0) * 512 + t],       wa1 = w1[(d + 0) * 512 + t + 256];
      float wb0 = w1[(d + 1) * 512 + t],       wb1 = w1[(d + 1) * 512 + t + 256];
      float wc0 = w1[(d + 2) * 512 + t],       wc1 = w1[(d + 2) * 512 + t + 256];
      float wd0 = w1[(d + 3) * 512 + t],       wd1 = w1[(d + 3) * 512 + t + 256];
      #pragma unroll
      for (int s = 0; s < 16; ++s) {
        float4 h4 = *reinterpret_cast<const float4*>(&h1[s * 256 + d]);
        acc0[s] = fmaf(h4.x, wa0, acc0[s]); acc0[s] = fmaf(h4.y, wb0, acc0[s]);
        acc0[s] = fmaf(h4.z, wc0, acc0[s]); acc0[s] = fmaf(h4.w, wd0, acc0[s]);
        acc1[s] = fmaf(h4.x, wa1, acc1[s]); acc1[s] = fmaf(h4.y, wb1, acc1[s]);
        acc1[s] = fmaf(h4.z, wc1, acc1[s]); acc1[s] = fmaf(h4.w, wd1, acc1[s]);
      }
    }
    __syncthreads();
    #pragma unroll
    for (int s = 0; s < 16; ++s) {
      h2[s * 512 + t]       = fmaxf(acc0[s] * BN_SCALE, 0.f);
      h2[s * 512 + t + 256] = fmaxf(acc1[s] * BN_SCALE, 0.f);
    }
  }
  __syncthreads();
  {
    float acc0[16], acc1[16], acc2[16];
    float ba = b2[t], bb2 = b2[t + 256], bc = b2[t + 512];
    #pragma unroll
    for (int s = 0; s < 16; ++s) { acc0[s] = ba; acc1[s] = bb2; acc2[s] = bc; }
    for (int d4 = 0; d4 < 128; ++d4) {
      int d = d4 * 4;
      float wA0 = w2[(size_t)(d + 0) * 768 + t], wA1 = w2[(size_t)(d + 0) * 768 + t + 256], wA2 = w2[(size_t)(d + 0) * 768 + t + 512];
      float wB0 = w2[(size_t)(d + 1) * 768 + t], wB1 = w2[(size_t)(d + 1) * 768 + t + 256], wB2 = w2[(size_t)(d + 1) * 768 + t + 512];
      float wC0 = w2[(size_t)(d + 2) * 768 + t], wC1 = w2[(size_t)(d + 2) * 768 + t + 256], wC2 = w2[(size_t)(d + 2) * 768 + t + 512];
      float wD0 = w2[(size_t)(d + 3) * 768 + t], wD1 = w2[(size_t)(d + 3) * 768 + t + 256], wD2 = w2[(size_t)(d + 3) * 768 + t + 512];
      #pragma unroll
      for (int s = 0; s < 16; ++s) {
        float4 h4 = *reinterpret_cast<const float4*>(&h2[s * 512 + d]);
        acc0[s] = fmaf(h4.x, wA0, acc0[s]); acc0[s] = fmaf(h4.y, wB0, acc0[s]);
        acc0[s] = fmaf(h4.z, wC0, acc0[s]); acc0[s] = fmaf(h4.w, wD0, acc0[s]);
        acc1[s] = fmaf(h4.x, wA1, acc1[s]); acc1[s] = fmaf(h4.y, wB1, acc1[s]);
        acc1[s] = fmaf(h4.z, wC1, acc1[s]); acc1[s] = fmaf(h4.w, wD1, acc1[s]);
        acc2[s] = fmaf(h4.x, wA2, acc2[s]); acc2[s] = fmaf(h4.y, wB2, acc2[s]);
        acc2[s] = fmaf(h4.z, wC2, acc2[s]); acc2[s] = fmaf(h4.w, wD2, acc2[s]);
      }
    }
    float m0 = 0.f, m1 = 0.f, m2 = 0.f;
    #pragma unroll
    for (int s = 0; s < 16; ++s) {
      m0 = fmaxf(m0, fmaxf(acc0[s] * BN_SCALE, 0.f));
      m1 = fmaxf(m1, fmaxf(acc1[s] * BN_SCALE, 0.f));
      m2 = fmaxf(m2, fmaxf(acc2[s] * BN_SCALE, 0.f));
    }
    __syncthreads();
    g[t] = m0; g[t + 256] = m1; g[t + 512] = m2;
  }
  __syncthreads();
  {
    float a0 = fcb[t], a1 = fcb[t + 256], a2 = fcb[t + 512];
    for (int d4 = 0; d4 < 192; ++d4) {
      int d = d4 * 4;
      float4 g4 = *reinterpret_cast<const float4*>(&g[d]);
      float wA0 = fcw[(size_t)(d + 0) * 768 + t], wA1 = fcw[(size_t)(d + 0) * 768 + t + 256], wA2 = fcw[(size_t)(d + 0) * 768 + t + 512];
      float wB0 = fcw[(size_t)(d + 1) * 768 + t], wB1 = fcw[(size_t)(d + 1) * 768 + t + 256], wB2 = fcw[(size_t)(d + 1) * 768 + t + 512];
      float wC0 = fcw[(size_t)(d + 2) * 768 + t], wC1 = fcw[(size_t)(d + 2) * 768 + t + 256], wC2 = fcw[(size_t)(d + 2) * 768 + t + 512];
      float wD0 = fcw[(size_t)(d + 3) * 768 + t], wD1 = fcw[(size_t)(d + 3) * 768 + t + 256], wD2 = fcw[(size_t)(d + 3) * 768 + t + 512];
      a0 = fmaf(g4.x, wA0, a0); a0 = fmaf(g4.y, wB0, a0); a0 = fmaf(g4.z, wC0, a0); a0 = fmaf(g4.w, wD0, a0);
      a1 = fmaf(g4.x, wA1, a1); a1 = fmaf(g4.y, wB1, a1); a1 = fmaf(g4.z, wC1, a1); a1 = fmaf(g4.w, wD1, a1);
      a2 = fmaf(g4.x, wA2, a2); a2 = fmaf(g4.y, wB2, a2); a2 = fmaf(g4.z, wC2, a2); a2 = fmaf(g4.w, wD2, a2);
    }
    outp[(size_t)b * 768 + t]       = a0;
    outp[(size_t)b * 768 + t + 256] = a1;
    outp[(size_t)b * 768 + t + 512] = a2;
  }
}

// ---------------------------------------------------------------------------
extern "C" void kernel_launch(void* const* d_in, const int* in_sizes, int n_in,
                              void* d_out, int out_size, void* d_ws, size_t ws_size,
                              hipStream_t stream) {
  const float* x    = (const float*)d_in[0];
  const float* w1_0 = (const float*)d_in[1];  const float* b1_0 = (const float*)d_in[2];
  const float* w1_1 = (const float*)d_in[3];  const float* b1_1 = (const float*)d_in[4];
  const float* w1_2 = (const float*)d_in[5];  const float* b1_2 = (const float*)d_in[6];
  const float* w2_0 = (const float*)d_in[7];  const float* b2_0 = (const float*)d_in[8];
  const float* w2_1 = (const float*)d_in[9];  const float* b2_1 = (const float*)d_in[10];
  const float* w2_2 = (const float*)d_in[11]; const float* b2_2 = (const float*)d_in[12];
  const float* w3_0 = (const float*)d_in[13]; const float* b3_0 = (const float*)d_in[14];
  const float* w3_1 = (const float*)d_in[15]; const float* b3_1 = (const float*)d_in[16];
  const float* w3_2 = (const float*)d_in[17]; const float* b3_2 = (const float*)d_in[18];
  const float* fc_w = (const float*)d_in[19]; const float* fc_b = (const float*)d_in[20];
  float* outp = (float*)d_out;

  // Workspace: floats (nxyz1,nxyz2,f1,f2) + ints (idx1,idx2) + bf16 frag weights
  const size_t n_float = (size_t)NB * 96 + (size_t)NB * 48 +
                         (size_t)NB * 32 * 128 + (size_t)NB * 16 * 256;
  const size_t n_int   = (size_t)NB * 32 * 32 + (size_t)NB * 16 * 32;
  const size_t n_short = (40960 + 32768 + 65536) + (4096 + 8192 + 16384);
  const size_t need_bytes = n_float * 4 + n_int * 4 + n_short * 2;
  if (ws_size < need_bytes) return;

  float* nxyz1 = (float*)d_ws;
  float* nxyz2 = nxyz1 + (size_t)NB * 96;
  float* f1    = nxyz2 + (size_t)NB * 48;
  float* f2    = f1    + (size_t)NB * 32 * 128;
  int*   idx1  = (int*)(f2 + (size_t)NB * 16 * 256);
  int*   idx2  = idx1 + (size_t)NB * 32 * 32;
  short* wt0   = (short*)(idx2 + (size_t)NB * 16 * 32);
  short* wt1   = wt0 + 40960;
  short* wt2   = wt1 + 32768;
  short* wt10  = wt2 + 65536;
  short* wt11  = wt10 + 4096;
  short* wt12  = wt11 + 8192;

  k_prep <<<272, 256, 0, stream>>>(w2_0, w2_1, w2_2, wt0, wt1, wt2);
  k_prep1<<<56, 256, 0, stream>>>(w1_0, w1_1, w1_2, wt10, wt11, wt12);
  k_fps1<<<NB, 256, 0, stream>>>(x, nxyz1);
  k_bq1 <<<(NB * 32) / 256, 256, 0, stream>>>(x, nxyz1, idx1);
  k_sa1 <<<NB * 16, 256, 0, stream>>>(x, nxyz1, idx1, wt10, wt11, wt12,
                                      b1_0, b1_1, b1_2, f1);
  k_fps2<<<NB, 64, 0, stream>>>(nxyz1, nxyz2);
  k_bq2 <<<(NB * 16) / 256, 256, 0, stream>>>(nxyz1, nxyz2, idx2);
  k_sa2 <<<NB * 8, 256, 0, stream>>>(nxyz1, nxyz2, idx2, f1, wt0, wt1, wt2,
                                     b2_0, b2_1, b2_2, f2);
  k_mlp3<<<NB, 256, 0, stream>>>(nxyz2, f2, w3_0, b3_0, w3_1, b3_1, w3_2, b3_2,
                                 fc_w, fc_b, outp);
}

// Round 7
// 1505.719 us; speedup vs baseline: 3.1256x; 1.2469x over previous
//
#include <hip/hip_runtime.h>
#include <math.h>

#define BN_SCALE 0.999995000037499687f   // 1/sqrt(1+1e-5)
#define NPTS 1024
#define NB   2048    // 32*64 clouds

typedef __attribute__((ext_vector_type(8))) short bh8;
typedef __attribute__((ext_vector_type(4))) float f32x4;

// exact-rounding sum of 3 squares, matching XLA/NumPy's ((x*x + y*y) + z*z) without fma contraction
__device__ __forceinline__ float sq3(float x, float y, float z) {
  return __fadd_rn(__fadd_rn(__fmul_rn(x, x), __fmul_rn(y, y)), __fmul_rn(z, z));
}

// RNE f32 -> bf16 bits
__device__ __forceinline__ short bf16hi(float v) {
  unsigned u = __float_as_uint(v);
  unsigned r = (u + 0x7FFFu + ((u >> 16) & 1u)) >> 16;
  return (short)r;
}
__device__ __forceinline__ float bf16tof(short s) {
  unsigned u = ((unsigned)(unsigned short)s) << 16;
  return __uint_as_float(u);
}
__device__ __forceinline__ void bf16split(float v, short& hi, short& lo) {
  hi = bf16hi(v);
  lo = bf16hi(v - bf16tof(hi));
}

// ---------------------------------------------------------------------------
// FPS over 1024 points -> 32 centers per cloud. Bit-exact mirror of reference.
// ---------------------------------------------------------------------------
__global__ __launch_bounds__(256) void k_fps1(const float* __restrict__ x,
                                              float* __restrict__ nxyz1) {
  int b = blockIdx.x;
  const float* cloud = x + (size_t)b * NPTS * 6;
  __shared__ float px[NPTS], py[NPTS], pz[NPTS], dist[NPTS];
  __shared__ float wv_s[4];
  __shared__ int   wi_s[4];
  __shared__ int   last_s;
  int t = threadIdx.x;
  for (int i = t; i < NPTS; i += 256) {
    px[i] = cloud[i * 6 + 0];
    py[i] = cloud[i * 6 + 1];
    pz[i] = cloud[i * 6 + 2];
    dist[i] = 1e10f;
  }
  __syncthreads();
  if (t == 0) {
    nxyz1[(size_t)b * 96 + 0] = px[0];
    nxyz1[(size_t)b * 96 + 1] = py[0];
    nxyz1[(size_t)b * 96 + 2] = pz[0];
  }
  int last = 0;
  for (int s = 1; s < 32; ++s) {
    float lx = px[last], ly = py[last], lz = pz[last];
    float bv = -1.0f; int bi = NPTS;
    for (int i = t; i < NPTS; i += 256) {
      float dx = __fsub_rn(px[i], lx);
      float dy = __fsub_rn(py[i], ly);
      float dz = __fsub_rn(pz[i], lz);
      float d  = sq3(dx, dy, dz);
      float nd = fminf(dist[i], d);
      dist[i] = nd;
      if (nd > bv || (nd == bv && i < bi)) { bv = nd; bi = i; }
    }
    for (int off = 32; off; off >>= 1) {
      float ov = __shfl_down(bv, off);
      int   oi = __shfl_down(bi, off);
      if (ov > bv || (ov == bv && oi < bi)) { bv = ov; bi = oi; }
    }
    if ((t & 63) == 0) { wv_s[t >> 6] = bv; wi_s[t >> 6] = bi; }
    __syncthreads();
    if (t == 0) {
      for (int w = 1; w < 4; ++w)
        if (wv_s[w] > bv || (wv_s[w] == bv && wi_s[w] < bi)) { bv = wv_s[w]; bi = wi_s[w]; }
      last_s = bi;
      nxyz1[(size_t)b * 96 + s * 3 + 0] = px[bi];
      nxyz1[(size_t)b * 96 + s * 3 + 1] = py[bi];
      nxyz1[(size_t)b * 96 + s * 3 + 2] = pz[bi];
    }
    __syncthreads();
    last = last_s;
  }
}

// ---------------------------------------------------------------------------
// Ball query SA1 (bit-exact d2 formula).
// ---------------------------------------------------------------------------
__global__ __launch_bounds__(256) void k_bq1(const float* __restrict__ x,
                                             const float* __restrict__ nxyz1,
                                             int* __restrict__ idx1) {
  int c = blockIdx.x * 256 + threadIdx.x;
  if (c >= NB * 32) return;
  int b = c >> 5;
  const float* cloud = x + (size_t)b * NPTS * 6;
  float cx = nxyz1[c * 3 + 0], cy = nxyz1[c * 3 + 1], cz = nxyz1[c * 3 + 2];
  float sqc = sq3(cx, cy, cz);
  const float r2 = (float)(0.2 * 0.2);
  int hits = 0, fh = NPTS - 1;
  int* outp = idx1 + (size_t)c * 32;
  for (int i = 0; i < NPTS; ++i) {
    float ppx = cloud[i * 6 + 0], ppy = cloud[i * 6 + 1], ppz = cloud[i * 6 + 2];
    float sqp = sq3(ppx, ppy, ppz);
    float dt  = __fadd_rn(__fadd_rn(__fmul_rn(cx, ppx), __fmul_rn(cy, ppy)), __fmul_rn(cz, ppz));
    float d2  = __fsub_rn(__fadd_rn(sqc, sqp), __fmul_rn(2.0f, dt));
    if (d2 < r2) {
      if (hits == 0) fh = i;
      outp[hits] = i;
      if (++hits == 32) break;
    }
  }
  for (int j = hits; j < 32; ++j) outp[j] = fh;
}

// ---------------------------------------------------------------------------
// Generic weight prep: src fp32 [K][N] -> fragment-major hi/lo bf16.
// Layout: [nt][kt][{hi,lo}][lane 0..63][elem 0..7], elem e of lane l covers
//   k = kt*32 + (l>>4)*8 + e, col = nt*16 + (l&15); zero-padded for k >= Kreal.
// ---------------------------------------------------------------------------
__device__ __forceinline__ void prep_one(const float* __restrict__ src,
                                         short* __restrict__ dst,
                                         int q, int KT, int Kreal, int N) {
  int nt = q / (KT * 512);
  int r  = q - nt * (KT * 512);
  int kt = r >> 9;
  int e  = r & 511;
  int l = e >> 3, i = e & 7;
  int k = kt * 32 + ((l >> 4) << 3) + i;
  int col = nt * 16 + (l & 15);
  float v = (k < Kreal) ? src[(size_t)k * N + col] : 0.f;
  short hi, lo;
  bf16split(v, hi, lo);
  size_t base = ((size_t)(nt * KT + kt) * 2) * 512 + e;
  dst[base] = hi;
  dst[base + 512] = lo;
}

// SA2 weights: w2_0 [131][128] KT=5, w2_1 [128][128] KT=4, w2_2 [128][256] KT=4
__global__ __launch_bounds__(256) void k_prep(const float* __restrict__ w0,
                                              const float* __restrict__ w1,
                                              const float* __restrict__ w2,
                                              short* __restrict__ wt0,
                                              short* __restrict__ wt1,
                                              short* __restrict__ wt2) {
  int p = blockIdx.x * 256 + threadIdx.x;
  const int S1 = 8 * 5 * 512, S2 = 8 * 4 * 512, S3 = 16 * 4 * 512;
  if (p < S1)                 prep_one(w0, wt0, p,           5, 131, 128);
  else if (p < S1 + S2)       prep_one(w1, wt1, p - S1,      4, 128, 128);
  else if (p < S1 + S2 + S3)  prep_one(w2, wt2, p - S1 - S2, 4, 128, 256);
}

// SA1 weights: w1_0 [6][64] KT=1, w1_1 [64][64] KT=2, w1_2 [64][128] KT=2
__global__ __launch_bounds__(256) void k_prep1(const float* __restrict__ w0,
                                               const float* __restrict__ w1,
                                               const float* __restrict__ w2,
                                               short* __restrict__ wt0,
                                               short* __restrict__ wt1,
                                               short* __restrict__ wt2) {
  int p = blockIdx.x * 256 + threadIdx.x;
  const int S1 = 4 * 1 * 512, S2 = 4 * 2 * 512, S3 = 8 * 2 * 512;
  if (p < S1)                 prep_one(w0, wt0, p,           1, 6,  64);
  else if (p < S1 + S2)       prep_one(w1, wt1, p - S1,      2, 64, 64);
  else if (p < S1 + S2 + S3)  prep_one(w2, wt2, p - S1 - S2, 2, 64, 128);
}

// MLP3 weights: w3_0 [259][256] KT=9, w3_1 [256][512] KT=8, w3_2 [512][768] KT=16,
// fc_w [768][768] KT=24
__global__ __launch_bounds__(256) void k_prep3(const float* __restrict__ w0,
                                               const float* __restrict__ w1,
                                               const float* __restrict__ w2,
                                               const float* __restrict__ wf,
                                               short* __restrict__ wt0,
                                               short* __restrict__ wt1,
                                               short* __restrict__ wt2,
                                               short* __restrict__ wtf) {
  int p = blockIdx.x * 256 + threadIdx.x;
  const int S1 = 16 * 9 * 512;    // 73,728
  const int S2 = 32 * 8 * 512;    // 131,072
  const int S3 = 48 * 16 * 512;   // 393,216
  const int S4 = 48 * 24 * 512;   // 589,824
  if (p < S1)                      prep_one(w0, wt0, p,                9,  259, 256);
  else if (p < S1 + S2)            prep_one(w1, wt1, p - S1,           8,  256, 512);
  else if (p < S1 + S2 + S3)       prep_one(w2, wt2, p - S1 - S2,      16, 512, 768);
  else if (p < S1 + S2 + S3 + S4)  prep_one(wf, wtf, p - S1 - S2 - S3, 24, 768, 768);
}

// ---------------------------------------------------------------------------
// MFMA GEMM helper: per-wave tile set = NTL ntiles x MT mtiles, K = KT*32.
// A hi/lo (pitch PA shorts), B from prepped frag-major weights.
// 3-term split: hi*Whi + hi*Wlo + lo*Whi.
// ---------------------------------------------------------------------------
template<int NTL, int KT, int PA, int MT>
__device__ __forceinline__ void mfma_gemm(const short* Ahi, const short* Alo,
                                          const short* __restrict__ wt,
                                          int w, int l, int lrow, int lk,
                                          f32x4 acc[][MT]) {
  for (int kt = 0; kt < KT; ++kt) {
    bh8 ahi[MT], alo[MT];
    #pragma unroll
    for (int mt = 0; mt < MT; ++mt) {
      int aoff = (mt * 16 + lrow) * PA + kt * 32 + lk;
      ahi[mt] = *(const bh8*)(Ahi + aoff);
      alo[mt] = *(const bh8*)(Alo + aoff);
    }
    #pragma unroll
    for (int ntl = 0; ntl < NTL; ++ntl) {
      int nt = w * NTL + ntl;
      bh8 bhi = *(const bh8*)(wt + (size_t)((nt * KT + kt) * 2 + 0) * 512 + l * 8);
      bh8 blo = *(const bh8*)(wt + (size_t)((nt * KT + kt) * 2 + 1) * 512 + l * 8);
      #pragma unroll
      for (int mt = 0; mt < MT; ++mt) {
        acc[ntl][mt] = __builtin_amdgcn_mfma_f32_16x16x32_bf16(ahi[mt], bhi, acc[ntl][mt], 0, 0, 0);
        acc[ntl][mt] = __builtin_amdgcn_mfma_f32_16x16x32_bf16(ahi[mt], blo, acc[ntl][mt], 0, 0, 0);
        acc[ntl][mt] = __builtin_amdgcn_mfma_f32_16x16x32_bf16(alo[mt], bhi, acc[ntl][mt], 0, 0, 0);
      }
    }
  }
}

// Epilogue for mid layers: bias+BN+relu, split hi/lo, store to LDS (pitch PD).
template<int NTL, int PD, int MT>
__device__ __forceinline__ void epi_mid(f32x4 acc[][MT], const float* __restrict__ bias,
                                        short* Dhi, short* Dlo,
                                        int w, int lrow, int lhi4) {
  #pragma unroll
  for (int ntl = 0; ntl < NTL; ++ntl) {
    int col = (w * NTL + ntl) * 16 + lrow;
    float bv = bias[col];
    #pragma unroll
    for (int mt = 0; mt < MT; ++mt) {
      #pragma unroll
      for (int r = 0; r < 4; ++r) {
        int row = mt * 16 + lhi4 + r;
        float o = fmaxf((acc[ntl][mt][r] + bv) * BN_SCALE, 0.f);
        short hi, lo;
        bf16split(o, hi, lo);
        Dhi[row * PD + col] = hi;
        Dlo[row * PD + col] = lo;
      }
    }
  }
}

// Final epilogue (SA): bias+BN+relu, per-center (rows 0..31 / 32..63) column max.
template<int NTL>
__device__ __forceinline__ void epi_max(f32x4 acc[][4], const float* __restrict__ bias,
                                        float* __restrict__ outA, float* __restrict__ outB,
                                        int w, int l, int lrow) {
  #pragma unroll
  for (int ntl = 0; ntl < NTL; ++ntl) {
    int col = (w * NTL + ntl) * 16 + lrow;
    float bv = bias[col];
    float m0 = 0.f, m1 = 0.f;
    #pragma unroll
    for (int mt = 0; mt < 4; ++mt) {
      float mm = 0.f;
      #pragma unroll
      for (int r = 0; r < 4; ++r)
        mm = fmaxf(mm, fmaxf((acc[ntl][mt][r] + bv) * BN_SCALE, 0.f));
      if (mt < 2) m0 = fmaxf(m0, mm); else m1 = fmaxf(m1, mm);
    }
    m0 = fmaxf(m0, __shfl_xor(m0, 16)); m0 = fmaxf(m0, __shfl_xor(m0, 32));
    m1 = fmaxf(m1, __shfl_xor(m1, 16)); m1 = fmaxf(m1, __shfl_xor(m1, 32));
    if (l < 16) {
      outA[col] = m0;
      outB[col] = m1;
    }
  }
}

// ---------------------------------------------------------------------------
// SA1: 2 centers per block (M=64). MLP(6->64->64->128) via split-bf16 MFMA.
// ---------------------------------------------------------------------------
__global__ __launch_bounds__(256) void k_sa1(const float* __restrict__ x,
                                             const float* __restrict__ nxyz1,
                                             const int* __restrict__ idx1,
                                             const short* __restrict__ wt0,
                                             const short* __restrict__ wt1,
                                             const short* __restrict__ wt2,
                                             const float* __restrict__ b0g,
                                             const float* __restrict__ b1g,
                                             const float* __restrict__ b2g,
                                             float* __restrict__ f1) {
  int c2 = blockIdx.x;
  int t  = threadIdx.x;
  __shared__ __align__(16) short lds[18432];
  __shared__ int pts[64];
  short* h0hi = lds;             // [64][40]
  short* h0lo = lds + 4608;
  short* h1hi = lds + 9216;      // [64][72]
  short* h1lo = lds + 13824;
  short* h2hi = lds;             // [64][72] overlays h0hi
  short* h2lo = lds + 4608;

  if (t < 64) {
    int g = t >> 5, samp = t & 31;
    pts[t] = idx1[(size_t)(c2 * 2 + g) * 32 + samp];
  }
  for (int j = t; j < 64 * 34; j += 256) {
    int s = j / 34, d = 6 + (j - s * 34);
    h0hi[s * 40 + d] = 0;
    h0lo[s * 40 + d] = 0;
  }
  __syncthreads();

  for (int j = t; j < 384; j += 256) {
    int s = j / 6, d = j - (j / 6) * 6;
    int g = s >> 5; int c = c2 * 2 + g; int b = c >> 5;
    int pt = pts[s];
    float v = x[((size_t)b * NPTS + pt) * 6 + d];
    if (d < 3) v -= nxyz1[(size_t)c * 3 + d];
    short hi, lo; bf16split(v, hi, lo);
    h0hi[s * 40 + d] = hi; h0lo[s * 40 + d] = lo;
  }
  __syncthreads();

  int l = t & 63, w = t >> 6;
  int lrow = l & 15;
  int lk   = (l >> 4) << 3;
  int lhi4 = (l >> 4) << 2;
  f32x4 zz = {0.f, 0.f, 0.f, 0.f};

  {
    f32x4 acc[1][4];
    #pragma unroll
    for (int j = 0; j < 4; ++j) acc[0][j] = zz;
    mfma_gemm<1, 1, 40, 4>(h0hi, h0lo, wt0, w, l, lrow, lk, acc);
    epi_mid<1, 72, 4>(acc, b0g, h1hi, h1lo, w, lrow, lhi4);
  }
  __syncthreads();
  {
    f32x4 acc[1][4];
    #pragma unroll
    for (int j = 0; j < 4; ++j) acc[0][j] = zz;
    mfma_gemm<1, 2, 72, 4>(h1hi, h1lo, wt1, w, l, lrow, lk, acc);
    epi_mid<1, 72, 4>(acc, b1g, h2hi, h2lo, w, lrow, lhi4);
  }
  __syncthreads();
  {
    f32x4 acc[2][4];
    #pragma unroll
    for (int i = 0; i < 2; ++i)
      #pragma unroll
      for (int j = 0; j < 4; ++j) acc[i][j] = zz;
    mfma_gemm<2, 2, 72, 4>(h2hi, h2lo, wt2, w, l, lrow, lk, acc);
    epi_max<2>(acc, b2g,
               f1 + (size_t)(c2 * 2 + 0) * 128,
               f1 + (size_t)(c2 * 2 + 1) * 128,
               w, l, lrow);
  }
}

// ---------------------------------------------------------------------------
// FPS over 32 centers -> 16. One wave per cloud. (unchanged)
// ---------------------------------------------------------------------------
__global__ __launch_bounds__(64) void k_fps2(const float* __restrict__ nxyz1,
                                             float* __restrict__ nxyz2) {
  int b = blockIdx.x;
  int t = threadIdx.x;
  const float* pts = nxyz1 + (size_t)b * 96;
  float ppx = 0.f, ppy = 0.f, ppz = 0.f, dist = -1.f;
  if (t < 32) { ppx = pts[t * 3]; ppy = pts[t * 3 + 1]; ppz = pts[t * 3 + 2]; dist = 1e10f; }
  if (t == 0) {
    nxyz2[(size_t)b * 48 + 0] = ppx;
    nxyz2[(size_t)b * 48 + 1] = ppy;
    nxyz2[(size_t)b * 48 + 2] = ppz;
  }
  int last = 0;
  for (int s = 1; s < 16; ++s) {
    float lx = __shfl(ppx, last), ly = __shfl(ppy, last), lz = __shfl(ppz, last);
    if (t < 32) {
      float dx = __fsub_rn(ppx, lx);
      float dy = __fsub_rn(ppy, ly);
      float dz = __fsub_rn(ppz, lz);
      dist = fminf(dist, sq3(dx, dy, dz));
    }
    float bv = dist; int bi = (t < 32) ? t : 1000;
    for (int off = 32; off; off >>= 1) {
      float ov = __shfl_xor(bv, off);
      int   oi = __shfl_xor(bi, off);
      if (ov > bv || (ov == bv && oi < bi)) { bv = ov; bi = oi; }
    }
    last = bi;
    float bx = __shfl(ppx, last), by = __shfl(ppy, last), bz = __shfl(ppz, last);
    if (t == 0) {
      nxyz2[(size_t)b * 48 + s * 3 + 0] = bx;
      nxyz2[(size_t)b * 48 + s * 3 + 1] = by;
      nxyz2[(size_t)b * 48 + s * 3 + 2] = bz;
    }
  }
}

// ---------------------------------------------------------------------------
// Ball query SA2 (unchanged).
// ---------------------------------------------------------------------------
__global__ __launch_bounds__(256) void k_bq2(const float* __restrict__ nxyz1,
                                             const float* __restrict__ nxyz2,
                                             int* __restrict__ idx2) {
  int c = blockIdx.x * 256 + threadIdx.x;
  if (c >= NB * 16) return;
  int b = c >> 4;
  const float* pts = nxyz1 + (size_t)b * 96;
  float cx = nxyz2[c * 3 + 0], cy = nxyz2[c * 3 + 1], cz = nxyz2[c * 3 + 2];
  float sqc = sq3(cx, cy, cz);
  const float r2 = (float)(0.4 * 0.4);
  int hits = 0, fh = 31;
  int* outp = idx2 + (size_t)c * 32;
  for (int i = 0; i < 32; ++i) {
    float ppx = pts[i * 3], ppy = pts[i * 3 + 1], ppz = pts[i * 3 + 2];
    float sqp = sq3(ppx, ppy, ppz);
    float dt  = __fadd_rn(__fadd_rn(__fmul_rn(cx, ppx), __fmul_rn(cy, ppy)), __fmul_rn(cz, ppz));
    float d2  = __fsub_rn(__fadd_rn(sqc, sqp), __fmul_rn(2.0f, dt));
    if (d2 < r2) { if (hits == 0) fh = i; outp[hits++] = i; }
  }
  for (int j = hits; j < 32; ++j) outp[j] = fh;
}

// ---------------------------------------------------------------------------
// SA2: 2 centers per block (M=64). MLP(131->128->128->256) via split-bf16 MFMA.
// ---------------------------------------------------------------------------
__global__ __launch_bounds__(256, 2) void k_sa2(const float* __restrict__ nxyz1,
                                                const float* __restrict__ nxyz2,
                                                const int* __restrict__ idx2,
                                                const float* __restrict__ f1,
                                                const short* __restrict__ wt0,
                                                const short* __restrict__ wt1,
                                                const short* __restrict__ wt2,
                                                const float* __restrict__ b0g,
                                                const float* __restrict__ b1g,
                                                const float* __restrict__ b2g,
                                                float* __restrict__ f2) {
  int c2 = blockIdx.x;
  int t  = threadIdx.x;
  __shared__ __align__(16) short lds[38912];
  __shared__ int pts[64];
  short* h0hi = lds;             // [64][168]
  short* h0lo = lds + 10752;
  short* h1hi = lds + 21504;     // [64][136]
  short* h1lo = lds + 30208;
  short* h2hi = lds;             // [64][136] overlays h0hi
  short* h2lo = lds + 10752;

  if (t < 64) {
    int g = t >> 5, samp = t & 31;
    pts[t] = idx2[(size_t)(c2 * 2 + g) * 32 + samp];
  }
  for (int j = t; j < 64 * 29; j += 256) {
    int s = j / 29, d = 131 + (j - s * 29);
    h0hi[s * 168 + d] = 0;
    h0lo[s * 168 + d] = 0;
  }
  __syncthreads();

  for (int j = t; j < 192; j += 256) {
    int s = j / 3, d = j - (j / 3) * 3;
    int g = s >> 5; int c = c2 * 2 + g; int b = c >> 4;
    int pt = pts[s];
    float v = nxyz1[((size_t)b * 32 + pt) * 3 + d] - nxyz2[(size_t)c * 3 + d];
    short hi, lo; bf16split(v, hi, lo);
    h0hi[s * 168 + d] = hi; h0lo[s * 168 + d] = lo;
  }
  for (int j = t; j < 2048; j += 256) {
    int s = j >> 5, d4 = j & 31;
    int g = s >> 5; int c = c2 * 2 + g; int b = c >> 4;
    int pt = pts[s];
    const float4 v4 = *reinterpret_cast<const float4*>(&f1[((size_t)b * 32 + pt) * 128 + d4 * 4]);
    int base = s * 168 + 3 + d4 * 4;
    short hi, lo;
    bf16split(v4.x, hi, lo); h0hi[base + 0] = hi; h0lo[base + 0] = lo;
    bf16split(v4.y, hi, lo); h0hi[base + 1] = hi; h0lo[base + 1] = lo;
    bf16split(v4.z, hi, lo); h0hi[base + 2] = hi; h0lo[base + 2] = lo;
    bf16split(v4.w, hi, lo); h0hi[base + 3] = hi; h0lo[base + 3] = lo;
  }
  __syncthreads();

  int l = t & 63, w = t >> 6;
  int lrow = l & 15;
  int lk   = (l >> 4) << 3;
  int lhi4 = (l >> 4) << 2;
  f32x4 zz = {0.f, 0.f, 0.f, 0.f};

  {
    f32x4 acc[2][4];
    #pragma unroll
    for (int i = 0; i < 2; ++i)
      #pragma unroll
      for (int j = 0; j < 4; ++j) acc[i][j] = zz;
    mfma_gemm<2, 5, 168, 4>(h0hi, h0lo, wt0, w, l, lrow, lk, acc);
    epi_mid<2, 136, 4>(acc, b0g, h1hi, h1lo, w, lrow, lhi4);
  }
  __syncthreads();
  {
    f32x4 acc[2][4];
    #pragma unroll
    for (int i = 0; i < 2; ++i)
      #pragma unroll
      for (int j = 0; j < 4; ++j) acc[i][j] = zz;
    mfma_gemm<2, 4, 136, 4>(h1hi, h1lo, wt1, w, l, lrow, lk, acc);
    epi_mid<2, 136, 4>(acc, b1g, h2hi, h2lo, w, lrow, lhi4);
  }
  __syncthreads();
  {
    f32x4 acc[4][4];
    #pragma unroll
    for (int i = 0; i < 4; ++i)
      #pragma unroll
      for (int j = 0; j < 4; ++j) acc[i][j] = zz;
    mfma_gemm<4, 4, 136, 4>(h2hi, h2lo, wt2, w, l, lrow, lk, acc);
    epi_max<4>(acc, b2g,
               f2 + (size_t)(c2 * 2 + 0) * 256,
               f2 + (size_t)(c2 * 2 + 1) * 256,
               w, l, lrow);
  }
}

// ---------------------------------------------------------------------------
// MLP3 via split-bf16 MFMA: one cloud per block, M=16, 4 waves.
// L1 [16][288p]x[288][256]; L2 [16][256]x[256][512] (acc in regs, h2 overlays h0);
// L3 [16][512]x[512][768] + 16-row max -> g (hi/lo bf16 in ws).
// ---------------------------------------------------------------------------
__global__ __launch_bounds__(256) void k_mlp3(const float* __restrict__ nxyz2,
                                              const float* __restrict__ f2,
                                              const short* __restrict__ wt0,
                                              const short* __restrict__ wt1,
                                              const short* __restrict__ wt2,
                                              const float* __restrict__ b0g,
                                              const float* __restrict__ b1g,
                                              const float* __restrict__ b2g,
                                              short* __restrict__ ghi,
                                              short* __restrict__ glo) {
  int b = blockIdx.x;
  int t = threadIdx.x;
  __shared__ __align__(16) short lds[25088];   // 50,176 B
  short* h1hi = lds;             // [16][264]
  short* h1lo = lds + 4224;
  short* h0hi = lds + 8448;      // [16][296]
  short* h0lo = lds + 13184;
  short* h2hi = lds + 8448;      // [16][520] overlays h0
  short* h2lo = lds + 16768;

  // zero h0 K-pad cols 259..287 (pitch 296)
  for (int j = t; j < 16 * 29; j += 256) {
    int s = j / 29, d = 259 + (j - s * 29);
    h0hi[s * 296 + d] = 0;
    h0lo[s * 296 + d] = 0;
  }
  // stage h0 = [nxyz2(3) | f2(256)]
  for (int j = t; j < 16 * 259; j += 256) {
    int s = j / 259, d = j - s * 259;
    float v = (d < 3) ? nxyz2[(size_t)b * 48 + s * 3 + d]
                      : f2[((size_t)b * 16 + s) * 256 + (d - 3)];
    short hi, lo; bf16split(v, hi, lo);
    h0hi[s * 296 + d] = hi;
    h0lo[s * 296 + d] = lo;
  }
  __syncthreads();

  int l = t & 63, w = t >> 6;
  int lrow = l & 15;
  int lk   = (l >> 4) << 3;
  int lhi4 = (l >> 4) << 2;
  f32x4 zz = {0.f, 0.f, 0.f, 0.f};

  // L1: N=256 -> 4 ntiles/wave, KT=9
  {
    f32x4 acc[4][1];
    #pragma unroll
    for (int i = 0; i < 4; ++i) acc[i][0] = zz;
    mfma_gemm<4, 9, 296, 1>(h0hi, h0lo, wt0, w, l, lrow, lk, acc);
    epi_mid<4, 264, 1>(acc, b0g, h1hi, h1lo, w, lrow, lhi4);
  }
  __syncthreads();   // h1 ready; h0 dead from here
  // L2: N=512 -> 8 ntiles/wave, KT=8; write h2 over h0
  {
    f32x4 acc[8][1];
    #pragma unroll
    for (int i = 0; i < 8; ++i) acc[i][0] = zz;
    mfma_gemm<8, 8, 264, 1>(h1hi, h1lo, wt1, w, l, lrow, lk, acc);
    epi_mid<8, 520, 1>(acc, b1g, h2hi, h2lo, w, lrow, lhi4);
  }
  __syncthreads();
  // L3: N=768 -> 12 ntiles/wave, KT=16; max over 16 rows -> g hi/lo
  {
    f32x4 acc[12][1];
    #pragma unroll
    for (int i = 0; i < 12; ++i) acc[i][0] = zz;
    mfma_gemm<12, 16, 520, 1>(h2hi, h2lo, wt2, w, l, lrow, lk, acc);
    #pragma unroll
    for (int ntl = 0; ntl < 12; ++ntl) {
      int col = (w * 12 + ntl) * 16 + lrow;
      float bv = b2g[col];
      float m = 0.f;
      #pragma unroll
      for (int r = 0; r < 4; ++r)
        m = fmaxf(m, fmaxf((acc[ntl][0][r] + bv) * BN_SCALE, 0.f));
      m = fmaxf(m, __shfl_xor(m, 16));
      m = fmaxf(m, __shfl_xor(m, 32));
      if (l < 16) {
        short hi, lo; bf16split(m, hi, lo);
        ghi[(size_t)b * 768 + col] = hi;
        glo[(size_t)b * 768 + col] = lo;
      }
    }
  }
}

// ---------------------------------------------------------------------------
// FC: [2048][768] x [768][768] + bias -> out. M=16/block, N split in halves.
// A frags straight from global g (hi/lo). KT=24.
// ---------------------------------------------------------------------------
__global__ __launch_bounds__(256) void k_fc(const short* __restrict__ ghi,
                                            const short* __restrict__ glo,
                                            const short* __restrict__ wtf,
                                            const float* __restrict__ fcb,
                                            float* __restrict__ outp) {
  int mblk = blockIdx.x;       // 0..127 (16 clouds each)
  int nh   = blockIdx.y;       // 0..1 (384-col halves)
  int t = threadIdx.x;
  int l = t & 63, w = t >> 6;
  int lrow = l & 15;
  int lk   = (l >> 4) << 3;
  int lhi4 = (l >> 4) << 2;
  f32x4 zz = {0.f, 0.f, 0.f, 0.f};

  const short* Ahi = ghi + (size_t)mblk * 16 * 768;
  const short* Alo = glo + (size_t)mblk * 16 * 768;
  const short* wt  = wtf + (size_t)nh * 24 * 24 * 1024;  // 24 ntiles x KT=24 x 1024 shorts

  f32x4 acc[6][1];
  #pragma unroll
  for (int i = 0; i < 6; ++i) acc[i][0] = zz;
  mfma_gemm<6, 24, 768, 1>(Ahi, Alo, wt, w, l, lrow, lk, acc);

  #pragma unroll
  for (int ntl = 0; ntl < 6; ++ntl) {
    int col = nh * 384 + (w * 6 + ntl) * 16 + lrow;
    float bv = fcb[col];
    #pragma unroll
    for (int r = 0; r < 4; ++r) {
      int row = mblk * 16 + lhi4 + r;
      outp[(size_t)row * 768 + col] = acc[ntl][0][r] + bv;
    }
  }
}

// ---------------------------------------------------------------------------
extern "C" void kernel_launch(void* const* d_in, const int* in_sizes, int n_in,
                              void* d_out, int out_size, void* d_ws, size_t ws_size,
                              hipStream_t stream) {
  const float* x    = (const float*)d_in[0];
  const float* w1_0 = (const float*)d_in[1];  const float* b1_0 = (const float*)d_in[2];
  const float* w1_1 = (const float*)d_in[3];  const float* b1_1 = (const float*)d_in[4];
  const float* w1_2 = (const float*)d_in[5];  const float* b1_2 = (const float*)d_in[6];
  const float* w2_0 = (const float*)d_in[7];  const float* b2_0 = (const float*)d_in[8];
  const float* w2_1 = (const float*)d_in[9];  const float* b2_1 = (const float*)d_in[10];
  const float* w2_2 = (const float*)d_in[11]; const float* b2_2 = (const float*)d_in[12];
  const float* w3_0 = (const float*)d_in[13]; const float* b3_0 = (const float*)d_in[14];
  const float* w3_1 = (const float*)d_in[15]; const float* b3_1 = (const float*)d_in[16];
  const float* w3_2 = (const float*)d_in[17]; const float* b3_2 = (const float*)d_in[18];
  const float* fc_w = (const float*)d_in[19]; const float* fc_b = (const float*)d_in[20];
  float* outp = (float*)d_out;

  const size_t n_float = (size_t)NB * 96 + (size_t)NB * 48 +
                         (size_t)NB * 32 * 128 + (size_t)NB * 16 * 256;
  const size_t n_int   = (size_t)NB * 32 * 32 + (size_t)NB * 16 * 32;
  // shorts: sa2 wts + sa1 wts + mlp3 wts + fc wt + g hi/lo
  const size_t n_short = (40960 + 32768 + 65536) + (4096 + 8192 + 16384) +
                         (147456 + 262144 + 786432) + 1179648 +
                         2 * (size_t)NB * 768;
  const size_t need_bytes = n_float * 4 + n_int * 4 + n_short * 2;
  if (ws_size < need_bytes) return;

  float* nxyz1 = (float*)d_ws;
  float* nxyz2 = nxyz1 + (size_t)NB * 96;
  float* f1    = nxyz2 + (size_t)NB * 48;
  float* f2    = f1    + (size_t)NB * 32 * 128;
  int*   idx1  = (int*)(f2 + (size_t)NB * 16 * 256);
  int*   idx2  = idx1 + (size_t)NB * 32 * 32;
  short* wt0   = (short*)(idx2 + (size_t)NB * 16 * 32);
  short* wt1   = wt0 + 40960;
  short* wt2   = wt1 + 32768;
  short* wt10  = wt2 + 65536;
  short* wt11  = wt10 + 4096;
  short* wt12  = wt11 + 8192;
  short* wt30  = wt12 + 16384;
  short* wt31  = wt30 + 147456;
  short* wt32  = wt31 + 262144;
  short* wtfc  = wt32 + 786432;
  short* ghi   = wtfc + 1179648;
  short* glo   = ghi + (size_t)NB * 768;

  k_prep <<<272, 256, 0, stream>>>(w2_0, w2_1, w2_2, wt0, wt1, wt2);
  k_prep1<<<56, 256, 0, stream>>>(w1_0, w1_1, w1_2, wt10, wt11, wt12);
  k_prep3<<<4640, 256, 0, stream>>>(w3_0, w3_1, w3_2, fc_w, wt30, wt31, wt32, wtfc);
  k_fps1<<<NB, 256, 0, stream>>>(x, nxyz1);
  k_bq1 <<<(NB * 32) / 256, 256, 0, stream>>>(x, nxyz1, idx1);
  k_sa1 <<<NB * 16, 256, 0, stream>>>(x, nxyz1, idx1, wt10, wt11, wt12,
                                      b1_0, b1_1, b1_2, f1);
  k_fps2<<<NB, 64, 0, stream>>>(nxyz1, nxyz2);
  k_bq2 <<<(NB * 16) / 256, 256, 0, stream>>>(nxyz1, nxyz2, idx2);
  k_sa2 <<<NB * 8, 256, 0, stream>>>(nxyz1, nxyz2, idx2, f1, wt0, wt1, wt2,
                                     b2_0, b2_1, b2_2, f2);
  k_mlp3<<<NB, 256, 0, stream>>>(nxyz2, f2, wt30, wt31, wt32,
                                 b3_0, b3_1, b3_2, ghi, glo);
  k_fc  <<<dim3(NB / 16, 2), 256, 0, stream>>>(ghi, glo, wtfc, fc_b, outp);
}

// Round 8
// 1285.872 us; speedup vs baseline: 3.6600x; 1.1710x over previous
//
#include <hip/hip_runtime.h>
#include <math.h>

#define BN_SCALE 0.999995000037499687f   // 1/sqrt(1+1e-5)
#define NPTS 1024
#define NB   2048    // 32*64 clouds

typedef __attribute__((ext_vector_type(8))) short bh8;
typedef __attribute__((ext_vector_type(4))) float f32x4;

__device__ __forceinline__ float sq3(float x, float y, float z) {
  return __fadd_rn(__fadd_rn(__fmul_rn(x, x), __fmul_rn(y, y)), __fmul_rn(z, z));
}

// RNE f32 -> bf16 bits
__device__ __forceinline__ short bf16hi(float v) {
  unsigned u = __float_as_uint(v);
  unsigned r = (u + 0x7FFFu + ((u >> 16) & 1u)) >> 16;
  return (short)r;
}
__device__ __forceinline__ float bf16tof(short s) {
  unsigned u = ((unsigned)(unsigned short)s) << 16;
  return __uint_as_float(u);
}
__device__ __forceinline__ void bf16split(float v, short& hi, short& lo) {
  hi = bf16hi(v);
  lo = bf16hi(v - bf16tof(hi));
}

// ---------------------------------------------------------------------------
// FPS over 1024 points -> 32 centers per cloud. Bit-exact mirror of reference.
// ---------------------------------------------------------------------------
__global__ __launch_bounds__(256) void k_fps1(const float* __restrict__ x,
                                              float* __restrict__ nxyz1) {
  int b = blockIdx.x;
  const float* cloud = x + (size_t)b * NPTS * 6;
  __shared__ float px[NPTS], py[NPTS], pz[NPTS], dist[NPTS];
  __shared__ float wv_s[4];
  __shared__ int   wi_s[4];
  __shared__ int   last_s;
  int t = threadIdx.x;
  for (int i = t; i < NPTS; i += 256) {
    px[i] = cloud[i * 6 + 0];
    py[i] = cloud[i * 6 + 1];
    pz[i] = cloud[i * 6 + 2];
    dist[i] = 1e10f;
  }
  __syncthreads();
  if (t == 0) {
    nxyz1[(size_t)b * 96 + 0] = px[0];
    nxyz1[(size_t)b * 96 + 1] = py[0];
    nxyz1[(size_t)b * 96 + 2] = pz[0];
  }
  int last = 0;
  for (int s = 1; s < 32; ++s) {
    float lx = px[last], ly = py[last], lz = pz[last];
    float bv = -1.0f; int bi = NPTS;
    for (int i = t; i < NPTS; i += 256) {
      float dx = __fsub_rn(px[i], lx);
      float dy = __fsub_rn(py[i], ly);
      float dz = __fsub_rn(pz[i], lz);
      float d  = sq3(dx, dy, dz);
      float nd = fminf(dist[i], d);
      dist[i] = nd;
      if (nd > bv || (nd == bv && i < bi)) { bv = nd; bi = i; }
    }
    for (int off = 32; off; off >>= 1) {
      float ov = __shfl_down(bv, off);
      int   oi = __shfl_down(bi, off);
      if (ov > bv || (ov == bv && oi < bi)) { bv = ov; bi = oi; }
    }
    if ((t & 63) == 0) { wv_s[t >> 6] = bv; wi_s[t >> 6] = bi; }
    __syncthreads();
    if (t == 0) {
      for (int w = 1; w < 4; ++w)
        if (wv_s[w] > bv || (wv_s[w] == bv && wi_s[w] < bi)) { bv = wv_s[w]; bi = wi_s[w]; }
      last_s = bi;
      nxyz1[(size_t)b * 96 + s * 3 + 0] = px[bi];
      nxyz1[(size_t)b * 96 + s * 3 + 1] = py[bi];
      nxyz1[(size_t)b * 96 + s * 3 + 2] = pz[bi];
    }
    __syncthreads();
    last = last_s;
  }
}

// ---------------------------------------------------------------------------
// Ball query SA1 (bit-exact d2 formula).
// ---------------------------------------------------------------------------
__global__ __launch_bounds__(256) void k_bq1(const float* __restrict__ x,
                                             const float* __restrict__ nxyz1,
                                             int* __restrict__ idx1) {
  int c = blockIdx.x * 256 + threadIdx.x;
  if (c >= NB * 32) return;
  int b = c >> 5;
  const float* cloud = x + (size_t)b * NPTS * 6;
  float cx = nxyz1[c * 3 + 0], cy = nxyz1[c * 3 + 1], cz = nxyz1[c * 3 + 2];
  float sqc = sq3(cx, cy, cz);
  const float r2 = (float)(0.2 * 0.2);
  int hits = 0, fh = NPTS - 1;
  int* outp = idx1 + (size_t)c * 32;
  for (int i = 0; i < NPTS; ++i) {
    float ppx = cloud[i * 6 + 0], ppy = cloud[i * 6 + 1], ppz = cloud[i * 6 + 2];
    float sqp = sq3(ppx, ppy, ppz);
    float dt  = __fadd_rn(__fadd_rn(__fmul_rn(cx, ppx), __fmul_rn(cy, ppy)), __fmul_rn(cz, ppz));
    float d2  = __fsub_rn(__fadd_rn(sqc, sqp), __fmul_rn(2.0f, dt));
    if (d2 < r2) {
      if (hits == 0) fh = i;
      outp[hits] = i;
      if (++hits == 32) break;
    }
  }
  for (int j = hits; j < 32; ++j) outp[j] = fh;
}

// ---------------------------------------------------------------------------
// Weight prep: src fp32 [K][N] -> fragment-major hi/lo bf16.
// elem e of lane l covers k_new = kt*32 + (l>>4)*8 + e, col = nt*16 + (l&15).
// permS != 0 remaps the K index (activation layout [feat(S) | xyz(3)]):
//   k_orig = k_new < S ? k_new + 3 : k_new - S   (valid while k_new < Kreal)
// ---------------------------------------------------------------------------
__device__ __forceinline__ void prep_one(const float* __restrict__ src,
                                         short* __restrict__ dst,
                                         int q, int KT, int Kreal, int N, int permS) {
  int nt = q / (KT * 512);
  int r  = q - nt * (KT * 512);
  int kt = r >> 9;
  int e  = r & 511;
  int l = e >> 3, i = e & 7;
  int k = kt * 32 + ((l >> 4) << 3) + i;
  int col = nt * 16 + (l & 15);
  int ko = k;
  if (permS) ko = (k < permS) ? k + 3 : k - permS;
  float v = (k < Kreal) ? src[(size_t)ko * N + col] : 0.f;
  short hi, lo;
  bf16split(v, hi, lo);
  size_t base = ((size_t)(nt * KT + kt) * 2) * 512 + e;
  dst[base] = hi;
  dst[base + 512] = lo;
}

// SA2 weights: w2_0 [131][128] KT=5 (perm 128), w2_1 [128][128] KT=4, w2_2 [128][256] KT=4
__global__ __launch_bounds__(256) void k_prep(const float* __restrict__ w0,
                                              const float* __restrict__ w1,
                                              const float* __restrict__ w2,
                                              short* __restrict__ wt0,
                                              short* __restrict__ wt1,
                                              short* __restrict__ wt2) {
  int p = blockIdx.x * 256 + threadIdx.x;
  const int S1 = 8 * 5 * 512, S2 = 8 * 4 * 512, S3 = 16 * 4 * 512;
  if (p < S1)                 prep_one(w0, wt0, p,           5, 131, 128, 128);
  else if (p < S1 + S2)       prep_one(w1, wt1, p - S1,      4, 128, 128, 0);
  else if (p < S1 + S2 + S3)  prep_one(w2, wt2, p - S1 - S2, 4, 128, 256, 0);
}

// SA1 weights: w1_0 [6][64] KT=1, w1_1 [64][64] KT=2, w1_2 [64][128] KT=2
__global__ __launch_bounds__(256) void k_prep1(const float* __restrict__ w0,
                                               const float* __restrict__ w1,
                                               const float* __restrict__ w2,
                                               short* __restrict__ wt0,
                                               short* __restrict__ wt1,
                                               short* __restrict__ wt2) {
  int p = blockIdx.x * 256 + threadIdx.x;
  const int S1 = 4 * 1 * 512, S2 = 4 * 2 * 512, S3 = 8 * 2 * 512;
  if (p < S1)                 prep_one(w0, wt0, p,           1, 6,  64, 0);
  else if (p < S1 + S2)       prep_one(w1, wt1, p - S1,      2, 64, 64, 0);
  else if (p < S1 + S2 + S3)  prep_one(w2, wt2, p - S1 - S2, 2, 64, 128, 0);
}

// MLP3: w3_0 [259][256] KT=9 (perm 256), w3_1 [256][512] KT=8, w3_2 [512][768] KT=16,
// fc_w [768][768] KT=24
__global__ __launch_bounds__(256) void k_prep3(const float* __restrict__ w0,
                                               const float* __restrict__ w1,
                                               const float* __restrict__ w2,
                                               const float* __restrict__ wf,
                                               short* __restrict__ wt0,
                                               short* __restrict__ wt1,
                                               short* __restrict__ wt2,
                                               short* __restrict__ wtf) {
  int p = blockIdx.x * 256 + threadIdx.x;
  const int S1 = 16 * 9 * 512;
  const int S2 = 32 * 8 * 512;
  const int S3 = 48 * 16 * 512;
  const int S4 = 48 * 24 * 512;
  if (p < S1)                      prep_one(w0, wt0, p,                9,  259, 256, 256);
  else if (p < S1 + S2)            prep_one(w1, wt1, p - S1,           8,  256, 512, 0);
  else if (p < S1 + S2 + S3)       prep_one(w2, wt2, p - S1 - S2,      16, 512, 768, 0);
  else if (p < S1 + S2 + S3 + S4)  prep_one(wf, wtf, p - S1 - S2 - S3, 24, 768, 768, 0);
}

// ---------------------------------------------------------------------------
// MFMA GEMM helper: NTL ntiles x MT mtiles per wave, K = KT*32.
// 3-term split: hi*Whi + hi*Wlo + lo*Whi.
// ---------------------------------------------------------------------------
template<int NTL, int KT, int PA, int MT>
__device__ __forceinline__ void mfma_gemm(const short* Ahi, const short* Alo,
                                          const short* __restrict__ wt,
                                          int w, int l, int lrow, int lk,
                                          f32x4 acc[][MT]) {
  for (int kt = 0; kt < KT; ++kt) {
    bh8 ahi[MT], alo[MT];
    #pragma unroll
    for (int mt = 0; mt < MT; ++mt) {
      int aoff = (mt * 16 + lrow) * PA + kt * 32 + lk;
      ahi[mt] = *(const bh8*)(Ahi + aoff);
      alo[mt] = *(const bh8*)(Alo + aoff);
    }
    #pragma unroll
    for (int ntl = 0; ntl < NTL; ++ntl) {
      int nt = w * NTL + ntl;
      bh8 bhi = *(const bh8*)(wt + (size_t)((nt * KT + kt) * 2 + 0) * 512 + l * 8);
      bh8 blo = *(const bh8*)(wt + (size_t)((nt * KT + kt) * 2 + 1) * 512 + l * 8);
      #pragma unroll
      for (int mt = 0; mt < MT; ++mt) {
        acc[ntl][mt] = __builtin_amdgcn_mfma_f32_16x16x32_bf16(ahi[mt], bhi, acc[ntl][mt], 0, 0, 0);
        acc[ntl][mt] = __builtin_amdgcn_mfma_f32_16x16x32_bf16(ahi[mt], blo, acc[ntl][mt], 0, 0, 0);
        acc[ntl][mt] = __builtin_amdgcn_mfma_f32_16x16x32_bf16(alo[mt], bhi, acc[ntl][mt], 0, 0, 0);
      }
    }
  }
}

// Mid-layer epilogue: bias+BN+relu, split hi/lo, store to LDS (pitch PD).
template<int NTL, int PD, int MT>
__device__ __forceinline__ void epi_mid(f32x4 acc[][MT], const float* __restrict__ bias,
                                        short* Dhi, short* Dlo,
                                        int w, int lrow, int lhi4) {
  #pragma unroll
  for (int ntl = 0; ntl < NTL; ++ntl) {
    int col = (w * NTL + ntl) * 16 + lrow;
    float bv = bias[col];
    #pragma unroll
    for (int mt = 0; mt < MT; ++mt) {
      #pragma unroll
      for (int r = 0; r < 4; ++r) {
        int row = mt * 16 + lhi4 + r;
        float o = fmaxf((acc[ntl][mt][r] + bv) * BN_SCALE, 0.f);
        short hi, lo;
        bf16split(o, hi, lo);
        Dhi[row * PD + col] = hi;
        Dlo[row * PD + col] = lo;
      }
    }
  }
}

// Final epilogue (SA, M=64, 2 centers): per-center column max -> hi/lo bf16.
template<int NTL>
__device__ __forceinline__ void epi_max_bf(f32x4 acc[][4], const float* __restrict__ bias,
                                           short* __restrict__ hiA, short* __restrict__ loA,
                                           short* __restrict__ hiB, short* __restrict__ loB,
                                           int w, int l, int lrow) {
  #pragma unroll
  for (int ntl = 0; ntl < NTL; ++ntl) {
    int col = (w * NTL + ntl) * 16 + lrow;
    float bv = bias[col];
    float m0 = 0.f, m1 = 0.f;
    #pragma unroll
    for (int mt = 0; mt < 4; ++mt) {
      float mm = 0.f;
      #pragma unroll
      for (int r = 0; r < 4; ++r)
        mm = fmaxf(mm, fmaxf((acc[ntl][mt][r] + bv) * BN_SCALE, 0.f));
      if (mt < 2) m0 = fmaxf(m0, mm); else m1 = fmaxf(m1, mm);
    }
    m0 = fmaxf(m0, __shfl_xor(m0, 16)); m0 = fmaxf(m0, __shfl_xor(m0, 32));
    m1 = fmaxf(m1, __shfl_xor(m1, 16)); m1 = fmaxf(m1, __shfl_xor(m1, 32));
    if (l < 16) {
      short hi, lo;
      bf16split(m0, hi, lo); hiA[col] = hi; loA[col] = lo;
      bf16split(m1, hi, lo); hiB[col] = hi; loB[col] = lo;
    }
  }
}

// ---------------------------------------------------------------------------
// SA1: 2 centers/block (M=64), MLP(6->64->64->128), f1 emitted as hi/lo bf16.
// ---------------------------------------------------------------------------
__global__ __launch_bounds__(256) void k_sa1(const float* __restrict__ x,
                                             const float* __restrict__ nxyz1,
                                             const int* __restrict__ idx1,
                                             const short* __restrict__ wt0,
                                             const short* __restrict__ wt1,
                                             const short* __restrict__ wt2,
                                             const float* __restrict__ b0g,
                                             const float* __restrict__ b1g,
                                             const float* __restrict__ b2g,
                                             short* __restrict__ f1hi,
                                             short* __restrict__ f1lo) {
  int c2 = blockIdx.x;
  int t  = threadIdx.x;
  __shared__ __align__(16) short lds[18432];
  __shared__ int pts[64];
  short* h0hi = lds;             // [64][40]
  short* h0lo = lds + 4608;
  short* h1hi = lds + 9216;      // [64][72]
  short* h1lo = lds + 13824;
  short* h2hi = lds;             // [64][72] overlays h0hi
  short* h2lo = lds + 4608;

  if (t < 64) {
    int g = t >> 5, samp = t & 31;
    pts[t] = idx1[(size_t)(c2 * 2 + g) * 32 + samp];
  }
  for (int j = t; j < 64 * 34; j += 256) {
    int s = j / 34, d = 6 + (j - s * 34);
    h0hi[s * 40 + d] = 0;
    h0lo[s * 40 + d] = 0;
  }
  __syncthreads();

  for (int j = t; j < 384; j += 256) {
    int s = j / 6, d = j - (j / 6) * 6;
    int g = s >> 5; int c = c2 * 2 + g; int b = c >> 5;
    int pt = pts[s];
    float v = x[((size_t)b * NPTS + pt) * 6 + d];
    if (d < 3) v -= nxyz1[(size_t)c * 3 + d];
    short hi, lo; bf16split(v, hi, lo);
    h0hi[s * 40 + d] = hi; h0lo[s * 40 + d] = lo;
  }
  __syncthreads();

  int l = t & 63, w = t >> 6;
  int lrow = l & 15;
  int lk   = (l >> 4) << 3;
  int lhi4 = (l >> 4) << 2;
  f32x4 zz = {0.f, 0.f, 0.f, 0.f};

  {
    f32x4 acc[1][4];
    #pragma unroll
    for (int j = 0; j < 4; ++j) acc[0][j] = zz;
    mfma_gemm<1, 1, 40, 4>(h0hi, h0lo, wt0, w, l, lrow, lk, acc);
    epi_mid<1, 72, 4>(acc, b0g, h1hi, h1lo, w, lrow, lhi4);
  }
  __syncthreads();
  {
    f32x4 acc[1][4];
    #pragma unroll
    for (int j = 0; j < 4; ++j) acc[0][j] = zz;
    mfma_gemm<1, 2, 72, 4>(h1hi, h1lo, wt1, w, l, lrow, lk, acc);
    epi_mid<1, 72, 4>(acc, b1g, h2hi, h2lo, w, lrow, lhi4);
  }
  __syncthreads();
  {
    f32x4 acc[2][4];
    #pragma unroll
    for (int i = 0; i < 2; ++i)
      #pragma unroll
      for (int j = 0; j < 4; ++j) acc[i][j] = zz;
    mfma_gemm<2, 2, 72, 4>(h2hi, h2lo, wt2, w, l, lrow, lk, acc);
    epi_max_bf<2>(acc, b2g,
                  f1hi + (size_t)(c2 * 2 + 0) * 128, f1lo + (size_t)(c2 * 2 + 0) * 128,
                  f1hi + (size_t)(c2 * 2 + 1) * 128, f1lo + (size_t)(c2 * 2 + 1) * 128,
                  w, l, lrow);
  }
}

// ---------------------------------------------------------------------------
// FPS over 32 centers -> 16. One wave per cloud. (unchanged)
// ---------------------------------------------------------------------------
__global__ __launch_bounds__(64) void k_fps2(const float* __restrict__ nxyz1,
                                             float* __restrict__ nxyz2) {
  int b = blockIdx.x;
  int t = threadIdx.x;
  const float* pts = nxyz1 + (size_t)b * 96;
  float ppx = 0.f, ppy = 0.f, ppz = 0.f, dist = -1.f;
  if (t < 32) { ppx = pts[t * 3]; ppy = pts[t * 3 + 1]; ppz = pts[t * 3 + 2]; dist = 1e10f; }
  if (t == 0) {
    nxyz2[(size_t)b * 48 + 0] = ppx;
    nxyz2[(size_t)b * 48 + 1] = ppy;
    nxyz2[(size_t)b * 48 + 2] = ppz;
  }
  int last = 0;
  for (int s = 1; s < 16; ++s) {
    float lx = __shfl(ppx, last), ly = __shfl(ppy, last), lz = __shfl(ppz, last);
    if (t < 32) {
      float dx = __fsub_rn(ppx, lx);
      float dy = __fsub_rn(ppy, ly);
      float dz = __fsub_rn(ppz, lz);
      dist = fminf(dist, sq3(dx, dy, dz));
    }
    float bv = dist; int bi = (t < 32) ? t : 1000;
    for (int off = 32; off; off >>= 1) {
      float ov = __shfl_xor(bv, off);
      int   oi = __shfl_xor(bi, off);
      if (ov > bv || (ov == bv && oi < bi)) { bv = ov; bi = oi; }
    }
    last = bi;
    float bx = __shfl(ppx, last), by = __shfl(ppy, last), bz = __shfl(ppz, last);
    if (t == 0) {
      nxyz2[(size_t)b * 48 + s * 3 + 0] = bx;
      nxyz2[(size_t)b * 48 + s * 3 + 1] = by;
      nxyz2[(size_t)b * 48 + s * 3 + 2] = bz;
    }
  }
}

// ---------------------------------------------------------------------------
// Ball query SA2 (unchanged).
// ---------------------------------------------------------------------------
__global__ __launch_bounds__(256) void k_bq2(const float* __restrict__ nxyz1,
                                             const float* __restrict__ nxyz2,
                                             int* __restrict__ idx2) {
  int c = blockIdx.x * 256 + threadIdx.x;
  if (c >= NB * 16) return;
  int b = c >> 4;
  const float* pts = nxyz1 + (size_t)b * 96;
  float cx = nxyz2[c * 3 + 0], cy = nxyz2[c * 3 + 1], cz = nxyz2[c * 3 + 2];
  float sqc = sq3(cx, cy, cz);
  const float r2 = (float)(0.4 * 0.4);
  int hits = 0, fh = 31;
  int* outp = idx2 + (size_t)c * 32;
  for (int i = 0; i < 32; ++i) {
    float ppx = pts[i * 3], ppy = pts[i * 3 + 1], ppz = pts[i * 3 + 2];
    float sqp = sq3(ppx, ppy, ppz);
    float dt  = __fadd_rn(__fadd_rn(__fmul_rn(cx, ppx), __fmul_rn(cy, ppy)), __fmul_rn(cz, ppz));
    float d2  = __fsub_rn(__fadd_rn(sqc, sqp), __fmul_rn(2.0f, dt));
    if (d2 < r2) { if (hits == 0) fh = i; outp[hits++] = i; }
  }
  for (int j = hits; j < 32; ++j) outp[j] = fh;
}

// ---------------------------------------------------------------------------
// SA2: 2 centers/block (M=64), 512 threads (8 waves), MLP(131->128->128->256).
// h0 layout: [f1(128) | gx(3) | pad], staged via aligned bh8 copies from f1hi/lo.
// f2 emitted as hi/lo bf16.
// ---------------------------------------------------------------------------
__global__ __launch_bounds__(512, 4) void k_sa2(const float* __restrict__ nxyz1,
                                                const float* __restrict__ nxyz2,
                                                const int* __restrict__ idx2,
                                                const short* __restrict__ f1hi,
                                                const short* __restrict__ f1lo,
                                                const short* __restrict__ wt0,
                                                const short* __restrict__ wt1,
                                                const short* __restrict__ wt2,
                                                const float* __restrict__ b0g,
                                                const float* __restrict__ b1g,
                                                const float* __restrict__ b2g,
                                                short* __restrict__ f2hi,
                                                short* __restrict__ f2lo) {
  int c2 = blockIdx.x;
  int t  = threadIdx.x;
  __shared__ __align__(16) short lds[38912];
  __shared__ int pts[64];
  short* h0hi = lds;             // [64][168]: cols 0..127 f1, 128..130 gx, 131..159 pad
  short* h0lo = lds + 10752;
  short* h1hi = lds + 21504;     // [64][136]
  short* h1lo = lds + 30208;
  short* h2hi = lds;             // [64][136] overlays h0hi
  short* h2lo = lds + 10752;

  if (t < 64) {
    int g = t >> 5, samp = t & 31;
    pts[t] = idx2[(size_t)(c2 * 2 + g) * 32 + samp];
  }
  // zero pad cols 131..159
  for (int j = t; j < 64 * 29; j += 512) {
    int s = j / 29, d = 131 + (j - s * 29);
    h0hi[s * 168 + d] = 0;
    h0lo[s * 168 + d] = 0;
  }
  __syncthreads();

  // f1 copy (aligned 16B): 64 rows x 16 chunks
  for (int j = t; j < 1024; j += 512) {
    int s = j >> 4, c8 = j & 15;
    int g = s >> 5; int c = c2 * 2 + g; int b = c >> 4;
    int pt = pts[s];
    size_t src = ((size_t)b * 32 + pt) * 128 + c8 * 8;
    *(bh8*)(h0hi + s * 168 + c8 * 8) = *(const bh8*)(f1hi + src);
    *(bh8*)(h0lo + s * 168 + c8 * 8) = *(const bh8*)(f1lo + src);
  }
  // gx cols 128..130
  for (int j = t; j < 192; j += 512) {
    int s = j / 3, d = j - (j / 3) * 3;
    int g = s >> 5; int c = c2 * 2 + g; int b = c >> 4;
    int pt = pts[s];
    float v = nxyz1[((size_t)b * 32 + pt) * 3 + d] - nxyz2[(size_t)c * 3 + d];
    short hi, lo; bf16split(v, hi, lo);
    h0hi[s * 168 + 128 + d] = hi; h0lo[s * 168 + 128 + d] = lo;
  }
  __syncthreads();

  int l = t & 63, w = t >> 6;          // w in [0,8)
  int lrow = l & 15;
  int lk   = (l >> 4) << 3;
  int lhi4 = (l >> 4) << 2;
  f32x4 zz = {0.f, 0.f, 0.f, 0.f};

  // GEMM1: N=128 -> 1 ntile/wave, KT=5
  {
    f32x4 acc[1][4];
    #pragma unroll
    for (int j = 0; j < 4; ++j) acc[0][j] = zz;
    mfma_gemm<1, 5, 168, 4>(h0hi, h0lo, wt0, w, l, lrow, lk, acc);
    epi_mid<1, 136, 4>(acc, b0g, h1hi, h1lo, w, lrow, lhi4);
  }
  __syncthreads();
  // GEMM2: N=128 -> 1 ntile/wave, KT=4 (h2 overlays h0)
  {
    f32x4 acc[1][4];
    #pragma unroll
    for (int j = 0; j < 4; ++j) acc[0][j] = zz;
    mfma_gemm<1, 4, 136, 4>(h1hi, h1lo, wt1, w, l, lrow, lk, acc);
    epi_mid<1, 136, 4>(acc, b1g, h2hi, h2lo, w, lrow, lhi4);
  }
  __syncthreads();
  // GEMM3: N=256 -> 2 ntiles/wave, KT=4; per-center max -> f2 hi/lo
  {
    f32x4 acc[2][4];
    #pragma unroll
    for (int i = 0; i < 2; ++i)
      #pragma unroll
      for (int j = 0; j < 4; ++j) acc[i][j] = zz;
    mfma_gemm<2, 4, 136, 4>(h2hi, h2lo, wt2, w, l, lrow, lk, acc);
    epi_max_bf<2>(acc, b2g,
                  f2hi + (size_t)(c2 * 2 + 0) * 256, f2lo + (size_t)(c2 * 2 + 0) * 256,
                  f2hi + (size_t)(c2 * 2 + 1) * 256, f2lo + (size_t)(c2 * 2 + 1) * 256,
                  w, l, lrow);
  }
}

// ---------------------------------------------------------------------------
// MLP3: one cloud/block, M=16, 4 waves. h0 = [f2(256) | nxyz2(3) | pad],
// staged via aligned bh8 copies from f2hi/lo. Output g as hi/lo bf16.
// ---------------------------------------------------------------------------
__global__ __launch_bounds__(256) void k_mlp3(const float* __restrict__ nxyz2,
                                              const short* __restrict__ f2hi,
                                              const short* __restrict__ f2lo,
                                              const short* __restrict__ wt0,
                                              const short* __restrict__ wt1,
                                              const short* __restrict__ wt2,
                                              const float* __restrict__ b0g,
                                              const float* __restrict__ b1g,
                                              const float* __restrict__ b2g,
                                              short* __restrict__ ghi,
                                              short* __restrict__ glo) {
  int b = blockIdx.x;
  int t = threadIdx.x;
  __shared__ __align__(16) short lds[25088];
  short* h1hi = lds;             // [16][264]
  short* h1lo = lds + 4224;
  short* h0hi = lds + 8448;      // [16][296]
  short* h0lo = lds + 13184;
  short* h2hi = lds + 8448;      // [16][520] overlays h0
  short* h2lo = lds + 16768;

  // zero pad cols 259..287
  for (int j = t; j < 16 * 29; j += 256) {
    int s = j / 29, d = 259 + (j - s * 29);
    h0hi[s * 296 + d] = 0;
    h0lo[s * 296 + d] = 0;
  }
  // f2 cols 0..255 (aligned bh8), 16 rows x 32 chunks
  for (int j = t; j < 512; j += 256) {
    int s = j >> 5, c8 = j & 31;
    size_t src = ((size_t)b * 16 + s) * 256 + c8 * 8;
    *(bh8*)(h0hi + s * 296 + c8 * 8) = *(const bh8*)(f2hi + src);
    *(bh8*)(h0lo + s * 296 + c8 * 8) = *(const bh8*)(f2lo + src);
  }
  // nxyz2 cols 256..258
  for (int j = t; j < 48; j += 256) {
    int s = j / 3, d = j - (j / 3) * 3;
    float v = nxyz2[(size_t)b * 48 + s * 3 + d];
    short hi, lo; bf16split(v, hi, lo);
    h0hi[s * 296 + 256 + d] = hi;
    h0lo[s * 296 + 256 + d] = lo;
  }
  __syncthreads();

  int l = t & 63, w = t >> 6;
  int lrow = l & 15;
  int lk   = (l >> 4) << 3;
  int lhi4 = (l >> 4) << 2;
  f32x4 zz = {0.f, 0.f, 0.f, 0.f};

  // L1: N=256 -> 4 ntiles/wave, KT=9
  {
    f32x4 acc[4][1];
    #pragma unroll
    for (int i = 0; i < 4; ++i) acc[i][0] = zz;
    mfma_gemm<4, 9, 296, 1>(h0hi, h0lo, wt0, w, l, lrow, lk, acc);
    epi_mid<4, 264, 1>(acc, b0g, h1hi, h1lo, w, lrow, lhi4);
  }
  __syncthreads();
  // L2: N=512 -> 8 ntiles/wave, KT=8; h2 overlays h0
  {
    f32x4 acc[8][1];
    #pragma unroll
    for (int i = 0; i < 8; ++i) acc[i][0] = zz;
    mfma_gemm<8, 8, 264, 1>(h1hi, h1lo, wt1, w, l, lrow, lk, acc);
    epi_mid<8, 520, 1>(acc, b1g, h2hi, h2lo, w, lrow, lhi4);
  }
  __syncthreads();
  // L3: N=768 -> 12 ntiles/wave, KT=16; max over 16 rows -> g hi/lo
  {
    f32x4 acc[12][1];
    #pragma unroll
    for (int i = 0; i < 12; ++i) acc[i][0] = zz;
    mfma_gemm<12, 16, 520, 1>(h2hi, h2lo, wt2, w, l, lrow, lk, acc);
    #pragma unroll
    for (int ntl = 0; ntl < 12; ++ntl) {
      int col = (w * 12 + ntl) * 16 + lrow;
      float bv = b2g[col];
      float m = 0.f;
      #pragma unroll
      for (int r = 0; r < 4; ++r)
        m = fmaxf(m, fmaxf((acc[ntl][0][r] + bv) * BN_SCALE, 0.f));
      m = fmaxf(m, __shfl_xor(m, 16));
      m = fmaxf(m, __shfl_xor(m, 32));
      if (l < 16) {
        short hi, lo; bf16split(m, hi, lo);
        ghi[(size_t)b * 768 + col] = hi;
        glo[(size_t)b * 768 + col] = lo;
      }
    }
  }
}

// ---------------------------------------------------------------------------
// FC: [2048][768] x [768][768] + bias -> out. M=16/block, N in halves. KT=24.
// ---------------------------------------------------------------------------
__global__ __launch_bounds__(256) void k_fc(const short* __restrict__ ghi,
                                            const short* __restrict__ glo,
                                            const short* __restrict__ wtf,
                                            const float* __restrict__ fcb,
                                            float* __restrict__ outp) {
  int mblk = blockIdx.x;
  int nh   = blockIdx.y;
  int t = threadIdx.x;
  int l = t & 63, w = t >> 6;
  int lrow = l & 15;
  int lk   = (l >> 4) << 3;
  int lhi4 = (l >> 4) << 2;
  f32x4 zz = {0.f, 0.f, 0.f, 0.f};

  const short* Ahi = ghi + (size_t)mblk * 16 * 768;
  const short* Alo = glo + (size_t)mblk * 16 * 768;
  const short* wt  = wtf + (size_t)nh * 24 * 24 * 1024;

  f32x4 acc[6][1];
  #pragma unroll
  for (int i = 0; i < 6; ++i) acc[i][0] = zz;
  mfma_gemm<6, 24, 768, 1>(Ahi, Alo, wt, w, l, lrow, lk, acc);

  #pragma unroll
  for (int ntl = 0; ntl < 6; ++ntl) {
    int col = nh * 384 + (w * 6 + ntl) * 16 + lrow;
    float bv = fcb[col];
    #pragma unroll
    for (int r = 0; r < 4; ++r) {
      int row = mblk * 16 + lhi4 + r;
      outp[(size_t)row * 768 + col] = acc[ntl][0][r] + bv;
    }
  }
}

// ---------------------------------------------------------------------------
extern "C" void kernel_launch(void* const* d_in, const int* in_sizes, int n_in,
                              void* d_out, int out_size, void* d_ws, size_t ws_size,
                              hipStream_t stream) {
  const float* x    = (const float*)d_in[0];
  const float* w1_0 = (const float*)d_in[1];  const float* b1_0 = (const float*)d_in[2];
  const float* w1_1 = (const float*)d_in[3];  const float* b1_1 = (const float*)d_in[4];
  const float* w1_2 = (const float*)d_in[5];  const float* b1_2 = (const float*)d_in[6];
  const float* w2_0 = (const float*)d_in[7];  const float* b2_0 = (const float*)d_in[8];
  const float* w2_1 = (const float*)d_in[9];  const float* b2_1 = (const float*)d_in[10];
  const float* w2_2 = (const float*)d_in[11]; const float* b2_2 = (const float*)d_in[12];
  const float* w3_0 = (const float*)d_in[13]; const float* b3_0 = (const float*)d_in[14];
  const float* w3_1 = (const float*)d_in[15]; const float* b3_1 = (const float*)d_in[16];
  const float* w3_2 = (const float*)d_in[17]; const float* b3_2 = (const float*)d_in[18];
  const float* fc_w = (const float*)d_in[19]; const float* fc_b = (const float*)d_in[20];
  float* outp = (float*)d_out;

  const size_t n_float = (size_t)NB * 96 + (size_t)NB * 48;
  const size_t n_int   = (size_t)NB * 1024 + (size_t)NB * 512;
  const size_t n_short = 4 * (size_t)NB * 4096                    // f1/f2 hi+lo
                       + (40960 + 32768 + 65536)                  // sa2 wts
                       + (4096 + 8192 + 16384)                    // sa1 wts
                       + (147456 + 262144 + 786432) + 1179648     // mlp3 + fc wts
                       + 2 * (size_t)NB * 768;                    // g hi/lo
  const size_t need_bytes = n_float * 4 + n_int * 4 + n_short * 2;
  if (ws_size < need_bytes) return;

  float* nxyz1 = (float*)d_ws;
  float* nxyz2 = nxyz1 + (size_t)NB * 96;
  int*   idx1  = (int*)(nxyz2 + (size_t)NB * 48);
  int*   idx2  = idx1 + (size_t)NB * 1024;
  short* f1hi  = (short*)(idx2 + (size_t)NB * 512);
  short* f1lo  = f1hi + (size_t)NB * 4096;
  short* f2hi  = f1lo + (size_t)NB * 4096;
  short* f2lo  = f2hi + (size_t)NB * 4096;
  short* wt0   = f2lo + (size_t)NB * 4096;
  short* wt1   = wt0 + 40960;
  short* wt2   = wt1 + 32768;
  short* wt10  = wt2 + 65536;
  short* wt11  = wt10 + 4096;
  short* wt12  = wt11 + 8192;
  short* wt30  = wt12 + 16384;
  short* wt31  = wt30 + 147456;
  short* wt32  = wt31 + 262144;
  short* wtfc  = wt32 + 786432;
  short* ghi   = wtfc + 1179648;
  short* glo   = ghi + (size_t)NB * 768;

  k_prep <<<272, 256, 0, stream>>>(w2_0, w2_1, w2_2, wt0, wt1, wt2);
  k_prep1<<<56, 256, 0, stream>>>(w1_0, w1_1, w1_2, wt10, wt11, wt12);
  k_prep3<<<4640, 256, 0, stream>>>(w3_0, w3_1, w3_2, fc_w, wt30, wt31, wt32, wtfc);
  k_fps1<<<NB, 256, 0, stream>>>(x, nxyz1);
  k_bq1 <<<(NB * 32) / 256, 256, 0, stream>>>(x, nxyz1, idx1);
  k_sa1 <<<NB * 16, 256, 0, stream>>>(x, nxyz1, idx1, wt10, wt11, wt12,
                                      b1_0, b1_1, b1_2, f1hi, f1lo);
  k_fps2<<<NB, 64, 0, stream>>>(nxyz1, nxyz2);
  k_bq2 <<<(NB * 16) / 256, 256, 0, stream>>>(nxyz1, nxyz2, idx2);
  k_sa2 <<<NB * 8, 512, 0, stream>>>(nxyz1, nxyz2, idx2, f1hi, f1lo,
                                     wt0, wt1, wt2, b2_0, b2_1, b2_2, f2hi, f2lo);
  k_mlp3<<<NB, 256, 0, stream>>>(nxyz2, f2hi, f2lo, wt30, wt31, wt32,
                                 b3_0, b3_1, b3_2, ghi, glo);
  k_fc  <<<dim3(NB / 16, 2), 256, 0, stream>>>(ghi, glo, wtfc, fc_b, outp);
}

// Round 10
// 1244.657 us; speedup vs baseline: 3.7812x; 1.0331x over previous
//
#include <hip/hip_runtime.h>
#include <math.h>

#define BN_SCALE 0.999995000037499687f   // 1/sqrt(1+1e-5)
#define NPTS 1024
#define NB   2048    // 32*64 clouds

typedef __attribute__((ext_vector_type(8))) short bh8;
typedef __attribute__((ext_vector_type(4))) float f32x4;

__device__ __forceinline__ float sq3(float x, float y, float z) {
  return __fadd_rn(__fadd_rn(__fmul_rn(x, x), __fmul_rn(y, y)), __fmul_rn(z, z));
}

// RNE f32 -> bf16 bits
__device__ __forceinline__ short bf16hi(float v) {
  unsigned u = __float_as_uint(v);
  unsigned r = (u + 0x7FFFu + ((u >> 16) & 1u)) >> 16;
  return (short)r;
}
__device__ __forceinline__ float bf16tof(short s) {
  unsigned u = ((unsigned)(unsigned short)s) << 16;
  return __uint_as_float(u);
}
__device__ __forceinline__ void bf16split(float v, short& hi, short& lo) {
  hi = bf16hi(v);
  lo = bf16hi(v - bf16tof(hi));
}

// ---------------------------------------------------------------------------
// FPS over 1024 points -> 32 centers per cloud. Bit-exact mirror of reference.
// ---------------------------------------------------------------------------
__global__ __launch_bounds__(256) void k_fps1(const float* __restrict__ x,
                                              float* __restrict__ nxyz1) {
  int b = blockIdx.x;
  const float* cloud = x + (size_t)b * NPTS * 6;
  __shared__ float px[NPTS], py[NPTS], pz[NPTS], dist[NPTS];
  __shared__ float wv_s[4];
  __shared__ int   wi_s[4];
  __shared__ int   last_s;
  int t = threadIdx.x;
  for (int i = t; i < NPTS; i += 256) {
    px[i] = cloud[i * 6 + 0];
    py[i] = cloud[i * 6 + 1];
    pz[i] = cloud[i * 6 + 2];
    dist[i] = 1e10f;
  }
  __syncthreads();
  if (t == 0) {
    nxyz1[(size_t)b * 96 + 0] = px[0];
    nxyz1[(size_t)b * 96 + 1] = py[0];
    nxyz1[(size_t)b * 96 + 2] = pz[0];
  }
  int last = 0;
  for (int s = 1; s < 32; ++s) {
    float lx = px[last], ly = py[last], lz = pz[last];
    float bv = -1.0f; int bi = NPTS;
    for (int i = t; i < NPTS; i += 256) {
      float dx = __fsub_rn(px[i], lx);
      float dy = __fsub_rn(py[i], ly);
      float dz = __fsub_rn(pz[i], lz);
      float d  = sq3(dx, dy, dz);
      float nd = fminf(dist[i], d);
      dist[i] = nd;
      if (nd > bv || (nd == bv && i < bi)) { bv = nd; bi = i; }
    }
    for (int off = 32; off; off >>= 1) {
      float ov = __shfl_down(bv, off);
      int   oi = __shfl_down(bi, off);
      if (ov > bv || (ov == bv && oi < bi)) { bv = ov; bi = oi; }
    }
    if ((t & 63) == 0) { wv_s[t >> 6] = bv; wi_s[t >> 6] = bi; }
    __syncthreads();
    if (t == 0) {
      for (int w = 1; w < 4; ++w)
        if (wv_s[w] > bv || (wv_s[w] == bv && wi_s[w] < bi)) { bv = wv_s[w]; bi = wi_s[w]; }
      last_s = bi;
      nxyz1[(size_t)b * 96 + s * 3 + 0] = px[bi];
      nxyz1[(size_t)b * 96 + s * 3 + 1] = py[bi];
      nxyz1[(size_t)b * 96 + s * 3 + 2] = pz[bi];
    }
    __syncthreads();
    last = last_s;
  }
}

// ---------------------------------------------------------------------------
// Ball query SA1 (bit-exact d2 formula).
// ---------------------------------------------------------------------------
__global__ __launch_bounds__(256) void k_bq1(const float* __restrict__ x,
                                             const float* __restrict__ nxyz1,
                                             int* __restrict__ idx1) {
  int c = blockIdx.x * 256 + threadIdx.x;
  if (c >= NB * 32) return;
  int b = c >> 5;
  const float* cloud = x + (size_t)b * NPTS * 6;
  float cx = nxyz1[c * 3 + 0], cy = nxyz1[c * 3 + 1], cz = nxyz1[c * 3 + 2];
  float sqc = sq3(cx, cy, cz);
  const float r2 = (float)(0.2 * 0.2);
  int hits = 0, fh = NPTS - 1;
  int* outp = idx1 + (size_t)c * 32;
  for (int i = 0; i < NPTS; ++i) {
    float ppx = cloud[i * 6 + 0], ppy = cloud[i * 6 + 1], ppz = cloud[i * 6 + 2];
    float sqp = sq3(ppx, ppy, ppz);
    float dt  = __fadd_rn(__fadd_rn(__fmul_rn(cx, ppx), __fmul_rn(cy, ppy)), __fmul_rn(cz, ppz));
    float d2  = __fsub_rn(__fadd_rn(sqc, sqp), __fmul_rn(2.0f, dt));
    if (d2 < r2) {
      if (hits == 0) fh = i;
      outp[hits] = i;
      if (++hits == 32) break;
    }
  }
  for (int j = hits; j < 32; ++j) outp[j] = fh;
}

// ---------------------------------------------------------------------------
// Weight prep: src fp32 [K][N] -> fragment-major hi/lo bf16.
// permS != 0: activation layout [feat(S) | xyz(3)] k-remap.
// ---------------------------------------------------------------------------
__device__ __forceinline__ void prep_one(const float* __restrict__ src,
                                         short* __restrict__ dst,
                                         int q, int KT, int Kreal, int N, int permS) {
  int nt = q / (KT * 512);
  int r  = q - nt * (KT * 512);
  int kt = r >> 9;
  int e  = r & 511;
  int l = e >> 3, i = e & 7;
  int k = kt * 32 + ((l >> 4) << 3) + i;
  int col = nt * 16 + (l & 15);
  int ko = k;
  if (permS) ko = (k < permS) ? k + 3 : k - permS;
  float v = (k < Kreal) ? src[(size_t)ko * N + col] : 0.f;
  short hi, lo;
  bf16split(v, hi, lo);
  size_t base = ((size_t)(nt * KT + kt) * 2) * 512 + e;
  dst[base] = hi;
  dst[base + 512] = lo;
}

__global__ __launch_bounds__(256) void k_prep(const float* __restrict__ w0,
                                              const float* __restrict__ w1,
                                              const float* __restrict__ w2,
                                              short* __restrict__ wt0,
                                              short* __restrict__ wt1,
                                              short* __restrict__ wt2) {
  int p = blockIdx.x * 256 + threadIdx.x;
  const int S1 = 8 * 5 * 512, S2 = 8 * 4 * 512, S3 = 16 * 4 * 512;
  if (p < S1)                 prep_one(w0, wt0, p,           5, 131, 128, 128);
  else if (p < S1 + S2)       prep_one(w1, wt1, p - S1,      4, 128, 128, 0);
  else if (p < S1 + S2 + S3)  prep_one(w2, wt2, p - S1 - S2, 4, 128, 256, 0);
}

__global__ __launch_bounds__(256) void k_prep1(const float* __restrict__ w0,
                                               const float* __restrict__ w1,
                                               const float* __restrict__ w2,
                                               short* __restrict__ wt0,
                                               short* __restrict__ wt1,
                                               short* __restrict__ wt2) {
  int p = blockIdx.x * 256 + threadIdx.x;
  const int S1 = 4 * 1 * 512, S2 = 4 * 2 * 512, S3 = 8 * 2 * 512;
  if (p < S1)                 prep_one(w0, wt0, p,           1, 6,  64, 0);
  else if (p < S1 + S2)       prep_one(w1, wt1, p - S1,      2, 64, 64, 0);
  else if (p < S1 + S2 + S3)  prep_one(w2, wt2, p - S1 - S2, 2, 64, 128, 0);
}

__global__ __launch_bounds__(256) void k_prep3(const float* __restrict__ w0,
                                               const float* __restrict__ w1,
                                               const float* __restrict__ w2,
                                               const float* __restrict__ wf,
                                               short* __restrict__ wt0,
                                               short* __restrict__ wt1,
                                               short* __restrict__ wt2,
                                               short* __restrict__ wtf) {
  int p = blockIdx.x * 256 + threadIdx.x;
  const int S1 = 16 * 9 * 512;
  const int S2 = 32 * 8 * 512;
  const int S3 = 48 * 16 * 512;
  const int S4 = 48 * 24 * 512;
  if (p < S1)                      prep_one(w0, wt0, p,                9,  259, 256, 256);
  else if (p < S1 + S2)            prep_one(w1, wt1, p - S1,           8,  256, 512, 0);
  else if (p < S1 + S2 + S3)       prep_one(w2, wt2, p - S1 - S2,      16, 512, 768, 0);
  else if (p < S1 + S2 + S3 + S4)  prep_one(wf, wtf, p - S1 - S2 - S3, 24, 768, 768, 0);
}

// ---------------------------------------------------------------------------
// MFMA GEMM: wave handles mtiles {mg*MT+i}, ntiles {ng*NTL+j}, K = KT*32.
// 3-term split: hi*Whi + hi*Wlo + lo*Whi. acc[NTL][MT].
// ---------------------------------------------------------------------------
template<int MT, int NTL, int KT, int PA>
__device__ __forceinline__ void mfma_gemm(const short* Ahi, const short* Alo,
                                          const short* __restrict__ wt,
                                          int mg, int ng, int l, int lrow, int lk,
                                          f32x4 acc[][MT]) {
  for (int kt = 0; kt < KT; ++kt) {
    bh8 ahi[MT], alo[MT];
    #pragma unroll
    for (int mt = 0; mt < MT; ++mt) {
      int aoff = ((mg * MT + mt) * 16 + lrow) * PA + kt * 32 + lk;
      ahi[mt] = *(const bh8*)(Ahi + aoff);
      alo[mt] = *(const bh8*)(Alo + aoff);
    }
    #pragma unroll
    for (int ntl = 0; ntl < NTL; ++ntl) {
      int nt = ng * NTL + ntl;
      bh8 bhi = *(const bh8*)(wt + (size_t)((nt * KT + kt) * 2 + 0) * 512 + l * 8);
      bh8 blo = *(const bh8*)(wt + (size_t)((nt * KT + kt) * 2 + 1) * 512 + l * 8);
      #pragma unroll
      for (int mt = 0; mt < MT; ++mt) {
        acc[ntl][mt] = __builtin_amdgcn_mfma_f32_16x16x32_bf16(ahi[mt], bhi, acc[ntl][mt], 0, 0, 0);
        acc[ntl][mt] = __builtin_amdgcn_mfma_f32_16x16x32_bf16(ahi[mt], blo, acc[ntl][mt], 0, 0, 0);
        acc[ntl][mt] = __builtin_amdgcn_mfma_f32_16x16x32_bf16(alo[mt], bhi, acc[ntl][mt], 0, 0, 0);
      }
    }
  }
}

// Mid-layer epilogue: bias+BN+relu, split hi/lo, store to LDS (pitch PD).
template<int MT, int NTL, int PD>
__device__ __forceinline__ void epi_mid(f32x4 acc[][MT], const float* __restrict__ bias,
                                        short* Dhi, short* Dlo,
                                        int mg, int ng, int lrow, int lhi4) {
  #pragma unroll
  for (int ntl = 0; ntl < NTL; ++ntl) {
    int col = (ng * NTL + ntl) * 16 + lrow;
    float bv = bias[col];
    #pragma unroll
    for (int mt = 0; mt < MT; ++mt) {
      #pragma unroll
      for (int r = 0; r < 4; ++r) {
        int row = (mg * MT + mt) * 16 + lhi4 + r;
        float o = fmaxf((acc[ntl][mt][r] + bv) * BN_SCALE, 0.f);
        short hi, lo;
        bf16split(o, hi, lo);
        Dhi[row * PD + col] = hi;
        Dlo[row * PD + col] = lo;
      }
    }
  }
}

// Final epilogue (SA): one center per wave (its MT mtiles), column max -> hi/lo bf16.
template<int MT, int NTL>
__device__ __forceinline__ void epi_max_bf(f32x4 acc[][MT], const float* __restrict__ bias,
                                           short* __restrict__ hiC, short* __restrict__ loC,
                                           int ng, int l, int lrow) {
  #pragma unroll
  for (int ntl = 0; ntl < NTL; ++ntl) {
    int col = (ng * NTL + ntl) * 16 + lrow;
    float bv = bias[col];
    float m = 0.f;
    #pragma unroll
    for (int mt = 0; mt < MT; ++mt)
      #pragma unroll
      for (int r = 0; r < 4; ++r)
        m = fmaxf(m, fmaxf((acc[ntl][mt][r] + bv) * BN_SCALE, 0.f));
    m = fmaxf(m, __shfl_xor(m, 16));
    m = fmaxf(m, __shfl_xor(m, 32));
    if (l < 16) {
      short hi, lo; bf16split(m, hi, lo);
      hiC[col] = hi; loC[col] = lo;
    }
  }
}

// ---------------------------------------------------------------------------
// SA1: 2 centers/block (M=64), 4 waves, MLP(6->64->64->128).
// Wave (mg = w&1 -> center, ng = w>>1). f1 emitted as hi/lo bf16.
// ---------------------------------------------------------------------------
__global__ __launch_bounds__(256) void k_sa1(const float* __restrict__ x,
                                             const float* __restrict__ nxyz1,
                                             const int* __restrict__ idx1,
                                             const short* __restrict__ wt0,
                                             const short* __restrict__ wt1,
                                             const short* __restrict__ wt2,
                                             const float* __restrict__ b0g,
                                             const float* __restrict__ b1g,
                                             const float* __restrict__ b2g,
                                             short* __restrict__ f1hi,
                                             short* __restrict__ f1lo) {
  int c2 = blockIdx.x;
  int t  = threadIdx.x;
  __shared__ __align__(16) short lds[18432];
  __shared__ int pts[64];
  short* h0hi = lds;             // [64][40]
  short* h0lo = lds + 4608;
  short* h1hi = lds + 9216;      // [64][72]
  short* h1lo = lds + 13824;
  short* h2hi = lds;             // [64][72] overlays h0hi
  short* h2lo = lds + 4608;

  if (t < 64) {
    int g = t >> 5, samp = t & 31;
    pts[t] = idx1[(size_t)(c2 * 2 + g) * 32 + samp];
  }
  for (int j = t; j < 64 * 34; j += 256) {
    int s = j / 34, d = 6 + (j - s * 34);
    h0hi[s * 40 + d] = 0;
    h0lo[s * 40 + d] = 0;
  }
  __syncthreads();

  for (int j = t; j < 384; j += 256) {
    int s = j / 6, d = j - (j / 6) * 6;
    int g = s >> 5; int c = c2 * 2 + g; int b = c >> 5;
    int pt = pts[s];
    float v = x[((size_t)b * NPTS + pt) * 6 + d];
    if (d < 3) v -= nxyz1[(size_t)c * 3 + d];
    short hi, lo; bf16split(v, hi, lo);
    h0hi[s * 40 + d] = hi; h0lo[s * 40 + d] = lo;
  }
  __syncthreads();

  int l = t & 63, w = t >> 6;
  int mg = w & 1, ng = w >> 1;     // MG=2, NG=2
  int lrow = l & 15;
  int lk   = (l >> 4) << 3;
  int lhi4 = (l >> 4) << 2;
  f32x4 zz = {0.f, 0.f, 0.f, 0.f};

  // G1: MT=2, NTL=2, KT=1
  {
    f32x4 acc[2][2];
    #pragma unroll
    for (int i = 0; i < 2; ++i) { acc[i][0] = zz; acc[i][1] = zz; }
    mfma_gemm<2, 2, 1, 40>(h0hi, h0lo, wt0, mg, ng, l, lrow, lk, acc);
    epi_mid<2, 2, 72>(acc, b0g, h1hi, h1lo, mg, ng, lrow, lhi4);
  }
  __syncthreads();
  // G2: MT=2, NTL=2, KT=2
  {
    f32x4 acc[2][2];
    #pragma unroll
    for (int i = 0; i < 2; ++i) { acc[i][0] = zz; acc[i][1] = zz; }
    mfma_gemm<2, 2, 2, 72>(h1hi, h1lo, wt1, mg, ng, l, lrow, lk, acc);
    epi_mid<2, 2, 72>(acc, b1g, h2hi, h2lo, mg, ng, lrow, lhi4);
  }
  __syncthreads();
  // G3: MT=2, NTL=4, KT=2; per-wave center mg
  {
    f32x4 acc[4][2];
    #pragma unroll
    for (int i = 0; i < 4; ++i) { acc[i][0] = zz; acc[i][1] = zz; }
    mfma_gemm<2, 4, 2, 72>(h2hi, h2lo, wt2, mg, ng, l, lrow, lk, acc);
    epi_max_bf<2, 4>(acc, b2g,
                     f1hi + (size_t)(c2 * 2 + mg) * 128,
                     f1lo + (size_t)(c2 * 2 + mg) * 128,
                     ng, l, lrow);
  }
}

// ---------------------------------------------------------------------------
// FPS over 32 centers -> 16. One wave per cloud. (unchanged)
// ---------------------------------------------------------------------------
__global__ __launch_bounds__(64) void k_fps2(const float* __restrict__ nxyz1,
                                             float* __restrict__ nxyz2) {
  int b = blockIdx.x;
  int t = threadIdx.x;
  const float* pts = nxyz1 + (size_t)b * 96;
  float ppx = 0.f, ppy = 0.f, ppz = 0.f, dist = -1.f;
  if (t < 32) { ppx = pts[t * 3]; ppy = pts[t * 3 + 1]; ppz = pts[t * 3 + 2]; dist = 1e10f; }
  if (t == 0) {
    nxyz2[(size_t)b * 48 + 0] = ppx;
    nxyz2[(size_t)b * 48 + 1] = ppy;
    nxyz2[(size_t)b * 48 + 2] = ppz;
  }
  int last = 0;
  for (int s = 1; s < 16; ++s) {
    float lx = __shfl(ppx, last), ly = __shfl(ppy, last), lz = __shfl(ppz, last);
    if (t < 32) {
      float dx = __fsub_rn(ppx, lx);
      float dy = __fsub_rn(ppy, ly);
      float dz = __fsub_rn(ppz, lz);
      dist = fminf(dist, sq3(dx, dy, dz));
    }
    float bv = dist; int bi = (t < 32) ? t : 1000;
    for (int off = 32; off; off >>= 1) {
      float ov = __shfl_xor(bv, off);
      int   oi = __shfl_xor(bi, off);
      if (ov > bv || (ov == bv && oi < bi)) { bv = ov; bi = oi; }
    }
    last = bi;
    float bx = __shfl(ppx, last), by = __shfl(ppy, last), bz = __shfl(ppz, last);
    if (t == 0) {
      nxyz2[(size_t)b * 48 + s * 3 + 0] = bx;
      nxyz2[(size_t)b * 48 + s * 3 + 1] = by;
      nxyz2[(size_t)b * 48 + s * 3 + 2] = bz;
    }
  }
}

// ---------------------------------------------------------------------------
// Ball query SA2 (unchanged).
// ---------------------------------------------------------------------------
__global__ __launch_bounds__(256) void k_bq2(const float* __restrict__ nxyz1,
                                             const float* __restrict__ nxyz2,
                                             int* __restrict__ idx2) {
  int c = blockIdx.x * 256 + threadIdx.x;
  if (c >= NB * 16) return;
  int b = c >> 4;
  const float* pts = nxyz1 + (size_t)b * 96;
  float cx = nxyz2[c * 3 + 0], cy = nxyz2[c * 3 + 1], cz = nxyz2[c * 3 + 2];
  float sqc = sq3(cx, cy, cz);
  const float r2 = (float)(0.4 * 0.4);
  int hits = 0, fh = 31;
  int* outp = idx2 + (size_t)c * 32;
  for (int i = 0; i < 32; ++i) {
    float ppx = pts[i * 3], ppy = pts[i * 3 + 1], ppz = pts[i * 3 + 2];
    float sqp = sq3(ppx, ppy, ppz);
    float dt  = __fadd_rn(__fadd_rn(__fmul_rn(cx, ppx), __fmul_rn(cy, ppy)), __fmul_rn(cz, ppz));
    float d2  = __fsub_rn(__fadd_rn(sqc, sqp), __fmul_rn(2.0f, dt));
    if (d2 < r2) { if (hits == 0) fh = i; outp[hits++] = i; }
  }
  for (int j = hits; j < 32; ++j) outp[j] = fh;
}

// ---------------------------------------------------------------------------
// SA2: 2 centers/block (M=64), 8 waves. Wave (mg = w&1 -> center, ng = w>>1).
// MLP(131->128->128->256). f2 emitted as hi/lo bf16.
// ---------------------------------------------------------------------------
__global__ __launch_bounds__(512, 4) void k_sa2(const float* __restrict__ nxyz1,
                                                const float* __restrict__ nxyz2,
                                                const int* __restrict__ idx2,
                                                const short* __restrict__ f1hi,
                                                const short* __restrict__ f1lo,
                                                const short* __restrict__ wt0,
                                                const short* __restrict__ wt1,
                                                const short* __restrict__ wt2,
                                                const float* __restrict__ b0g,
                                                const float* __restrict__ b1g,
                                                const float* __restrict__ b2g,
                                                short* __restrict__ f2hi,
                                                short* __restrict__ f2lo) {
  int c2 = blockIdx.x;
  int t  = threadIdx.x;
  __shared__ __align__(16) short lds[38912];
  __shared__ int pts[64];
  short* h0hi = lds;             // [64][168]: 0..127 f1, 128..130 gx, 131..159 pad
  short* h0lo = lds + 10752;
  short* h1hi = lds + 21504;     // [64][136]
  short* h1lo = lds + 30208;
  short* h2hi = lds;             // [64][136] overlays h0hi
  short* h2lo = lds + 10752;

  if (t < 64) {
    int g = t >> 5, samp = t & 31;
    pts[t] = idx2[(size_t)(c2 * 2 + g) * 32 + samp];
  }
  for (int j = t; j < 64 * 29; j += 512) {
    int s = j / 29, d = 131 + (j - s * 29);
    h0hi[s * 168 + d] = 0;
    h0lo[s * 168 + d] = 0;
  }
  __syncthreads();

  for (int j = t; j < 1024; j += 512) {
    int s = j >> 4, c8 = j & 15;
    int g = s >> 5; int c = c2 * 2 + g; int b = c >> 4;
    int pt = pts[s];
    size_t src = ((size_t)b * 32 + pt) * 128 + c8 * 8;
    *(bh8*)(h0hi + s * 168 + c8 * 8) = *(const bh8*)(f1hi + src);
    *(bh8*)(h0lo + s * 168 + c8 * 8) = *(const bh8*)(f1lo + src);
  }
  for (int j = t; j < 192; j += 512) {
    int s = j / 3, d = j - (j / 3) * 3;
    int g = s >> 5; int c = c2 * 2 + g; int b = c >> 4;
    int pt = pts[s];
    float v = nxyz1[((size_t)b * 32 + pt) * 3 + d] - nxyz2[(size_t)c * 3 + d];
    short hi, lo; bf16split(v, hi, lo);
    h0hi[s * 168 + 128 + d] = hi; h0lo[s * 168 + 128 + d] = lo;
  }
  __syncthreads();

  int l = t & 63, w = t >> 6;      // w in [0,8)
  int mg = w & 1, ng = w >> 1;     // MG=2, NG=4
  int lrow = l & 15;
  int lk   = (l >> 4) << 3;
  int lhi4 = (l >> 4) << 2;
  f32x4 zz = {0.f, 0.f, 0.f, 0.f};

  // GEMM1: MT=2, NTL=2, KT=5
  {
    f32x4 acc[2][2];
    #pragma unroll
    for (int i = 0; i < 2; ++i) { acc[i][0] = zz; acc[i][1] = zz; }
    mfma_gemm<2, 2, 5, 168>(h0hi, h0lo, wt0, mg, ng, l, lrow, lk, acc);
    epi_mid<2, 2, 136>(acc, b0g, h1hi, h1lo, mg, ng, lrow, lhi4);
  }
  __syncthreads();
  // GEMM2: MT=2, NTL=2, KT=4 (h2 overlays h0)
  {
    f32x4 acc[2][2];
    #pragma unroll
    for (int i = 0; i < 2; ++i) { acc[i][0] = zz; acc[i][1] = zz; }
    mfma_gemm<2, 2, 4, 136>(h1hi, h1lo, wt1, mg, ng, l, lrow, lk, acc);
    epi_mid<2, 2, 136>(acc, b1g, h2hi, h2lo, mg, ng, lrow, lhi4);
  }
  __syncthreads();
  // GEMM3: MT=2, NTL=4, KT=4; per-wave center mg
  {
    f32x4 acc[4][2];
    #pragma unroll
    for (int i = 0; i < 4; ++i) { acc[i][0] = zz; acc[i][1] = zz; }
    mfma_gemm<2, 4, 4, 136>(h2hi, h2lo, wt2, mg, ng, l, lrow, lk, acc);
    epi_max_bf<2, 4>(acc, b2g,
                     f2hi + (size_t)(c2 * 2 + mg) * 256,
                     f2lo + (size_t)(c2 * 2 + mg) * 256,
                     ng, l, lrow);
  }
}

// ---------------------------------------------------------------------------
// MLP3: 2 clouds/block (M=32), 8 waves. Wave mg=0 (MT=2 covers both clouds),
// ng = w. h0 = [f2(256) | nxyz2(3) | pad]. Output g as hi/lo bf16.
// ---------------------------------------------------------------------------
__global__ __launch_bounds__(512) void k_mlp3(const float* __restrict__ nxyz2,
                                              const short* __restrict__ f2hi,
                                              const short* __restrict__ f2lo,
                                              const short* __restrict__ wt0,
                                              const short* __restrict__ wt1,
                                              const short* __restrict__ wt2,
                                              const float* __restrict__ b0g,
                                              const float* __restrict__ b1g,
                                              const float* __restrict__ b2g,
                                              short* __restrict__ ghi,
                                              short* __restrict__ glo) {
  int b2 = blockIdx.x;            // clouds 2*b2, 2*b2+1
  int t = threadIdx.x;
  __shared__ __align__(16) short lds[50176];   // 100,352 B
  short* h1hi = lds;              // [32][264]
  short* h1lo = lds + 8448;
  short* h0hi = lds + 16896;      // [32][296]
  short* h0lo = lds + 26368;
  short* h2hi = lds + 16896;      // [32][520] overlays h0
  short* h2lo = lds + 33536;

  // zero pad cols 259..287
  for (int j = t; j < 32 * 29; j += 512) {
    int s = j / 29, d = 259 + (j - s * 29);
    h0hi[s * 296 + d] = 0;
    h0lo[s * 296 + d] = 0;
  }
  // f2 cols 0..255 (aligned bh8): 32 rows x 32 chunks
  for (int j = t; j < 1024; j += 512) {
    int s = j >> 5, c8 = j & 31;
    int cl = b2 * 2 + (s >> 4);
    size_t src = ((size_t)cl * 16 + (s & 15)) * 256 + c8 * 8;
    *(bh8*)(h0hi + s * 296 + c8 * 8) = *(const bh8*)(f2hi + src);
    *(bh8*)(h0lo + s * 296 + c8 * 8) = *(const bh8*)(f2lo + src);
  }
  // nxyz2 cols 256..258
  for (int j = t; j < 96; j += 512) {
    int s = j / 3, d = j - (j / 3) * 3;
    int cl = b2 * 2 + (s >> 4);
    float v = nxyz2[(size_t)cl * 48 + (s & 15) * 3 + d];
    short hi, lo; bf16split(v, hi, lo);
    h0hi[s * 296 + 256 + d] = hi;
    h0lo[s * 296 + 256 + d] = lo;
  }
  __syncthreads();

  int l = t & 63, w = t >> 6;      // w in [0,8)
  int lrow = l & 15;
  int lk   = (l >> 4) << 3;
  int lhi4 = (l >> 4) << 2;
  f32x4 zz = {0.f, 0.f, 0.f, 0.f};

  // L1: MT=2, NTL=2, KT=9 (N=256: nt = w*2+j)
  {
    f32x4 acc[2][2];
    #pragma unroll
    for (int i = 0; i < 2; ++i) { acc[i][0] = zz; acc[i][1] = zz; }
    mfma_gemm<2, 2, 9, 296>(h0hi, h0lo, wt0, 0, w, l, lrow, lk, acc);
    epi_mid<2, 2, 264>(acc, b0g, h1hi, h1lo, 0, w, lrow, lhi4);
  }
  __syncthreads();
  // L2: MT=2, NTL=4, KT=8 (N=512); h2 overlays h0
  {
    f32x4 acc[4][2];
    #pragma unroll
    for (int i = 0; i < 4; ++i) { acc[i][0] = zz; acc[i][1] = zz; }
    mfma_gemm<2, 4, 8, 264>(h1hi, h1lo, wt1, 0, w, l, lrow, lk, acc);
    epi_mid<2, 4, 520>(acc, b1g, h2hi, h2lo, 0, w, lrow, lhi4);
  }
  __syncthreads();
  // L3: MT=2, NTL=6, KT=16 (N=768); per-cloud (mt) 16-row max -> g hi/lo
  {
    f32x4 acc[6][2];
    #pragma unroll
    for (int i = 0; i < 6; ++i) { acc[i][0] = zz; acc[i][1] = zz; }
    mfma_gemm<2, 6, 16, 520>(h2hi, h2lo, wt2, 0, w, l, lrow, lk, acc);
    #pragma unroll
    for (int ntl = 0; ntl < 6; ++ntl) {
      int col = (w * 6 + ntl) * 16 + lrow;
      float bv = b2g[col];
      #pragma unroll
      for (int mt = 0; mt < 2; ++mt) {
        float m = 0.f;
        #pragma unroll
        for (int r = 0; r < 4; ++r)
          m = fmaxf(m, fmaxf((acc[ntl][mt][r] + bv) * BN_SCALE, 0.f));
        m = fmaxf(m, __shfl_xor(m, 16));
        m = fmaxf(m, __shfl_xor(m, 32));
        if (l < 16) {
          short hi, lo; bf16split(m, hi, lo);
          ghi[(size_t)(b2 * 2 + mt) * 768 + col] = hi;
          glo[(size_t)(b2 * 2 + mt) * 768 + col] = lo;
        }
      }
    }
  }
}

// ---------------------------------------------------------------------------
// FC: [2048][768] x [768][768] + bias -> out. M=16/block, N in halves. KT=24.
// ---------------------------------------------------------------------------
__global__ __launch_bounds__(256) void k_fc(const short* __restrict__ ghi,
                                            const short* __restrict__ glo,
                                            const short* __restrict__ wtf,
                                            const float* __restrict__ fcb,
                                            float* __restrict__ outp) {
  int mblk = blockIdx.x;
  int nh   = blockIdx.y;
  int t = threadIdx.x;
  int l = t & 63, w = t >> 6;
  int lrow = l & 15;
  int lk   = (l >> 4) << 3;
  int lhi4 = (l >> 4) << 2;
  f32x4 zz = {0.f, 0.f, 0.f, 0.f};

  const short* Ahi = ghi + (size_t)mblk * 16 * 768;
  const short* Alo = glo + (size_t)mblk * 16 * 768;
  const short* wt  = wtf + (size_t)nh * 24 * 24 * 1024;

  f32x4 acc[6][1];
  #pragma unroll
  for (int i = 0; i < 6; ++i) acc[i][0] = zz;
  mfma_gemm<1, 6, 24, 768>(Ahi, Alo, wt, 0, w, l, lrow, lk, acc);

  #pragma unroll
  for (int ntl = 0; ntl < 6; ++ntl) {
    int col = nh * 384 + (w * 6 + ntl) * 16 + lrow;
    float bv = fcb[col];
    #pragma unroll
    for (int r = 0; r < 4; ++r) {
      int row = mblk * 16 + lhi4 + r;
      outp[(size_t)row * 768 + col] = acc[ntl][0][r] + bv;
    }
  }
}

// ---------------------------------------------------------------------------
extern "C" void kernel_launch(void* const* d_in, const int* in_sizes, int n_in,
                              void* d_out, int out_size, void* d_ws, size_t ws_size,
                              hipStream_t stream) {
  const float* x    = (const float*)d_in[0];
  const float* w1_0 = (const float*)d_in[1];  const float* b1_0 = (const float*)d_in[2];
  const float* w1_1 = (const float*)d_in[3];  const float* b1_1 = (const float*)d_in[4];
  const float* w1_2 = (const float*)d_in[5];  const float* b1_2 = (const float*)d_in[6];
  const float* w2_0 = (const float*)d_in[7];  const float* b2_0 = (const float*)d_in[8];
  const float* w2_1 = (const float*)d_in[9];  const float* b2_1 = (const float*)d_in[10];
  const float* w2_2 = (const float*)d_in[11]; const float* b2_2 = (const float*)d_in[12];
  const float* w3_0 = (const float*)d_in[13]; const float* b3_0 = (const float*)d_in[14];
  const float* w3_1 = (const float*)d_in[15]; const float* b3_1 = (const float*)d_in[16];
  const float* w3_2 = (const float*)d_in[17]; const float* b3_2 = (const float*)d_in[18];
  const float* fc_w = (const float*)d_in[19]; const float* fc_b = (const float*)d_in[20];
  float* outp = (float*)d_out;

  const size_t n_float = (size_t)NB * 96 + (size_t)NB * 48;
  const size_t n_int   = (size_t)NB * 1024 + (size_t)NB * 512;
  const size_t n_short = 4 * (size_t)NB * 4096
                       + (40960 + 32768 + 65536)
                       + (4096 + 8192 + 16384)
                       + (147456 + 262144 + 786432) + 1179648
                       + 2 * (size_t)NB * 768;
  const size_t need_bytes = n_float * 4 + n_int * 4 + n_short * 2;
  if (ws_size < need_bytes) return;

  float* nxyz1 = (float*)d_ws;
  float* nxyz2 = nxyz1 + (size_t)NB * 96;
  int*   idx1  = (int*)(nxyz2 + (size_t)NB * 48);
  int*   idx2  = idx1 + (size_t)NB * 1024;
  short* f1hi  = (short*)(idx2 + (size_t)NB * 512);
  short* f1lo  = f1hi + (size_t)NB * 4096;
  short* f2hi  = f1lo + (size_t)NB * 4096;
  short* f2lo  = f2hi + (size_t)NB * 4096;
  short* wt0   = f2lo + (size_t)NB * 4096;
  short* wt1   = wt0 + 40960;
  short* wt2   = wt1 + 32768;
  short* wt10  = wt2 + 65536;
  short* wt11  = wt10 + 4096;
  short* wt12  = wt11 + 8192;
  short* wt30  = wt12 + 16384;
  short* wt31  = wt30 + 147456;
  short* wt32  = wt31 + 262144;
  short* wtfc  = wt32 + 786432;
  short* ghi   = wtfc + 1179648;
  short* glo   = ghi + (size_t)NB * 768;

  k_prep <<<272, 256, 0, stream>>>(w2_0, w2_1, w2_2, wt0, wt1, wt2);
  k_prep1<<<56, 256, 0, stream>>>(w1_0, w1_1, w1_2, wt10, wt11, wt12);
  k_prep3<<<4640, 256, 0, stream>>>(w3_0, w3_1, w3_2, fc_w, wt30, wt31, wt32, wtfc);
  k_fps1<<<NB, 256, 0, stream>>>(x, nxyz1);
  k_bq1 <<<(NB * 32) / 256, 256, 0, stream>>>(x, nxyz1, idx1);
  k_sa1 <<<NB * 16, 256, 0, stream>>>(x, nxyz1, idx1, wt10, wt11, wt12,
                                      b1_0, b1_1, b1_2, f1hi, f1lo);
  k_fps2<<<NB, 64, 0, stream>>>(nxyz1, nxyz2);
  k_bq2 <<<(NB * 16) / 256, 256, 0, stream>>>(nxyz1, nxyz2, idx2);
  k_sa2 <<<NB * 8, 512, 0, stream>>>(nxyz1, nxyz2, idx2, f1hi, f1lo,
                                     wt0, wt1, wt2, b2_0, b2_1, b2_2, f2hi, f2lo);
  k_mlp3<<<NB / 2, 512, 0, stream>>>(nxyz2, f2hi, f2lo, wt30, wt31, wt32,
                                     b3_0, b3_1, b3_2, ghi, glo);
  k_fc  <<<dim3(NB / 16, 2), 256, 0, stream>>>(ghi, glo, wtfc, fc_b, outp);
}